// Round 1
// baseline (1206.545 us; speedup 1.0000x reference)
//
#include <hip/hip_runtime.h>
#include <math.h>

#define BG   256                   // graphs
#define NN   512                   // nodes per graph
#define HF   64                    // feat == hid == 64
#define NE   (BG * NN * 16)        // 2097152 edges
#define N0   (BG * NN)             // 131072
#define K1   256
#define N1_  (BG * K1)             // 65536
#define K2   128
#define N2_  (BG * K2)             // 32768

#ifndef __HIP_PLATFORM_AMD__
#define unsafeAtomicAdd atomicAdd
#endif

// ---------------- Y[n,64] = X[n,64] @ W[64,64] ----------------
__global__ void mm64_kernel(const float* __restrict__ X, const float* __restrict__ W,
                            float* __restrict__ Y, int nrows) {
    int lane = threadIdx.x & 63;
    int wid  = (blockIdx.x * blockDim.x + threadIdx.x) >> 6;
    int nw   = (gridDim.x * blockDim.x) >> 6;
    float wcol[64];                         // column `lane` of W
#pragma unroll
    for (int k = 0; k < 64; ++k) wcol[k] = W[k * 64 + lane];
    for (int r = wid; r < nrows; r += nw) {
        float xv  = X[(size_t)r * 64 + lane];
        float acc = 0.f;
#pragma unroll
        for (int k = 0; k < 64; ++k) {
            float b = __shfl(xv, k, 64);
            acc = fmaf(b, wcol[k], acc);
        }
        Y[(size_t)r * 64 + lane] = acc;
    }
}

// ---------------- y[n] = X[n,64] @ w[64] ----------------
__global__ void mv64_kernel(const float* __restrict__ X, const float* __restrict__ w,
                            float* __restrict__ y, int nrows) {
    int lane = threadIdx.x & 63;
    int wid  = (blockIdx.x * blockDim.x + threadIdx.x) >> 6;
    int nw   = (gridDim.x * blockDim.x) >> 6;
    float wv = w[lane];
    for (int r = wid; r < nrows; r += nw) {
        float v = X[(size_t)r * 64 + lane] * wv;
#pragma unroll
        for (int off = 32; off > 0; off >>= 1) v += __shfl_xor(v, off, 64);
        if (lane == 0) y[r] = v;
    }
}

__global__ void fill_kernel(float* __restrict__ p, float v, int n) {
    int i = blockIdx.x * blockDim.x + threadIdx.x;
    if (i < n) p[i] = v;
}

// deg[dst] += ew   (skip exact zeros: dropped edges in stage 2)
__global__ void deg_edge_kernel(const int* __restrict__ dst, const float* __restrict__ ew,
                                float* __restrict__ deg, int ne) {
    int e = blockIdx.x * blockDim.x + threadIdx.x;
    if (e < ne) {
        float w = ew[e];
        if (w != 0.f) unsafeAtomicAdd(&deg[dst[e]], w);
    }
}

// deg -> rsqrt(deg) in place
__global__ void rsqrt_kernel(float* __restrict__ deg, int n) {
    int i = blockIdx.x * blockDim.x + threadIdx.x;
    if (i < n) deg[i] = rsqrtf(deg[i]);
}

// out[i,c] = hx[i,c] * dinv[i]^2 + b[c]   (self-loop term + bias)
__global__ void init_out_kernel(const float* __restrict__ hx, const float* __restrict__ dinv,
                                const float* __restrict__ b, float* __restrict__ out, int n64) {
    int i = blockIdx.x * blockDim.x + threadIdx.x;
    if (i < n64) {
        int r = i >> 6, c = i & 63;
        float di = dinv[r];
        out[i] = hx[i] * di * di + b[c];
    }
}

// out[dst,:] += dinv[dst]*ew*dinv[src] * hx[src,:]   — one wave per edge, lane = feature
__global__ void scatter_feat_kernel(const float* __restrict__ hx,
                                    const int* __restrict__ src, const int* __restrict__ dst,
                                    const float* __restrict__ ew, const float* __restrict__ dinv,
                                    float* __restrict__ out, int ne) {
    int lane = threadIdx.x & 63;
    int wid  = (blockIdx.x * blockDim.x + threadIdx.x) >> 6;
    int nw   = (gridDim.x * blockDim.x) >> 6;
    int per  = (ne + nw - 1) / nw;          // contiguous chunk per wave for L2 locality
    int e0 = wid * per;
    int e1 = e0 + per; if (e1 > ne) e1 = ne;
    for (int e = e0; e < e1; ++e) {
        float w = ew[e];
        if (w == 0.f) continue;
        int s = src[e], d = dst[e];
        float coef = dinv[d] * w * dinv[s];
        unsafeAtomicAdd(&out[(size_t)d * 64 + lane], coef * hx[(size_t)s * 64 + lane]);
    }
}

__global__ void relu_kernel(float* __restrict__ p, int n) {
    int i = blockIdx.x * blockDim.x + threadIdx.x;
    if (i < n) p[i] = fmaxf(p[i], 0.f);
}

__global__ void score_init_kernel(const float* __restrict__ hp, const float* __restrict__ dinv,
                                  const float* __restrict__ bp, float* __restrict__ sc, int n) {
    int i = blockIdx.x * blockDim.x + threadIdx.x;
    if (i < n) {
        float di = dinv[i];
        sc[i] = hp[i] * di * di + bp[0];
    }
}

__global__ void scatter_score_kernel(const float* __restrict__ hp,
                                     const int* __restrict__ src, const int* __restrict__ dst,
                                     const float* __restrict__ ew, const float* __restrict__ dinv,
                                     float* __restrict__ sc, int ne) {
    int e = blockIdx.x * blockDim.x + threadIdx.x;
    if (e < ne) {
        float w = ew[e];
        if (w != 0.f) {
            int s = src[e], d = dst[e];
            unsafeAtomicAdd(&sc[d], dinv[d] * w * dinv[s] * hp[s]);
        }
    }
}

// Exact jax.lax.top_k order: rank = #(s[j] > s[i]) + #(s[j]==s[i] && j<i).
// Ranks are a permutation of [0,NPG) so every perm/gate slot is written.
template <int NPG, int K>
__global__ void pool_rank_kernel(const float* __restrict__ score, int* __restrict__ newid,
                                 int* __restrict__ perm, float* __restrict__ gate) {
    __shared__ float s[NPG];
    int g = blockIdx.x, base = g * NPG;
    for (int i = threadIdx.x; i < NPG; i += blockDim.x) s[i] = score[base + i];
    __syncthreads();
    for (int i = threadIdx.x; i < NPG; i += blockDim.x) {
        float si = s[i];
        int rank = 0;
        for (int j = 0; j < NPG; ++j) {
            float sj = s[j];
            rank += (sj > si) || (sj == si && j < i);
        }
        if (rank < K) {
            newid[base + i]   = g * K + rank;
            perm[g * K + rank] = base + i;
            gate[g * K + rank] = tanhf(si);
        } else {
            newid[base + i] = -1;
        }
    }
}

// xn[j,:] = h[perm[j],:] * gate[j]   — one wave per pooled node
__global__ void gather_pool_kernel(const float* __restrict__ h, const int* __restrict__ perm,
                                   const float* __restrict__ gate, float* __restrict__ xn, int np) {
    int lane = threadIdx.x & 63;
    int wid  = (blockIdx.x * blockDim.x + threadIdx.x) >> 6;
    int nw   = (gridDim.x * blockDim.x) >> 6;
    for (int j = wid; j < np; j += nw) {
        int node = perm[j];
        float gt = gate[j];
        xn[(size_t)j * 64 + lane] = h[(size_t)node * 64 + lane] * gt;
    }
}

__global__ void edge_remap_kernel(const int* __restrict__ src, const int* __restrict__ dst,
                                  const float* __restrict__ ew, const int* __restrict__ newid,
                                  int* __restrict__ s2, int* __restrict__ d2,
                                  float* __restrict__ ew2, int ne) {
    int e = blockIdx.x * blockDim.x + threadIdx.x;
    if (e < ne) {
        int a = newid[src[e]], b = newid[dst[e]];
        bool v = (a >= 0) && (b >= 0);
        s2[e]  = v ? a : 0;
        d2[e]  = v ? b : 0;
        ew2[e] = v ? ew[e] : 0.f;
    }
}

// [max || mean] per graph over K contiguous nodes
template <int K>
__global__ void readout_kernel(const float* __restrict__ xn, float* __restrict__ out) {
    int g = blockIdx.x;
    int c = threadIdx.x & 63;
    int q = threadIdx.x >> 6;               // 0..3
    float mx = -3.402823466e+38f, sm = 0.f;
    for (int j = q; j < K; j += 4) {
        float v = xn[((size_t)g * K + j) * 64 + c];
        mx = fmaxf(mx, v);
        sm += v;
    }
    __shared__ float smx[4][64], ssm[4][64];
    smx[q][c] = mx; ssm[q][c] = sm;
    __syncthreads();
    if (q == 0) {
#pragma unroll
        for (int t = 1; t < 4; ++t) { mx = fmaxf(mx, smx[t][c]); sm += ssm[t][c]; }
        out[g * 128 + c]      = mx;
        out[g * 128 + 64 + c] = sm * (1.f / K);
    }
}

__global__ void combine_kernel(const float* __restrict__ a, const float* __restrict__ b,
                               float* __restrict__ out, int n) {
    int i = blockIdx.x * blockDim.x + threadIdx.x;
    if (i < n) out[i] = 0.5f * (a[i] + b[i]);
}

extern "C" void kernel_launch(void* const* d_in, const int* in_sizes, int n_in,
                              void* d_out, int out_size, void* d_ws, size_t ws_size,
                              hipStream_t stream) {
    const float* x    = (const float*)d_in[0];
    const float* eatt = (const float*)d_in[1];
    const float* W1   = (const float*)d_in[2];
    const float* b1   = (const float*)d_in[3];
    const float* Wp1  = (const float*)d_in[4];
    const float* bp1  = (const float*)d_in[5];
    const float* W2   = (const float*)d_in[6];
    const float* b2   = (const float*)d_in[7];
    const float* Wp2  = (const float*)d_in[8];
    const float* bp2  = (const float*)d_in[9];
    const int*   esrc = (const int*)d_in[10];
    const int*   edst = (const int*)d_in[11];
    float* out = (float*)d_out;

    // workspace layout (floats); R1/R2 regions are reused across stages (~86 MB total)
    float* ws = (float*)d_ws;
    size_t o = 0;
    float* R1   = ws + o; o += (size_t)N0 * 64;   // hx1 -> later {hx2, h2}
    float* R2   = ws + o; o += (size_t)N0 * 64;   // h1  -> later {s2, d2, ew2}
    float* deg1 = ws + o; o += N0;                // becomes dinv1
    float* hp1  = ws + o; o += N0;
    float* sc1  = ws + o; o += N0;
    int*   nid1 = (int*)(ws + o); o += N0;
    int*   pm1  = (int*)(ws + o); o += N1_;
    float* gt1  = ws + o; o += N1_;
    float* xn1  = ws + o; o += (size_t)N1_ * 64;  // -> later xn2
    float* deg2 = ws + o; o += N1_;
    float* hp2  = ws + o; o += N1_;
    float* sc2  = ws + o; o += N1_;
    int*   nid2 = (int*)(ws + o); o += N1_;
    int*   pm2  = (int*)(ws + o); o += N2_;
    float* gt2  = ws + o; o += N2_;
    float* x1r  = ws + o; o += BG * 128;
    float* x2r  = ws + o; o += BG * 128;

    float* hx1 = R1;
    float* h1  = R2;
    float* hx2 = R1;                       // alive after hx1 dead
    float* h2  = R1 + (size_t)N1_ * 64;
    int*   s2  = (int*)R2;                 // alive after h1 dead
    int*   d2  = (int*)R2 + NE;
    float* ew2 = R2 + 2 * (size_t)NE;
    float* xn2 = xn1;                      // alive after xn1 dead

    const int TB = 256;
    // ---- stage 1: conv1 + relu ----
    mm64_kernel<<<1024, TB, 0, stream>>>(x, W1, hx1, N0);
    fill_kernel<<<(N0 + TB - 1) / TB, TB, 0, stream>>>(deg1, 1.0f, N0);
    deg_edge_kernel<<<(NE + TB - 1) / TB, TB, 0, stream>>>(edst, eatt, deg1, NE);
    rsqrt_kernel<<<(N0 + TB - 1) / TB, TB, 0, stream>>>(deg1, N0);
    init_out_kernel<<<(N0 * 64 + TB - 1) / TB, TB, 0, stream>>>(hx1, deg1, b1, h1, N0 * 64);
    scatter_feat_kernel<<<2048, TB, 0, stream>>>(hx1, esrc, edst, eatt, deg1, h1, NE);
    relu_kernel<<<(N0 * 64 + TB - 1) / TB, TB, 0, stream>>>(h1, N0 * 64);
    // ---- score1 = gcn(h1, Wp1) ----
    mv64_kernel<<<1024, TB, 0, stream>>>(h1, Wp1, hp1, N0);
    score_init_kernel<<<(N0 + TB - 1) / TB, TB, 0, stream>>>(hp1, deg1, bp1, sc1, N0);
    scatter_score_kernel<<<(NE + TB - 1) / TB, TB, 0, stream>>>(hp1, esrc, edst, eatt, deg1, sc1, NE);
    // ---- pool1 + readout1 ----
    pool_rank_kernel<NN, K1><<<BG, TB, 0, stream>>>(sc1, nid1, pm1, gt1);
    gather_pool_kernel<<<512, TB, 0, stream>>>(h1, pm1, gt1, xn1, N1_);   // h1 dead after this
    readout_kernel<K1><<<BG, TB, 0, stream>>>(xn1, x1r);
    edge_remap_kernel<<<(NE + TB - 1) / TB, TB, 0, stream>>>(esrc, edst, eatt, nid1, s2, d2, ew2, NE);
    // ---- stage 2: conv2 + relu ----
    mm64_kernel<<<1024, TB, 0, stream>>>(xn1, W2, hx2, N1_);              // hx1 dead, reuse R1
    fill_kernel<<<(N1_ + TB - 1) / TB, TB, 0, stream>>>(deg2, 1.0f, N1_);
    deg_edge_kernel<<<(NE + TB - 1) / TB, TB, 0, stream>>>(d2, ew2, deg2, NE);
    rsqrt_kernel<<<(N1_ + TB - 1) / TB, TB, 0, stream>>>(deg2, N1_);
    init_out_kernel<<<(N1_ * 64 + TB - 1) / TB, TB, 0, stream>>>(hx2, deg2, b2, h2, N1_ * 64);
    scatter_feat_kernel<<<2048, TB, 0, stream>>>(hx2, s2, d2, ew2, deg2, h2, NE);
    relu_kernel<<<(N1_ * 64 + TB - 1) / TB, TB, 0, stream>>>(h2, N1_ * 64);
    // ---- score2 ----
    mv64_kernel<<<512, TB, 0, stream>>>(h2, Wp2, hp2, N1_);
    score_init_kernel<<<(N1_ + TB - 1) / TB, TB, 0, stream>>>(hp2, deg2, bp2, sc2, N1_);
    scatter_score_kernel<<<(NE + TB - 1) / TB, TB, 0, stream>>>(hp2, s2, d2, ew2, deg2, sc2, NE);
    // ---- pool2 + readout2 ----
    pool_rank_kernel<K1, K2><<<BG, TB, 0, stream>>>(sc2, nid2, pm2, gt2);
    gather_pool_kernel<<<512, TB, 0, stream>>>(h2, pm2, gt2, xn2, N2_);
    readout_kernel<K2><<<BG, TB, 0, stream>>>(xn2, x2r);
    // ---- final ----
    combine_kernel<<<(BG * 128 + TB - 1) / TB, TB, 0, stream>>>(x1r, x2r, out, BG * 128);
}

// Round 2
// 647.347 us; speedup vs baseline: 1.8638x; 1.8638x over previous
//
#include <hip/hip_runtime.h>
#include <math.h>

#define BG   256                   // graphs
#define NN   512                   // nodes per graph
#define EPG  (NN * 16)             // 8192 edges per graph
#define NE   (BG * EPG)            // 2097152 edges
#define N0   (BG * NN)             // 131072
#define K1   256
#define N1_  (BG * K1)             // 65536
#define K2   128
#define N2_  (BG * K2)             // 32768

// ---------------- Y[n,64] = X[n,64] @ W[64,64] ----------------
__global__ void mm64_kernel(const float* __restrict__ X, const float* __restrict__ W,
                            float* __restrict__ Y, int nrows) {
    int lane = threadIdx.x & 63;
    int wid  = (blockIdx.x * blockDim.x + threadIdx.x) >> 6;
    int nw   = (gridDim.x * blockDim.x) >> 6;
    float wcol[64];                         // column `lane` of W
#pragma unroll
    for (int k = 0; k < 64; ++k) wcol[k] = W[k * 64 + lane];
    for (int r = wid; r < nrows; r += nw) {
        float xv  = X[(size_t)r * 64 + lane];
        float acc = 0.f;
#pragma unroll
        for (int k = 0; k < 64; ++k) {
            float b = __shfl(xv, k, 64);
            acc = fmaf(b, wcol[k], acc);
        }
        Y[(size_t)r * 64 + lane] = acc;
    }
}

// ---------------- y[n] = X[n,64] @ w[64] ----------------
__global__ void mv64_kernel(const float* __restrict__ X, const float* __restrict__ w,
                            float* __restrict__ y, int nrows) {
    int lane = threadIdx.x & 63;
    int wid  = (blockIdx.x * blockDim.x + threadIdx.x) >> 6;
    int nw   = (gridDim.x * blockDim.x) >> 6;
    float wv = w[lane];
    for (int r = wid; r < nrows; r += nw) {
        float v = X[(size_t)r * 64 + lane] * wv;
#pragma unroll
        for (int off = 32; off > 0; off >>= 1) v += __shfl_xor(v, off, 64);
        if (lane == 0) y[r] = v;
    }
}

// ---- block-per-graph CSR build (by dst) + weighted degree -> dinv ----
// nid == nullptr: stage-1 (identity mapping). nid != nullptr: stage-2 remap;
// edges with a dropped endpoint are excluded (equivalent to ew=0 in reference).
template <int NPG>
__global__ void csr_build_kernel(const int* __restrict__ esrc, const int* __restrict__ edst,
                                 const float* __restrict__ eatt, const int* __restrict__ nid,
                                 int* __restrict__ csr_eid, int* __restrict__ rowstart,
                                 int* __restrict__ rowcnt, float* __restrict__ dinv) {
    __shared__ int   cnt[NPG];
    __shared__ float wsum[NPG];
    __shared__ int   scn[NPG];
    constexpr int ITEMS = NPG / 256;
    int g  = blockIdx.x;
    int e0 = g * EPG;
#pragma unroll
    for (int t = 0; t < ITEMS; ++t) { int i = threadIdx.x + t * 256; cnt[i] = 0; wsum[i] = 0.f; }
    __syncthreads();
    for (int e = e0 + threadIdx.x; e < e0 + EPG; e += 256) {
        int d = edst[e];
        int dl; bool valid;
        if (nid) {
            int dn = nid[d], sn = nid[esrc[e]];
            valid = (dn >= 0) && (sn >= 0);
            dl = dn - g * NPG;
        } else { valid = true; dl = d - g * NPG; }
        if (valid) {
            atomicAdd(&cnt[dl], 1);
            atomicAdd(&wsum[dl], eatt[e]);
        }
    }
    __syncthreads();
#pragma unroll
    for (int t = 0; t < ITEMS; ++t) { int i = threadIdx.x + t * 256; scn[i] = cnt[i]; }
    __syncthreads();
    for (int off = 1; off < NPG; off <<= 1) {
        int v[ITEMS];
#pragma unroll
        for (int t = 0; t < ITEMS; ++t) { int i = threadIdx.x + t * 256; v[t] = (i >= off) ? scn[i - off] : 0; }
        __syncthreads();
#pragma unroll
        for (int t = 0; t < ITEMS; ++t) { int i = threadIdx.x + t * 256; scn[i] += v[t]; }
        __syncthreads();
    }
#pragma unroll
    for (int t = 0; t < ITEMS; ++t) {
        int i  = threadIdx.x + t * 256;
        int st = scn[i] - cnt[i];            // exclusive scan
        rowstart[g * NPG + i] = e0 + st;
        rowcnt[g * NPG + i]   = cnt[i];
        dinv[g * NPG + i]     = rsqrtf(wsum[i] + 1.0f);
        scn[i] = st;                          // becomes running slot offset
    }
    __syncthreads();
    for (int e = e0 + threadIdx.x; e < e0 + EPG; e += 256) {
        int d = edst[e];
        int dl; bool valid;
        if (nid) {
            int dn = nid[d], sn = nid[esrc[e]];
            valid = (dn >= 0) && (sn >= 0);
            dl = dn - g * NPG;
        } else { valid = true; dl = d - g * NPG; }
        if (valid) {
            int slot = e0 + atomicAdd(&scn[dl], 1);
            csr_eid[slot] = e;
        }
    }
}

// ---- gather conv: wave per dst node, lane = feature; relu fused ----
__global__ void gather_feat_kernel(const float* __restrict__ hx,
                                   const int* __restrict__ csr_eid,
                                   const int* __restrict__ rowstart, const int* __restrict__ rowcnt,
                                   const float* __restrict__ dinv,
                                   const int* __restrict__ esrc, const float* __restrict__ eatt,
                                   const int* __restrict__ nid,
                                   const float* __restrict__ b,
                                   float* __restrict__ out, int n) {
    int lane = threadIdx.x & 63;
    int node = (blockIdx.x * blockDim.x + threadIdx.x) >> 6;
    if (node >= n) return;
    float di = dinv[node];
    int st = rowstart[node], cn = rowcnt[node];
    float acc = hx[(size_t)node * 64 + lane] * di * di + b[lane];  // self-loop + bias
    for (int base = 0; base < cn; base += 64) {
        int m = cn - base; if (m > 64) m = 64;
        int s = 0; float c = 0.f;
        if (lane < m) {
            int eid = csr_eid[st + base + lane];
            s = esrc[eid];
            if (nid) s = nid[s];              // valid by construction of CSR
            c = di * eatt[eid] * dinv[s];
        }
        for (int j = 0; j < m; ++j) {
            int   sj = __shfl(s, j, 64);
            float cj = __shfl(c, j, 64);
            acc = fmaf(cj, hx[(size_t)sj * 64 + lane], acc);
        }
    }
    out[(size_t)node * 64 + lane] = fmaxf(acc, 0.f);
}

// ---- gather score conv (out dim 1): thread per dst node ----
__global__ void gather_score_kernel(const float* __restrict__ hp,
                                    const int* __restrict__ csr_eid,
                                    const int* __restrict__ rowstart, const int* __restrict__ rowcnt,
                                    const float* __restrict__ dinv,
                                    const int* __restrict__ esrc, const float* __restrict__ eatt,
                                    const int* __restrict__ nid,
                                    const float* __restrict__ bp,
                                    float* __restrict__ sc, int n) {
    int node = blockIdx.x * blockDim.x + threadIdx.x;
    if (node >= n) return;
    float di = dinv[node];
    int st = rowstart[node], cn = rowcnt[node];
    float acc = hp[node] * di * di + bp[0];
    for (int j = 0; j < cn; ++j) {
        int eid = csr_eid[st + j];
        int s = esrc[eid];
        if (nid) s = nid[s];
        acc += di * eatt[eid] * dinv[s] * hp[s];
    }
    sc[node] = acc;
}

// Exact jax.lax.top_k order: rank = #(s[j] > s[i]) + #(s[j]==s[i] && j<i).
template <int NPG, int K>
__global__ void pool_rank_kernel(const float* __restrict__ score, int* __restrict__ newid,
                                 int* __restrict__ perm, float* __restrict__ gate) {
    __shared__ float s[NPG];
    int g = blockIdx.x, base = g * NPG;
    for (int i = threadIdx.x; i < NPG; i += blockDim.x) s[i] = score[base + i];
    __syncthreads();
    for (int i = threadIdx.x; i < NPG; i += blockDim.x) {
        float si = s[i];
        int rank = 0;
        for (int j = 0; j < NPG; ++j) {
            float sj = s[j];
            rank += (sj > si) || (sj == si && j < i);
        }
        if (rank < K) {
            newid[base + i]    = g * K + rank;
            perm[g * K + rank] = base + i;
            gate[g * K + rank] = tanhf(si);
        } else {
            newid[base + i] = -1;
        }
    }
}

// xn[j,:] = h[perm[j],:] * gate[j]
__global__ void gather_pool_kernel(const float* __restrict__ h, const int* __restrict__ perm,
                                   const float* __restrict__ gate, float* __restrict__ xn, int np) {
    int lane = threadIdx.x & 63;
    int wid  = (blockIdx.x * blockDim.x + threadIdx.x) >> 6;
    int nw   = (gridDim.x * blockDim.x) >> 6;
    for (int j = wid; j < np; j += nw) {
        int node = perm[j];
        float gt = gate[j];
        xn[(size_t)j * 64 + lane] = h[(size_t)node * 64 + lane] * gt;
    }
}

// [max || mean] per graph over K contiguous nodes
template <int K>
__global__ void readout_kernel(const float* __restrict__ xn, float* __restrict__ out) {
    int g = blockIdx.x;
    int c = threadIdx.x & 63;
    int q = threadIdx.x >> 6;               // 0..3
    float mx = -3.402823466e+38f, sm = 0.f;
    for (int j = q; j < K; j += 4) {
        float v = xn[((size_t)g * K + j) * 64 + c];
        mx = fmaxf(mx, v);
        sm += v;
    }
    __shared__ float smx[4][64], ssm[4][64];
    smx[q][c] = mx; ssm[q][c] = sm;
    __syncthreads();
    if (q == 0) {
#pragma unroll
        for (int t = 1; t < 4; ++t) { mx = fmaxf(mx, smx[t][c]); sm += ssm[t][c]; }
        out[g * 128 + c]      = mx;
        out[g * 128 + 64 + c] = sm * (1.f / K);
    }
}

__global__ void combine_kernel(const float* __restrict__ a, const float* __restrict__ b,
                               float* __restrict__ out, int n) {
    int i = blockIdx.x * blockDim.x + threadIdx.x;
    if (i < n) out[i] = 0.5f * (a[i] + b[i]);
}

extern "C" void kernel_launch(void* const* d_in, const int* in_sizes, int n_in,
                              void* d_out, int out_size, void* d_ws, size_t ws_size,
                              hipStream_t stream) {
    const float* x    = (const float*)d_in[0];
    const float* eatt = (const float*)d_in[1];
    const float* W1   = (const float*)d_in[2];
    const float* b1   = (const float*)d_in[3];
    const float* Wp1  = (const float*)d_in[4];
    const float* bp1  = (const float*)d_in[5];
    const float* W2   = (const float*)d_in[6];
    const float* b2   = (const float*)d_in[7];
    const float* Wp2  = (const float*)d_in[8];
    const float* bp2  = (const float*)d_in[9];
    const int*   esrc = (const int*)d_in[10];
    const int*   edst = (const int*)d_in[11];
    float* out = (float*)d_out;

    // workspace layout (~79 MB of floats); A/B regions reused across stages
    float* ws = (float*)d_ws;
    size_t o = 0;
    float* A    = ws + o; o += (size_t)N0 * 64;   // hx1 -> {xn1 | hx2} -> xn2
    float* Bb   = ws + o; o += (size_t)N0 * 64;   // h1  -> h2
    int*   ceid = (int*)(ws + o); o += NE;        // CSR edge ids (rebuilt per stage)
    int*   rst  = (int*)(ws + o); o += N0;
    int*   rcn  = (int*)(ws + o); o += N0;
    float* dinv = ws + o; o += N0;
    float* hp   = ws + o; o += N0;
    float* sc   = ws + o; o += N0;
    int*   nid1 = (int*)(ws + o); o += N0;
    int*   nid2 = (int*)(ws + o); o += N1_;
    int*   pm1  = (int*)(ws + o); o += N1_;
    float* gt1  = ws + o; o += N1_;
    int*   pm2  = (int*)(ws + o); o += N2_;
    float* gt2  = ws + o; o += N2_;
    float* x1r  = ws + o; o += BG * 128;
    float* x2r  = ws + o; o += BG * 128;

    float* hx1 = A;
    float* h1  = Bb;
    float* xn1 = A;                        // after hx1 dead (first N1_*64)
    float* hx2 = A + (size_t)N1_ * 64;     // coexists with xn1
    float* h2  = Bb;                       // after h1 dead
    float* xn2 = A;                        // after xn1/mm64 consumers done

    const int TB = 256;
    // ---- stage 1 ----
    csr_build_kernel<NN><<<BG, TB, 0, stream>>>(esrc, edst, eatt, nullptr, ceid, rst, rcn, dinv);
    mm64_kernel<<<1024, TB, 0, stream>>>(x, W1, hx1, N0);
    gather_feat_kernel<<<(N0 * 64 + TB - 1) / TB, TB, 0, stream>>>(hx1, ceid, rst, rcn, dinv,
                                                                   esrc, eatt, nullptr, b1, h1, N0);
    mv64_kernel<<<1024, TB, 0, stream>>>(h1, Wp1, hp, N0);
    gather_score_kernel<<<(N0 + TB - 1) / TB, TB, 0, stream>>>(hp, ceid, rst, rcn, dinv,
                                                               esrc, eatt, nullptr, bp1, sc, N0);
    pool_rank_kernel<NN, K1><<<BG, TB, 0, stream>>>(sc, nid1, pm1, gt1);
    gather_pool_kernel<<<512, TB, 0, stream>>>(h1, pm1, gt1, xn1, N1_);
    readout_kernel<K1><<<BG, TB, 0, stream>>>(xn1, x1r);
    // ---- stage 2 ----
    csr_build_kernel<K1><<<BG, TB, 0, stream>>>(esrc, edst, eatt, nid1, ceid, rst, rcn, dinv);
    mm64_kernel<<<1024, TB, 0, stream>>>(xn1, W2, hx2, N1_);
    gather_feat_kernel<<<(N1_ * 64 + TB - 1) / TB, TB, 0, stream>>>(hx2, ceid, rst, rcn, dinv,
                                                                    esrc, eatt, nid1, b2, h2, N1_);
    mv64_kernel<<<512, TB, 0, stream>>>(h2, Wp2, hp, N1_);
    gather_score_kernel<<<(N1_ + TB - 1) / TB, TB, 0, stream>>>(hp, ceid, rst, rcn, dinv,
                                                                esrc, eatt, nid1, bp2, sc, N1_);
    pool_rank_kernel<K1, K2><<<BG, TB, 0, stream>>>(sc, nid2, pm2, gt2);
    gather_pool_kernel<<<512, TB, 0, stream>>>(h2, pm2, gt2, xn2, N2_);
    readout_kernel<K2><<<BG, TB, 0, stream>>>(xn2, x2r);
    // ---- final ----
    combine_kernel<<<(BG * 128 + TB - 1) / TB, TB, 0, stream>>>(x1r, x2r, out, BG * 128);
}

// Round 3
// 447.126 us; speedup vs baseline: 2.6984x; 1.4478x over previous
//
#include <hip/hip_runtime.h>
#include <math.h>

#define BG   256                   // graphs
#define NN   512                   // nodes per graph
#define EPG  (NN * 16)             // 8192 edges per graph
#define NE   (BG * EPG)            // 2097152 edges
#define N0   (BG * NN)             // 131072
#define K1   256
#define N1_  (BG * K1)             // 65536
#define K2   128
#define N2_  (BG * K2)             // 32768

// ---------------- Y[n,64] = X[n,64] @ W[64,64] ----------------
__global__ void mm64_kernel(const float* __restrict__ X, const float* __restrict__ W,
                            float* __restrict__ Y, int nrows) {
    int lane = threadIdx.x & 63;
    int wid  = (blockIdx.x * blockDim.x + threadIdx.x) >> 6;
    int nw   = (gridDim.x * blockDim.x) >> 6;
    float wcol[64];                         // column `lane` of W
#pragma unroll
    for (int k = 0; k < 64; ++k) wcol[k] = W[k * 64 + lane];
    for (int r = wid; r < nrows; r += nw) {
        float xv  = X[(size_t)r * 64 + lane];
        float acc = 0.f;
#pragma unroll
        for (int k = 0; k < 64; ++k) {
            float b = __shfl(xv, k, 64);
            acc = fmaf(b, wcol[k], acc);
        }
        Y[(size_t)r * 64 + lane] = acc;
    }
}

// ---- block-per-graph CSR build (by dst): counts, scan, dinv, (src,coef) pairs ----
// nid==nullptr: stage 1 identity. nid!=nullptr: stage-2 remap; edges with a
// dropped endpoint are excluded (== ew 0 in the reference).
template <int NPG>
__global__ __launch_bounds__(256)
void csr_build_kernel(const int* __restrict__ esrc, const int* __restrict__ edst,
                      const float* __restrict__ eatt, const int* __restrict__ nid,
                      int2* __restrict__ pairs, int* __restrict__ rowstart,
                      int* __restrict__ rowcnt, float* __restrict__ dinv) {
    __shared__ int   cnt[NPG];
    __shared__ float wsum[NPG];
    __shared__ int   scn[NPG];
    __shared__ float sdinv[NPG];
    constexpr int ITEMS = NPG / 256;
    int g = blockIdx.x;
    int e0 = g * EPG, nbase = g * NPG;
#pragma unroll
    for (int t = 0; t < ITEMS; ++t) { int i = threadIdx.x + t * 256; cnt[i] = 0; wsum[i] = 0.f; }
    __syncthreads();
    for (int e = e0 + threadIdx.x; e < e0 + EPG; e += 256) {
        int d = edst[e];
        int dl; bool valid;
        if (nid) {
            int dn = nid[d], sn = nid[esrc[e]];
            valid = (dn >= 0) && (sn >= 0);
            dl = dn - nbase;
        } else { valid = true; dl = d - nbase; }
        if (valid) {
            atomicAdd(&cnt[dl], 1);
            atomicAdd(&wsum[dl], eatt[e]);
        }
    }
    __syncthreads();
#pragma unroll
    for (int t = 0; t < ITEMS; ++t) { int i = threadIdx.x + t * 256; scn[i] = cnt[i]; }
    __syncthreads();
    for (int off = 1; off < NPG; off <<= 1) {
        int v[ITEMS];
#pragma unroll
        for (int t = 0; t < ITEMS; ++t) { int i = threadIdx.x + t * 256; v[t] = (i >= off) ? scn[i - off] : 0; }
        __syncthreads();
#pragma unroll
        for (int t = 0; t < ITEMS; ++t) { int i = threadIdx.x + t * 256; scn[i] += v[t]; }
        __syncthreads();
    }
#pragma unroll
    for (int t = 0; t < ITEMS; ++t) {
        int i  = threadIdx.x + t * 256;
        int st = scn[i] - cnt[i];            // exclusive scan
        rowstart[nbase + i] = e0 + st;
        rowcnt[nbase + i]   = cnt[i];
        float di = rsqrtf(wsum[i] + 1.0f);
        dinv[nbase + i] = di;
        sdinv[i] = di;
        scn[i] = st;                          // running slot offset
    }
    __syncthreads();
    for (int e = e0 + threadIdx.x; e < e0 + EPG; e += 256) {
        int d = edst[e], s = esrc[e];
        int dl, sl, snew; bool valid;
        if (nid) {
            int dn = nid[d], sn = nid[s];
            valid = (dn >= 0) && (sn >= 0);
            dl = dn - nbase; sl = sn - nbase; snew = dn >= 0 ? sn : 0;
        } else { valid = true; dl = d - nbase; sl = s - nbase; snew = s; }
        if (valid) {
            float coef = sdinv[dl] * eatt[e] * sdinv[sl];
            int slot = e0 + atomicAdd(&scn[dl], 1);
            pairs[slot] = make_int2(snew, __float_as_int(coef));
        }
    }
}

// ---- gather conv: wave = 4 nodes x 16 lanes (float4 feats); fused self+bias,
// relu, and hp = relu(h) . Wp. XCD-swizzled so one graph stays on one XCD. ----
template <int NPG>
__global__ __launch_bounds__(256)
void gather_feat_kernel(const float4* __restrict__ hx4, const int2* __restrict__ pairs,
                        const int* __restrict__ rowstart, const int* __restrict__ rowcnt,
                        const float* __restrict__ dinv, const float4* __restrict__ b4,
                        const float4* __restrict__ wp4, float* __restrict__ hp,
                        float4* __restrict__ out4) {
    constexpr int BPG = NPG / 16;           // blocks per graph
    int i   = blockIdx.x;
    int xcd = i & 7;
    int k   = i >> 3;
    int g     = xcd * (BG / 8) + k / BPG;   // all BPG blocks of graph g on one XCD
    int chunk = k % BPG;
    int lane16 = threadIdx.x & 15;
    int sub    = (threadIdx.x >> 4) & 3;
    int wv     = threadIdx.x >> 6;
    int lanebase = (threadIdx.x & 63) & 48; // sub*16
    int node = g * NPG + chunk * 16 + wv * 4 + sub;

    float di = dinv[node];
    int st = rowstart[node], cn = rowcnt[node];
    float4 acc = hx4[(size_t)node * 16 + lane16];
    float dii = di * di;
    float4 bb = b4[lane16];
    acc.x = fmaf(acc.x, dii, bb.x);
    acc.y = fmaf(acc.y, dii, bb.y);
    acc.z = fmaf(acc.z, dii, bb.z);
    acc.w = fmaf(acc.w, dii, bb.w);

    for (int eb = 0; eb < cn; eb += 16) {
        int m = cn - eb; if (m > 16) m = 16;
        int2 pr = make_int2(0, 0);
        if (lane16 < m) pr = pairs[st + eb + lane16];
        int   s_cur = __shfl(pr.x, lanebase, 64);
        float c_cur = __int_as_float(__shfl(pr.y, lanebase, 64));
        float4 v_cur = hx4[(size_t)s_cur * 16 + lane16];
        for (int j = 0; j < m; ++j) {
            int s_n = s_cur; float c_n = 0.f; float4 v_n = v_cur;
            if (j + 1 < m) {
                s_n = __shfl(pr.x, lanebase + j + 1, 64);
                c_n = __int_as_float(__shfl(pr.y, lanebase + j + 1, 64));
                v_n = hx4[(size_t)s_n * 16 + lane16];     // prefetch next neighbor row
            }
            acc.x = fmaf(c_cur, v_cur.x, acc.x);
            acc.y = fmaf(c_cur, v_cur.y, acc.y);
            acc.z = fmaf(c_cur, v_cur.z, acc.z);
            acc.w = fmaf(c_cur, v_cur.w, acc.w);
            s_cur = s_n; c_cur = c_n; v_cur = v_n;
        }
    }
    acc.x = fmaxf(acc.x, 0.f); acc.y = fmaxf(acc.y, 0.f);
    acc.z = fmaxf(acc.z, 0.f); acc.w = fmaxf(acc.w, 0.f);
    out4[(size_t)node * 16 + lane16] = acc;
    // fused hp = h . Wp (group reduction over 16 lanes)
    float4 w4 = wp4[lane16];
    float t = acc.x * w4.x + acc.y * w4.y + acc.z * w4.z + acc.w * w4.w;
    t += __shfl_xor(t, 1, 64); t += __shfl_xor(t, 2, 64);
    t += __shfl_xor(t, 4, 64); t += __shfl_xor(t, 8, 64);
    if (lane16 == 0) hp[node] = t;
}

// ---- score conv: wave = 4 nodes x 16 lanes; lane-parallel edge sum ----
__global__ __launch_bounds__(256)
void gather_score_kernel(const float* __restrict__ hp, const int2* __restrict__ pairs,
                         const int* __restrict__ rowstart, const int* __restrict__ rowcnt,
                         const float* __restrict__ dinv, const float* __restrict__ bp,
                         float* __restrict__ sc, int n) {
    int lane16 = threadIdx.x & 15;
    int sub    = (threadIdx.x >> 4) & 3;
    int wave   = (blockIdx.x * blockDim.x + threadIdx.x) >> 6;
    int node   = wave * 4 + sub;
    if (node >= n) return;
    int st = rowstart[node], cn = rowcnt[node];
    float part = 0.f;
    for (int eb = 0; eb < cn; eb += 16) {
        int m = cn - eb; if (m > 16) m = 16;
        if (lane16 < m) {
            int2 pr = pairs[st + eb + lane16];
            part += __int_as_float(pr.y) * hp[pr.x];
        }
    }
    part += __shfl_xor(part, 1, 64); part += __shfl_xor(part, 2, 64);
    part += __shfl_xor(part, 4, 64); part += __shfl_xor(part, 8, 64);
    if (lane16 == 0) {
        float di = dinv[node];
        sc[node] = fmaf(hp[node], di * di, bp[0]) + part;
    }
}

// ---- fused pool: exact top-k rank + nid + gated gather + [gmp||gap] readout ----
// rank = #(s[j] > s[i]) + #(s[j]==s[i] && j<i)  (exact jax.lax.top_k order)
template <int NPG, int K>
__global__ __launch_bounds__(256)
void pool_fused_kernel(const float* __restrict__ score, const float4* __restrict__ h4,
                       int* __restrict__ nid, float4* __restrict__ xn4,
                       float* __restrict__ xr) {
    __shared__ float  s[NPG];
    __shared__ int    lperm[K];
    __shared__ float  lgate[K];
    __shared__ float4 smx[16][16];
    __shared__ float4 ssm[16][16];
    int g = blockIdx.x, base = g * NPG;
    for (int i = threadIdx.x; i < NPG; i += 256) s[i] = score[base + i];
    __syncthreads();
    for (int i = threadIdx.x; i < NPG; i += 256) {
        float si = s[i];
        int rank = 0;
        for (int j = 0; j < NPG; ++j) {
            float sj = s[j];
            rank += (sj > si) || (sj == si && j < i);
        }
        if (rank < K) {
            nid[base + i] = g * K + rank;
            lperm[rank]   = i;
            lgate[rank]   = tanhf(si);
        } else {
            nid[base + i] = -1;
        }
    }
    __syncthreads();
    int q16 = threadIdx.x & 15;
    int jg  = threadIdx.x >> 4;
    float4 mx = make_float4(-3.402823466e38f, -3.402823466e38f, -3.402823466e38f, -3.402823466e38f);
    float4 sm = make_float4(0.f, 0.f, 0.f, 0.f);
    for (int j = jg; j < K; j += 16) {
        float gt = lgate[j];
        float4 v = h4[(size_t)(base + lperm[j]) * 16 + q16];
        v.x *= gt; v.y *= gt; v.z *= gt; v.w *= gt;
        xn4[((size_t)g * K + j) * 16 + q16] = v;
        mx.x = fmaxf(mx.x, v.x); mx.y = fmaxf(mx.y, v.y);
        mx.z = fmaxf(mx.z, v.z); mx.w = fmaxf(mx.w, v.w);
        sm.x += v.x; sm.y += v.y; sm.z += v.z; sm.w += v.w;
    }
    smx[jg][q16] = mx; ssm[jg][q16] = sm;
    __syncthreads();
    if (jg == 0) {
#pragma unroll
        for (int t = 1; t < 16; ++t) {
            float4 a = smx[t][q16], b = ssm[t][q16];
            mx.x = fmaxf(mx.x, a.x); mx.y = fmaxf(mx.y, a.y);
            mx.z = fmaxf(mx.z, a.z); mx.w = fmaxf(mx.w, a.w);
            sm.x += b.x; sm.y += b.y; sm.z += b.z; sm.w += b.w;
        }
        float invK = 1.f / K;
        int c = q16 * 4;
        xr[g * 128 + c + 0] = mx.x; xr[g * 128 + c + 1] = mx.y;
        xr[g * 128 + c + 2] = mx.z; xr[g * 128 + c + 3] = mx.w;
        xr[g * 128 + 64 + c + 0] = sm.x * invK; xr[g * 128 + 64 + c + 1] = sm.y * invK;
        xr[g * 128 + 64 + c + 2] = sm.z * invK; xr[g * 128 + 64 + c + 3] = sm.w * invK;
    }
}

__global__ void combine_kernel(const float* __restrict__ a, const float* __restrict__ b,
                               float* __restrict__ out, int n) {
    int i = blockIdx.x * blockDim.x + threadIdx.x;
    if (i < n) out[i] = 0.5f * (a[i] + b[i]);
}

extern "C" void kernel_launch(void* const* d_in, const int* in_sizes, int n_in,
                              void* d_out, int out_size, void* d_ws, size_t ws_size,
                              hipStream_t stream) {
    const float* x    = (const float*)d_in[0];
    const float* eatt = (const float*)d_in[1];
    const float* W1   = (const float*)d_in[2];
    const float* b1   = (const float*)d_in[3];
    const float* Wp1  = (const float*)d_in[4];
    const float* bp1  = (const float*)d_in[5];
    const float* W2   = (const float*)d_in[6];
    const float* b2   = (const float*)d_in[7];
    const float* Wp2  = (const float*)d_in[8];
    const float* bp2  = (const float*)d_in[9];
    const int*   esrc = (const int*)d_in[10];
    const int*   edst = (const int*)d_in[11];
    float* out = (float*)d_out;

    // workspace (~87 MB of floats); A/B regions reused across stages
    float* ws = (float*)d_ws;
    size_t o = 0;
    float* A    = ws + o; o += (size_t)N0 * 64;   // hx1 -> {xn1 | hx2} -> xn2
    float* Bb   = ws + o; o += (size_t)N0 * 64;   // h1 -> h2
    int2*  prs  = (int2*)(ws + o); o += (size_t)NE * 2;  // (src,coef) per CSR slot
    int*   rst  = (int*)(ws + o); o += N0;
    int*   rcn  = (int*)(ws + o); o += N0;
    float* dinv = ws + o; o += N0;
    float* hp   = ws + o; o += N0;
    float* sc   = ws + o; o += N0;
    int*   nid  = (int*)(ws + o); o += N0;        // nid1; reused as nid2 after csr2
    float* x1r  = ws + o; o += BG * 128;
    float* x2r  = ws + o; o += BG * 128;

    float* hx1 = A;
    float* h1  = Bb;
    float* xn1 = A;                        // after hx1 dead
    float* hx2 = A + (size_t)N1_ * 64;
    float* h2  = Bb;                       // after h1 dead
    float* xn2 = A;                        // after xn1 dead

    const int TB = 256;
    // ---- stage 1 ----
    csr_build_kernel<NN><<<BG, TB, 0, stream>>>(esrc, edst, eatt, nullptr, prs, rst, rcn, dinv);
    mm64_kernel<<<1024, TB, 0, stream>>>(x, W1, hx1, N0);
    gather_feat_kernel<NN><<<BG * (NN / 16), TB, 0, stream>>>(
        (const float4*)hx1, prs, rst, rcn, dinv, (const float4*)b1, (const float4*)Wp1, hp, (float4*)h1);
    gather_score_kernel<<<N0 / 16, TB, 0, stream>>>(hp, prs, rst, rcn, dinv, bp1, sc, N0);
    pool_fused_kernel<NN, K1><<<BG, TB, 0, stream>>>(sc, (const float4*)h1, nid, (float4*)xn1, x1r);
    // ---- stage 2 ----
    csr_build_kernel<K1><<<BG, TB, 0, stream>>>(esrc, edst, eatt, nid, prs, rst, rcn, dinv);
    mm64_kernel<<<1024, TB, 0, stream>>>(xn1, W2, hx2, N1_);
    gather_feat_kernel<K1><<<BG * (K1 / 16), TB, 0, stream>>>(
        (const float4*)hx2, prs, rst, rcn, dinv, (const float4*)b2, (const float4*)Wp2, hp, (float4*)h2);
    gather_score_kernel<<<N1_ / 16, TB, 0, stream>>>(hp, prs, rst, rcn, dinv, bp2, sc, N1_);
    pool_fused_kernel<K1, K2><<<BG, TB, 0, stream>>>(sc, (const float4*)h2, nid, (float4*)xn2, x2r);
    // ---- final ----
    combine_kernel<<<(BG * 128 + TB - 1) / TB, TB, 0, stream>>>(x1r, x2r, out, BG * 128);
}

// Round 4
// 386.277 us; speedup vs baseline: 3.1235x; 1.1575x over previous
//
#include <hip/hip_runtime.h>
#include <math.h>

#define BG   256                   // graphs
#define NN   512                   // nodes per graph
#define EPG  (NN * 16)             // 8192 edges per graph
#define NE   (BG * EPG)            // 2097152 edges
#define N0   (BG * NN)             // 131072
#define K1   256
#define N1_  (BG * K1)             // 65536
#define K2   128
#define N2_  (BG * K2)             // 32768

// ---------------- Y[n,64] = X[n,64] @ W[64,64] ----------------
// Wave-uniform row trick: x[r][k] is identical across the wave's 64 lanes, so
// read it through a readfirstlane'd (SGPR) address — no shuffles, no LDS.
// Lane c keeps W[:,c] in 64 VGPRs; per row: 16 uniform float4 loads + 64 FMA.
__global__ __launch_bounds__(256)
void mm64_kernel(const float* __restrict__ X, const float* __restrict__ W,
                 float* __restrict__ Y, int nrows) {
    int lane = threadIdx.x & 63;
    int wid  = (blockIdx.x * blockDim.x + threadIdx.x) >> 6;
    int nw   = (gridDim.x * blockDim.x) >> 6;
    float wcol[64];                         // column `lane` of W
#pragma unroll
    for (int k = 0; k < 64; ++k) wcol[k] = W[k * 64 + lane];
    for (int r = wid; r < nrows; r += nw) {
        int rb = __builtin_amdgcn_readfirstlane(r);
        const float4* xr = (const float4*)(X + (size_t)rb * 64);
        float acc = 0.f;
#pragma unroll
        for (int kq = 0; kq < 16; ++kq) {
            float4 xv = xr[kq];             // uniform address -> scalar/broadcast load
            acc = fmaf(xv.x, wcol[4 * kq + 0], acc);
            acc = fmaf(xv.y, wcol[4 * kq + 1], acc);
            acc = fmaf(xv.z, wcol[4 * kq + 2], acc);
            acc = fmaf(xv.w, wcol[4 * kq + 3], acc);
        }
        Y[(size_t)r * 64 + lane] = acc;
    }
}

// ---- block-per-graph CSR build (by dst): counts, scan, dinv, (src,coef) pairs ----
// nid==nullptr: stage 1 identity. nid!=nullptr: stage-2 remap; edges with a
// dropped endpoint are excluded (== ew 0 in the reference).
template <int NPG>
__global__ __launch_bounds__(256)
void csr_build_kernel(const int* __restrict__ esrc, const int* __restrict__ edst,
                      const float* __restrict__ eatt, const int* __restrict__ nid,
                      int2* __restrict__ pairs, int* __restrict__ rowstart,
                      int* __restrict__ rowcnt, float* __restrict__ dinv) {
    __shared__ int   cnt[NPG];
    __shared__ float wsum[NPG];
    __shared__ int   scn[NPG];
    __shared__ float sdinv[NPG];
    constexpr int ITEMS = NPG / 256;
    int g = blockIdx.x;
    int e0 = g * EPG, nbase = g * NPG;
#pragma unroll
    for (int t = 0; t < ITEMS; ++t) { int i = threadIdx.x + t * 256; cnt[i] = 0; wsum[i] = 0.f; }
    __syncthreads();
    for (int e = e0 + threadIdx.x; e < e0 + EPG; e += 256) {
        int d = edst[e];
        int dl; bool valid;
        if (nid) {
            int dn = nid[d], sn = nid[esrc[e]];
            valid = (dn >= 0) && (sn >= 0);
            dl = dn - nbase;
        } else { valid = true; dl = d - nbase; }
        if (valid) {
            atomicAdd(&cnt[dl], 1);
            atomicAdd(&wsum[dl], eatt[e]);
        }
    }
    __syncthreads();
#pragma unroll
    for (int t = 0; t < ITEMS; ++t) { int i = threadIdx.x + t * 256; scn[i] = cnt[i]; }
    __syncthreads();
    for (int off = 1; off < NPG; off <<= 1) {
        int v[ITEMS];
#pragma unroll
        for (int t = 0; t < ITEMS; ++t) { int i = threadIdx.x + t * 256; v[t] = (i >= off) ? scn[i - off] : 0; }
        __syncthreads();
#pragma unroll
        for (int t = 0; t < ITEMS; ++t) { int i = threadIdx.x + t * 256; scn[i] += v[t]; }
        __syncthreads();
    }
#pragma unroll
    for (int t = 0; t < ITEMS; ++t) {
        int i  = threadIdx.x + t * 256;
        int st = scn[i] - cnt[i];            // exclusive scan
        rowstart[nbase + i] = e0 + st;
        rowcnt[nbase + i]   = cnt[i];
        float di = rsqrtf(wsum[i] + 1.0f);
        dinv[nbase + i] = di;
        sdinv[i] = di;
        scn[i] = st;                          // running slot offset
    }
    __syncthreads();
    for (int e = e0 + threadIdx.x; e < e0 + EPG; e += 256) {
        int d = edst[e], s = esrc[e];
        int dl, sl, snew; bool valid;
        if (nid) {
            int dn = nid[d], sn = nid[s];
            valid = (dn >= 0) && (sn >= 0);
            dl = dn - nbase; sl = sn - nbase; snew = dn >= 0 ? sn : 0;
        } else { valid = true; dl = d - nbase; sl = s - nbase; snew = s; }
        if (valid) {
            float coef = sdinv[dl] * eatt[e] * sdinv[sl];
            int slot = e0 + atomicAdd(&scn[dl], 1);
            pairs[slot] = make_int2(snew, __float_as_int(coef));
        }
    }
}

// ---- gather conv: wave = 4 nodes x 16 lanes (float4 feats); fused self+bias,
// relu, and hp = relu(h) . Wp. XCD-swizzled so one graph stays on one XCD. ----
template <int NPG>
__global__ __launch_bounds__(256)
void gather_feat_kernel(const float4* __restrict__ hx4, const int2* __restrict__ pairs,
                        const int* __restrict__ rowstart, const int* __restrict__ rowcnt,
                        const float* __restrict__ dinv, const float4* __restrict__ b4,
                        const float4* __restrict__ wp4, float* __restrict__ hp,
                        float4* __restrict__ out4) {
    constexpr int BPG = NPG / 16;           // blocks per graph
    int i   = blockIdx.x;
    int xcd = i & 7;
    int k   = i >> 3;
    int g     = xcd * (BG / 8) + k / BPG;   // all BPG blocks of graph g on one XCD
    int chunk = k % BPG;
    int lane16 = threadIdx.x & 15;
    int sub    = (threadIdx.x >> 4) & 3;
    int wv     = threadIdx.x >> 6;
    int lanebase = (threadIdx.x & 63) & 48; // sub*16
    int node = g * NPG + chunk * 16 + wv * 4 + sub;

    float di = dinv[node];
    int st = rowstart[node], cn = rowcnt[node];
    float4 acc = hx4[(size_t)node * 16 + lane16];
    float dii = di * di;
    float4 bb = b4[lane16];
    acc.x = fmaf(acc.x, dii, bb.x);
    acc.y = fmaf(acc.y, dii, bb.y);
    acc.z = fmaf(acc.z, dii, bb.z);
    acc.w = fmaf(acc.w, dii, bb.w);

    for (int eb = 0; eb < cn; eb += 16) {
        int m = cn - eb; if (m > 16) m = 16;
        int2 pr = make_int2(0, 0);
        if (lane16 < m) pr = pairs[st + eb + lane16];
        int   s_cur = __shfl(pr.x, lanebase, 64);
        float c_cur = __int_as_float(__shfl(pr.y, lanebase, 64));
        float4 v_cur = hx4[(size_t)s_cur * 16 + lane16];
        for (int j = 0; j < m; ++j) {
            int s_n = s_cur; float c_n = 0.f; float4 v_n = v_cur;
            if (j + 1 < m) {
                s_n = __shfl(pr.x, lanebase + j + 1, 64);
                c_n = __int_as_float(__shfl(pr.y, lanebase + j + 1, 64));
                v_n = hx4[(size_t)s_n * 16 + lane16];     // prefetch next neighbor row
            }
            acc.x = fmaf(c_cur, v_cur.x, acc.x);
            acc.y = fmaf(c_cur, v_cur.y, acc.y);
            acc.z = fmaf(c_cur, v_cur.z, acc.z);
            acc.w = fmaf(c_cur, v_cur.w, acc.w);
            s_cur = s_n; c_cur = c_n; v_cur = v_n;
        }
    }
    acc.x = fmaxf(acc.x, 0.f); acc.y = fmaxf(acc.y, 0.f);
    acc.z = fmaxf(acc.z, 0.f); acc.w = fmaxf(acc.w, 0.f);
    out4[(size_t)node * 16 + lane16] = acc;
    // fused hp = h . Wp (group reduction over 16 lanes)
    float4 w4 = wp4[lane16];
    float t = acc.x * w4.x + acc.y * w4.y + acc.z * w4.z + acc.w * w4.w;
    t += __shfl_xor(t, 1, 64); t += __shfl_xor(t, 2, 64);
    t += __shfl_xor(t, 4, 64); t += __shfl_xor(t, 8, 64);
    if (lane16 == 0) hp[node] = t;
}

// ---- score conv: wave = 4 nodes x 16 lanes; lane-parallel edge sum ----
__global__ __launch_bounds__(256)
void gather_score_kernel(const float* __restrict__ hp, const int2* __restrict__ pairs,
                         const int* __restrict__ rowstart, const int* __restrict__ rowcnt,
                         const float* __restrict__ dinv, const float* __restrict__ bp,
                         float* __restrict__ sc, int n) {
    int lane16 = threadIdx.x & 15;
    int sub    = (threadIdx.x >> 4) & 3;
    int wave   = (blockIdx.x * blockDim.x + threadIdx.x) >> 6;
    int node   = wave * 4 + sub;
    if (node >= n) return;
    int st = rowstart[node], cn = rowcnt[node];
    float part = 0.f;
    for (int eb = 0; eb < cn; eb += 16) {
        int m = cn - eb; if (m > 16) m = 16;
        if (lane16 < m) {
            int2 pr = pairs[st + eb + lane16];
            part += __int_as_float(pr.y) * hp[pr.x];
        }
    }
    part += __shfl_xor(part, 1, 64); part += __shfl_xor(part, 2, 64);
    part += __shfl_xor(part, 4, 64); part += __shfl_xor(part, 8, 64);
    if (lane16 == 0) {
        float di = dinv[node];
        sc[node] = fmaf(hp[node], di * di, bp[0]) + part;
    }
}

// ---- fused pool: exact top-k rank + nid + gated gather + [gmp||gap] readout ----
// rank = #(s[j] > s[i]) + #(s[j]==s[i] && j<i)  (exact jax.lax.top_k order)
template <int NPG, int K>
__global__ __launch_bounds__(256)
void pool_fused_kernel(const float* __restrict__ score, const float4* __restrict__ h4,
                       int* __restrict__ nid, float4* __restrict__ xn4,
                       float* __restrict__ xr) {
    __shared__ float  s[NPG];
    __shared__ int    lperm[K];
    __shared__ float  lgate[K];
    __shared__ float4 smx[16][16];
    __shared__ float4 ssm[16][16];
    int g = blockIdx.x, base = g * NPG;
    for (int i = threadIdx.x; i < NPG; i += 256) s[i] = score[base + i];
    __syncthreads();
    for (int i = threadIdx.x; i < NPG; i += 256) {
        float si = s[i];
        int rank = 0;
        for (int j = 0; j < NPG; ++j) {
            float sj = s[j];
            rank += (sj > si) || (sj == si && j < i);
        }
        if (rank < K) {
            nid[base + i] = g * K + rank;
            lperm[rank]   = i;
            lgate[rank]   = tanhf(si);
        } else {
            nid[base + i] = -1;
        }
    }
    __syncthreads();
    int q16 = threadIdx.x & 15;
    int jg  = threadIdx.x >> 4;
    float4 mx = make_float4(-3.402823466e38f, -3.402823466e38f, -3.402823466e38f, -3.402823466e38f);
    float4 sm = make_float4(0.f, 0.f, 0.f, 0.f);
    for (int j = jg; j < K; j += 16) {
        float gt = lgate[j];
        float4 v = h4[(size_t)(base + lperm[j]) * 16 + q16];
        v.x *= gt; v.y *= gt; v.z *= gt; v.w *= gt;
        xn4[((size_t)g * K + j) * 16 + q16] = v;
        mx.x = fmaxf(mx.x, v.x); mx.y = fmaxf(mx.y, v.y);
        mx.z = fmaxf(mx.z, v.z); mx.w = fmaxf(mx.w, v.w);
        sm.x += v.x; sm.y += v.y; sm.z += v.z; sm.w += v.w;
    }
    smx[jg][q16] = mx; ssm[jg][q16] = sm;
    __syncthreads();
    if (jg == 0) {
#pragma unroll
        for (int t = 1; t < 16; ++t) {
            float4 a = smx[t][q16], b = ssm[t][q16];
            mx.x = fmaxf(mx.x, a.x); mx.y = fmaxf(mx.y, a.y);
            mx.z = fmaxf(mx.z, a.z); mx.w = fmaxf(mx.w, a.w);
            sm.x += b.x; sm.y += b.y; sm.z += b.z; sm.w += b.w;
        }
        float invK = 1.f / K;
        int c = q16 * 4;
        xr[g * 128 + c + 0] = mx.x; xr[g * 128 + c + 1] = mx.y;
        xr[g * 128 + c + 2] = mx.z; xr[g * 128 + c + 3] = mx.w;
        xr[g * 128 + 64 + c + 0] = sm.x * invK; xr[g * 128 + 64 + c + 1] = sm.y * invK;
        xr[g * 128 + 64 + c + 2] = sm.z * invK; xr[g * 128 + 64 + c + 3] = sm.w * invK;
    }
}

__global__ void combine_kernel(const float* __restrict__ a, const float* __restrict__ b,
                               float* __restrict__ out, int n) {
    int i = blockIdx.x * blockDim.x + threadIdx.x;
    if (i < n) out[i] = 0.5f * (a[i] + b[i]);
}

extern "C" void kernel_launch(void* const* d_in, const int* in_sizes, int n_in,
                              void* d_out, int out_size, void* d_ws, size_t ws_size,
                              hipStream_t stream) {
    const float* x    = (const float*)d_in[0];
    const float* eatt = (const float*)d_in[1];
    const float* W1   = (const float*)d_in[2];
    const float* b1   = (const float*)d_in[3];
    const float* Wp1  = (const float*)d_in[4];
    const float* bp1  = (const float*)d_in[5];
    const float* W2   = (const float*)d_in[6];
    const float* b2   = (const float*)d_in[7];
    const float* Wp2  = (const float*)d_in[8];
    const float* bp2  = (const float*)d_in[9];
    const int*   esrc = (const int*)d_in[10];
    const int*   edst = (const int*)d_in[11];
    float* out = (float*)d_out;

    // workspace (~87 MB of floats); A/B regions reused across stages
    float* ws = (float*)d_ws;
    size_t o = 0;
    float* A    = ws + o; o += (size_t)N0 * 64;   // hx1 -> {xn1 | hx2} -> xn2
    float* Bb   = ws + o; o += (size_t)N0 * 64;   // h1 -> h2
    int2*  prs  = (int2*)(ws + o); o += (size_t)NE * 2;  // (src,coef) per CSR slot
    int*   rst  = (int*)(ws + o); o += N0;
    int*   rcn  = (int*)(ws + o); o += N0;
    float* dinv = ws + o; o += N0;
    float* hp   = ws + o; o += N0;
    float* sc   = ws + o; o += N0;
    int*   nid  = (int*)(ws + o); o += N0;        // nid1; reused as nid2 after csr2
    float* x1r  = ws + o; o += BG * 128;
    float* x2r  = ws + o; o += BG * 128;

    float* hx1 = A;
    float* h1  = Bb;
    float* xn1 = A;                        // after hx1 dead
    float* hx2 = A + (size_t)N1_ * 64;
    float* h2  = Bb;                       // after h1 dead
    float* xn2 = A;                        // after xn1 dead

    const int TB = 256;
    // ---- stage 1 ----
    csr_build_kernel<NN><<<BG, TB, 0, stream>>>(esrc, edst, eatt, nullptr, prs, rst, rcn, dinv);
    mm64_kernel<<<1024, TB, 0, stream>>>(x, W1, hx1, N0);
    gather_feat_kernel<NN><<<BG * (NN / 16), TB, 0, stream>>>(
        (const float4*)hx1, prs, rst, rcn, dinv, (const float4*)b1, (const float4*)Wp1, hp, (float4*)h1);
    gather_score_kernel<<<N0 / 16, TB, 0, stream>>>(hp, prs, rst, rcn, dinv, bp1, sc, N0);
    pool_fused_kernel<NN, K1><<<BG, TB, 0, stream>>>(sc, (const float4*)h1, nid, (float4*)xn1, x1r);
    // ---- stage 2 ----
    csr_build_kernel<K1><<<BG, TB, 0, stream>>>(esrc, edst, eatt, nid, prs, rst, rcn, dinv);
    mm64_kernel<<<1024, TB, 0, stream>>>(xn1, W2, hx2, N1_);
    gather_feat_kernel<K1><<<BG * (K1 / 16), TB, 0, stream>>>(
        (const float4*)hx2, prs, rst, rcn, dinv, (const float4*)b2, (const float4*)Wp2, hp, (float4*)h2);
    gather_score_kernel<<<N1_ / 16, TB, 0, stream>>>(hp, prs, rst, rcn, dinv, bp2, sc, N1_);
    pool_fused_kernel<K1, K2><<<BG, TB, 0, stream>>>(sc, (const float4*)h2, nid, (float4*)xn2, x2r);
    // ---- final ----
    combine_kernel<<<(BG * 128 + TB - 1) / TB, TB, 0, stream>>>(x1r, x2r, out, BG * 128);
}

// Round 5
// 307.210 us; speedup vs baseline: 3.9274x; 1.2574x over previous
//
#include <hip/hip_runtime.h>
#include <math.h>

#define BG   256                   // graphs
#define NN   512                   // nodes per graph
#define EPG  (NN * 16)             // 8192 edges per graph
#define NE   (BG * EPG)            // 2097152 edges
#define N0   (BG * NN)             // 131072
#define K1   256
#define N1_  (BG * K1)             // 65536
#define K2   128
#define N2_  (BG * K2)             // 32768

__device__ __forceinline__ float4 f4fma(float s, float4 a, float4 c) {
    c.x = fmaf(s, a.x, c.x); c.y = fmaf(s, a.y, c.y);
    c.z = fmaf(s, a.z, c.z); c.w = fmaf(s, a.w, c.w);
    return c;
}

// ---- fused stage head: blocks [0,BG) build CSR (+dinv, (src,coef) pairs);
// blocks [BG, BG+mmb) run the 64x64 GEMM Y = X @ W, LDS-tiled, 4x4/thread.
// The csr blocks are latency-bound at ~1 block/CU; co-scheduling the GEMM
// blocks on the same CUs hides their stalls.
template <int NPG, bool REMAP>
__global__ __launch_bounds__(256)
void stage_head_kernel(const int* __restrict__ esrc, const int* __restrict__ edst,
                       const float* __restrict__ eatt, const int* __restrict__ nid,
                       int2* __restrict__ pairs, int* __restrict__ rowstart,
                       int* __restrict__ rowcnt, float* __restrict__ dinv,
                       const float4* __restrict__ X4, const float4* __restrict__ W4,
                       float4* __restrict__ Y4, int nrows, int mmb) {
    __shared__ __align__(16) char smem[34816];   // max(csr 8KB, 2x 64x68 f32)
    if ((int)blockIdx.x < BG) {
        // ---------------- CSR build for graph g ----------------
        int*   cnt   = (int*)smem;               // [NPG]
        float* wsum  = (float*)smem + NPG;       // [NPG]
        int*   scn   = (int*)smem + 2 * NPG;     // [NPG]
        float* sdinv = (float*)smem + 3 * NPG;   // [NPG]
        constexpr int ITEMS = NPG / 256;
        int g = blockIdx.x;
        int e0 = g * EPG, nbase = g * NPG;
        for (int i = threadIdx.x; i < NPG; i += 256) { cnt[i] = 0; wsum[i] = 0.f; }
        __syncthreads();
        const int4*   edst4 = (const int4*)(edst + e0);
        const int4*   esrc4 = (const int4*)(esrc + e0);
        const float4* eatt4 = (const float4*)(eatt + e0);
        // pass 1: counts + weighted degree (chunked int4/float4 loads for MLP)
        for (int ch = threadIdx.x; ch < EPG / 4; ch += 256) {
            int4   dd = edst4[ch];
            float4 ww = eatt4[ch];
            int4 ss = make_int4(0, 0, 0, 0);
            if (REMAP) ss = esrc4[ch];
            int   dv[4] = {dd.x, dd.y, dd.z, dd.w};
            int   sv[4] = {ss.x, ss.y, ss.z, ss.w};
            float wv[4] = {ww.x, ww.y, ww.z, ww.w};
#pragma unroll
            for (int j = 0; j < 4; ++j) {
                int dl; bool valid;
                if (REMAP) {
                    int dn = nid[dv[j]], sn = nid[sv[j]];
                    valid = (dn >= 0) && (sn >= 0);
                    dl = dn - nbase;
                } else { valid = true; dl = dv[j] - nbase; }
                if (valid) {
                    atomicAdd(&cnt[dl], 1);
                    atomicAdd(&wsum[dl], wv[j]);
                }
            }
        }
        __syncthreads();
#pragma unroll
        for (int t = 0; t < ITEMS; ++t) { int i = threadIdx.x + t * 256; scn[i] = cnt[i]; }
        __syncthreads();
        for (int off = 1; off < NPG; off <<= 1) {
            int v[ITEMS];
#pragma unroll
            for (int t = 0; t < ITEMS; ++t) { int i = threadIdx.x + t * 256; v[t] = (i >= off) ? scn[i - off] : 0; }
            __syncthreads();
#pragma unroll
            for (int t = 0; t < ITEMS; ++t) { int i = threadIdx.x + t * 256; scn[i] += v[t]; }
            __syncthreads();
        }
#pragma unroll
        for (int t = 0; t < ITEMS; ++t) {
            int i  = threadIdx.x + t * 256;
            int st = scn[i] - cnt[i];            // exclusive scan
            rowstart[nbase + i] = e0 + st;
            rowcnt[nbase + i]   = cnt[i];
            float di = rsqrtf(wsum[i] + 1.0f);
            dinv[nbase + i] = di;
            sdinv[i] = di;
            scn[i] = st;                          // running slot offset
        }
        __syncthreads();
        // pass 2: slot scatter with precomputed coef
        for (int ch = threadIdx.x; ch < EPG / 4; ch += 256) {
            int4   dd = edst4[ch];
            int4   ss = esrc4[ch];
            float4 ww = eatt4[ch];
            int   dv[4] = {dd.x, dd.y, dd.z, dd.w};
            int   sv[4] = {ss.x, ss.y, ss.z, ss.w};
            float wv[4] = {ww.x, ww.y, ww.z, ww.w};
#pragma unroll
            for (int j = 0; j < 4; ++j) {
                int dl, sl, snew; bool valid;
                if (REMAP) {
                    int dn = nid[dv[j]], sn = nid[sv[j]];
                    valid = (dn >= 0) && (sn >= 0);
                    dl = dn - nbase; sl = sn - nbase; snew = sn;
                } else { valid = true; dl = dv[j] - nbase; sl = sv[j] - nbase; snew = sv[j]; }
                if (valid) {
                    float coef = sdinv[dl] * wv[j] * sdinv[sl];
                    int slot = e0 + atomicAdd(&scn[dl], 1);
                    pairs[slot] = make_int2(snew, __float_as_int(coef));
                }
            }
        }
    } else {
        // ---------------- GEMM: Y[nrows,64] = X @ W ----------------
        float (*sX)[68] = (float (*)[68])smem;            // +4 pad: kill bank conflicts
        float (*sW)[68] = (float (*)[68])(smem + 17408);
        int mb = blockIdx.x - BG;
#pragma unroll
        for (int t = 0; t < 4; ++t) {                     // stage W once
            int idx = threadIdx.x + t * 256;
            int r = idx >> 4, c4 = idx & 15;
            *(float4*)&sW[r][c4 * 4] = W4[idx];
        }
        int ntiles = nrows >> 6;
        int rg = threadIdx.x >> 4, cg = threadIdx.x & 15;
        for (int tile = mb; tile < ntiles; tile += mmb) {
            __syncthreads();                              // protect sX reuse
            int row0 = tile << 6;
#pragma unroll
            for (int t = 0; t < 4; ++t) {                 // stage 64 rows of X
                int idx = threadIdx.x + t * 256;
                int r = idx >> 4, c4 = idx & 15;
                *(float4*)&sX[r][c4 * 4] = X4[(size_t)(row0 + r) * 16 + c4];
            }
            __syncthreads();
            float4 acc0 = make_float4(0.f, 0.f, 0.f, 0.f);
            float4 acc1 = acc0, acc2 = acc0, acc3 = acc0;
#pragma unroll
            for (int k4 = 0; k4 < 16; ++k4) {
                float4 xv0 = *(const float4*)&sX[rg * 4 + 0][k4 * 4];
                float4 xv1 = *(const float4*)&sX[rg * 4 + 1][k4 * 4];
                float4 xv2 = *(const float4*)&sX[rg * 4 + 2][k4 * 4];
                float4 xv3 = *(const float4*)&sX[rg * 4 + 3][k4 * 4];
                float4 wv0 = *(const float4*)&sW[k4 * 4 + 0][cg * 4];
                float4 wv1 = *(const float4*)&sW[k4 * 4 + 1][cg * 4];
                float4 wv2 = *(const float4*)&sW[k4 * 4 + 2][cg * 4];
                float4 wv3 = *(const float4*)&sW[k4 * 4 + 3][cg * 4];
                acc0 = f4fma(xv0.x, wv0, acc0); acc0 = f4fma(xv0.y, wv1, acc0);
                acc0 = f4fma(xv0.z, wv2, acc0); acc0 = f4fma(xv0.w, wv3, acc0);
                acc1 = f4fma(xv1.x, wv0, acc1); acc1 = f4fma(xv1.y, wv1, acc1);
                acc1 = f4fma(xv1.z, wv2, acc1); acc1 = f4fma(xv1.w, wv3, acc1);
                acc2 = f4fma(xv2.x, wv0, acc2); acc2 = f4fma(xv2.y, wv1, acc2);
                acc2 = f4fma(xv2.z, wv2, acc2); acc2 = f4fma(xv2.w, wv3, acc2);
                acc3 = f4fma(xv3.x, wv0, acc3); acc3 = f4fma(xv3.y, wv1, acc3);
                acc3 = f4fma(xv3.z, wv2, acc3); acc3 = f4fma(xv3.w, wv3, acc3);
            }
            size_t ob = (size_t)(row0 + rg * 4) * 16 + cg;
            Y4[ob]      = acc0;
            Y4[ob + 16] = acc1;
            Y4[ob + 32] = acc2;
            Y4[ob + 48] = acc3;
        }
    }
}

// ---- gather conv: wave = 4 nodes x 16 lanes (float4 feats); fused self+bias,
// relu, and hp = relu(h) . Wp. XCD-swizzled so one graph stays on one XCD. ----
template <int NPG>
__global__ __launch_bounds__(256)
void gather_feat_kernel(const float4* __restrict__ hx4, const int2* __restrict__ pairs,
                        const int* __restrict__ rowstart, const int* __restrict__ rowcnt,
                        const float* __restrict__ dinv, const float4* __restrict__ b4,
                        const float4* __restrict__ wp4, float* __restrict__ hp,
                        float4* __restrict__ out4) {
    constexpr int BPG = NPG / 16;           // blocks per graph
    int i   = blockIdx.x;
    int xcd = i & 7;
    int k   = i >> 3;
    int g     = xcd * (BG / 8) + k / BPG;   // all BPG blocks of graph g on one XCD
    int chunk = k % BPG;
    int lane16 = threadIdx.x & 15;
    int sub    = (threadIdx.x >> 4) & 3;
    int wv     = threadIdx.x >> 6;
    int lanebase = (threadIdx.x & 63) & 48; // sub*16
    int node = g * NPG + chunk * 16 + wv * 4 + sub;

    float di = dinv[node];
    int st = rowstart[node], cn = rowcnt[node];
    float4 acc = hx4[(size_t)node * 16 + lane16];
    float dii = di * di;
    float4 bb = b4[lane16];
    acc.x = fmaf(acc.x, dii, bb.x);
    acc.y = fmaf(acc.y, dii, bb.y);
    acc.z = fmaf(acc.z, dii, bb.z);
    acc.w = fmaf(acc.w, dii, bb.w);

    for (int eb = 0; eb < cn; eb += 16) {
        int m = cn - eb; if (m > 16) m = 16;
        int2 pr = make_int2(0, 0);
        if (lane16 < m) pr = pairs[st + eb + lane16];
        int   s_cur = __shfl(pr.x, lanebase, 64);
        float c_cur = __int_as_float(__shfl(pr.y, lanebase, 64));
        float4 v_cur = hx4[(size_t)s_cur * 16 + lane16];
        for (int j = 0; j < m; ++j) {
            int s_n = s_cur; float c_n = 0.f; float4 v_n = v_cur;
            if (j + 1 < m) {
                s_n = __shfl(pr.x, lanebase + j + 1, 64);
                c_n = __int_as_float(__shfl(pr.y, lanebase + j + 1, 64));
                v_n = hx4[(size_t)s_n * 16 + lane16];     // prefetch next neighbor row
            }
            acc.x = fmaf(c_cur, v_cur.x, acc.x);
            acc.y = fmaf(c_cur, v_cur.y, acc.y);
            acc.z = fmaf(c_cur, v_cur.z, acc.z);
            acc.w = fmaf(c_cur, v_cur.w, acc.w);
            s_cur = s_n; c_cur = c_n; v_cur = v_n;
        }
    }
    acc.x = fmaxf(acc.x, 0.f); acc.y = fmaxf(acc.y, 0.f);
    acc.z = fmaxf(acc.z, 0.f); acc.w = fmaxf(acc.w, 0.f);
    out4[(size_t)node * 16 + lane16] = acc;
    // fused hp = h . Wp (group reduction over 16 lanes)
    float4 w4 = wp4[lane16];
    float t = acc.x * w4.x + acc.y * w4.y + acc.z * w4.z + acc.w * w4.w;
    t += __shfl_xor(t, 1, 64); t += __shfl_xor(t, 2, 64);
    t += __shfl_xor(t, 4, 64); t += __shfl_xor(t, 8, 64);
    if (lane16 == 0) hp[node] = t;
}

// ---- score conv: wave = 4 nodes x 16 lanes; lane-parallel edge sum ----
__global__ __launch_bounds__(256)
void gather_score_kernel(const float* __restrict__ hp, const int2* __restrict__ pairs,
                         const int* __restrict__ rowstart, const int* __restrict__ rowcnt,
                         const float* __restrict__ dinv, const float* __restrict__ bp,
                         float* __restrict__ sc, int n) {
    int lane16 = threadIdx.x & 15;
    int sub    = (threadIdx.x >> 4) & 3;
    int wave   = (blockIdx.x * blockDim.x + threadIdx.x) >> 6;
    int node   = wave * 4 + sub;
    if (node >= n) return;
    int st = rowstart[node], cn = rowcnt[node];
    float part = 0.f;
    for (int eb = 0; eb < cn; eb += 16) {
        int m = cn - eb; if (m > 16) m = 16;
        if (lane16 < m) {
            int2 pr = pairs[st + eb + lane16];
            part += __int_as_float(pr.y) * hp[pr.x];
        }
    }
    part += __shfl_xor(part, 1, 64); part += __shfl_xor(part, 2, 64);
    part += __shfl_xor(part, 4, 64); part += __shfl_xor(part, 8, 64);
    if (lane16 == 0) {
        float di = dinv[node];
        sc[node] = fmaf(hp[node], di * di, bp[0]) + part;
    }
}

// ---- fused pool: exact top-k rank + nid + gated gather + [gmp||gap] readout ----
// rank = #(s[j] > s[i]) + #(s[j]==s[i] && j<i)  (exact jax.lax.top_k order)
template <int NPG, int K>
__global__ __launch_bounds__(256)
void pool_fused_kernel(const float* __restrict__ score, const float4* __restrict__ h4,
                       int* __restrict__ nid, float4* __restrict__ xn4,
                       float* __restrict__ xr) {
    __shared__ float  s[NPG];
    __shared__ int    lperm[K];
    __shared__ float  lgate[K];
    __shared__ float4 smx[16][16];
    __shared__ float4 ssm[16][16];
    int g = blockIdx.x, base = g * NPG;
    for (int i = threadIdx.x; i < NPG; i += 256) s[i] = score[base + i];
    __syncthreads();
    for (int i = threadIdx.x; i < NPG; i += 256) {
        float si = s[i];
        int rank = 0;
        for (int j = 0; j < NPG; ++j) {
            float sj = s[j];
            rank += (sj > si) || (sj == si && j < i);
        }
        if (rank < K) {
            nid[base + i] = g * K + rank;
            lperm[rank]   = i;
            lgate[rank]   = tanhf(si);
        } else {
            nid[base + i] = -1;
        }
    }
    __syncthreads();
    int q16 = threadIdx.x & 15;
    int jg  = threadIdx.x >> 4;
    float4 mx = make_float4(-3.402823466e38f, -3.402823466e38f, -3.402823466e38f, -3.402823466e38f);
    float4 sm = make_float4(0.f, 0.f, 0.f, 0.f);
    for (int j = jg; j < K; j += 16) {
        float gt = lgate[j];
        float4 v = h4[(size_t)(base + lperm[j]) * 16 + q16];
        v.x *= gt; v.y *= gt; v.z *= gt; v.w *= gt;
        xn4[((size_t)g * K + j) * 16 + q16] = v;
        mx.x = fmaxf(mx.x, v.x); mx.y = fmaxf(mx.y, v.y);
        mx.z = fmaxf(mx.z, v.z); mx.w = fmaxf(mx.w, v.w);
        sm.x += v.x; sm.y += v.y; sm.z += v.z; sm.w += v.w;
    }
    smx[jg][q16] = mx; ssm[jg][q16] = sm;
    __syncthreads();
    if (jg == 0) {
#pragma unroll
        for (int t = 1; t < 16; ++t) {
            float4 a = smx[t][q16], b = ssm[t][q16];
            mx.x = fmaxf(mx.x, a.x); mx.y = fmaxf(mx.y, a.y);
            mx.z = fmaxf(mx.z, a.z); mx.w = fmaxf(mx.w, a.w);
            sm.x += b.x; sm.y += b.y; sm.z += b.z; sm.w += b.w;
        }
        float invK = 1.f / K;
        int c = q16 * 4;
        xr[g * 128 + c + 0] = mx.x; xr[g * 128 + c + 1] = mx.y;
        xr[g * 128 + c + 2] = mx.z; xr[g * 128 + c + 3] = mx.w;
        xr[g * 128 + 64 + c + 0] = sm.x * invK; xr[g * 128 + 64 + c + 1] = sm.y * invK;
        xr[g * 128 + 64 + c + 2] = sm.z * invK; xr[g * 128 + 64 + c + 3] = sm.w * invK;
    }
}

__global__ void combine_kernel(const float* __restrict__ a, const float* __restrict__ b,
                               float* __restrict__ out, int n) {
    int i = blockIdx.x * blockDim.x + threadIdx.x;
    if (i < n) out[i] = 0.5f * (a[i] + b[i]);
}

extern "C" void kernel_launch(void* const* d_in, const int* in_sizes, int n_in,
                              void* d_out, int out_size, void* d_ws, size_t ws_size,
                              hipStream_t stream) {
    const float* x    = (const float*)d_in[0];
    const float* eatt = (const float*)d_in[1];
    const float* W1   = (const float*)d_in[2];
    const float* b1   = (const float*)d_in[3];
    const float* Wp1  = (const float*)d_in[4];
    const float* bp1  = (const float*)d_in[5];
    const float* W2   = (const float*)d_in[6];
    const float* b2   = (const float*)d_in[7];
    const float* Wp2  = (const float*)d_in[8];
    const float* bp2  = (const float*)d_in[9];
    const int*   esrc = (const int*)d_in[10];
    const int*   edst = (const int*)d_in[11];
    float* out = (float*)d_out;

    // workspace (~87 MB of floats); A/B regions reused across stages
    float* ws = (float*)d_ws;
    size_t o = 0;
    float* A    = ws + o; o += (size_t)N0 * 64;   // hx1 -> {xn1 | hx2} -> xn2
    float* Bb   = ws + o; o += (size_t)N0 * 64;   // h1 -> h2
    int2*  prs  = (int2*)(ws + o); o += (size_t)NE * 2;  // (src,coef) per CSR slot
    int*   rst  = (int*)(ws + o); o += N0;
    int*   rcn  = (int*)(ws + o); o += N0;
    float* dinv = ws + o; o += N0;
    float* hp   = ws + o; o += N0;
    float* sc   = ws + o; o += N0;
    int*   nid  = (int*)(ws + o); o += N0;        // nid1; reused as nid2 after csr2
    float* x1r  = ws + o; o += BG * 128;
    float* x2r  = ws + o; o += BG * 128;

    float* hx1 = A;
    float* h1  = Bb;
    float* xn1 = A;                        // after hx1 dead
    float* hx2 = A + (size_t)N1_ * 64;
    float* h2  = Bb;                       // after h1 dead
    float* xn2 = A;                        // after xn1 dead

    const int TB = 256;
    // ---- stage 1: CSR1 + (x @ W1) fused ----
    stage_head_kernel<NN, false><<<BG + 1024, TB, 0, stream>>>(
        esrc, edst, eatt, nullptr, prs, rst, rcn, dinv,
        (const float4*)x, (const float4*)W1, (float4*)hx1, N0, 1024);
    gather_feat_kernel<NN><<<BG * (NN / 16), TB, 0, stream>>>(
        (const float4*)hx1, prs, rst, rcn, dinv, (const float4*)b1, (const float4*)Wp1, hp, (float4*)h1);
    gather_score_kernel<<<N0 / 16, TB, 0, stream>>>(hp, prs, rst, rcn, dinv, bp1, sc, N0);
    pool_fused_kernel<NN, K1><<<BG, TB, 0, stream>>>(sc, (const float4*)h1, nid, (float4*)xn1, x1r);
    // ---- stage 2: CSR2 (remap) + (xn1 @ W2) fused ----
    stage_head_kernel<K1, true><<<BG + 512, TB, 0, stream>>>(
        esrc, edst, eatt, nid, prs, rst, rcn, dinv,
        (const float4*)xn1, (const float4*)W2, (float4*)hx2, N1_, 512);
    gather_feat_kernel<K1><<<BG * (K1 / 16), TB, 0, stream>>>(
        (const float4*)hx2, prs, rst, rcn, dinv, (const float4*)b2, (const float4*)Wp2, hp, (float4*)h2);
    gather_score_kernel<<<N1_ / 16, TB, 0, stream>>>(hp, prs, rst, rcn, dinv, bp2, sc, N1_);
    pool_fused_kernel<K1, K2><<<BG, TB, 0, stream>>>(sc, (const float4*)h2, nid, (float4*)xn2, x2r);
    // ---- final ----
    combine_kernel<<<(BG * 128 + TB - 1) / TB, TB, 0, stream>>>(x1r, x2r, out, BG * 128);
}

// Round 6
// 264.831 us; speedup vs baseline: 4.5559x; 1.1600x over previous
//
#include <hip/hip_runtime.h>
#include <math.h>

#define BG   256                   // graphs
#define NN   512                   // nodes per graph
#define EPG  (NN * 16)             // 8192 edges per graph
#define NE   (BG * EPG)            // 2097152 edges
#define N0   (BG * NN)             // 131072
#define K1   256
#define N1_  (BG * K1)             // 65536
#define K2   128
#define N2_  (BG * K2)             // 32768

__device__ __forceinline__ float4 f4fma(float s, float4 a, float4 c) {
    c.x = fmaf(s, a.x, c.x); c.y = fmaf(s, a.y, c.y);
    c.z = fmaf(s, a.z, c.z); c.w = fmaf(s, a.w, c.w);
    return c;
}

// ---- fused stage head (512 threads/block):
// blocks [0,BG): CSR build for graph g — each thread caches its 16 edges in
// registers (ONE global read pass), LDS count/scan, then slot-scatter of
// (src, coef) pairs. blocks [BG, BG+mmb): 64x64 GEMM Y = X @ W as two
// independent 256-thread tile pipelines (lockstep barriers, shared sW).
template <int NPG, bool REMAP>
__global__ __launch_bounds__(512)
void stage_head_kernel(const int* __restrict__ esrc, const int* __restrict__ edst,
                       const float* __restrict__ eatt, const int* __restrict__ nid,
                       int2* __restrict__ pairs, int* __restrict__ rowstart,
                       int* __restrict__ rowcnt, float* __restrict__ dinv,
                       const float4* __restrict__ X4, const float4* __restrict__ W4,
                       float4* __restrict__ Y4, int nrows, int mmb) {
    __shared__ __align__(16) char smem[52224];   // max(csr 8KB, sW + 2x sX)
    if ((int)blockIdx.x < BG) {
        // ---------------- CSR build for graph g ----------------
        int*   cnt   = (int*)smem;               // [NPG]
        float* wsum  = (float*)smem + NPG;       // [NPG]
        int*   scn   = (int*)smem + 2 * NPG;     // [NPG]
        float* sdinv = (float*)smem + 3 * NPG;   // [NPG]
        int g = blockIdx.x;
        int e0 = g * EPG, nbase = g * NPG;
        for (int i = threadIdx.x; i < NPG; i += 512) { cnt[i] = 0; wsum[i] = 0.f; }
        __syncthreads();
        const int4*   edst4 = (const int4*)(edst + e0);
        const int4*   esrc4 = (const int4*)(esrc + e0);
        const float4* eatt4 = (const float4*)(eatt + e0);
        int ed[16]; int es[16]; float ea[16];
#pragma unroll
        for (int c = 0; c < 4; ++c) {            // single global read pass
            int ch = threadIdx.x + c * 512;
            int4   dd = edst4[ch];
            int4   ss = esrc4[ch];
            float4 ww = eatt4[ch];
            ed[c * 4 + 0] = dd.x; ed[c * 4 + 1] = dd.y; ed[c * 4 + 2] = dd.z; ed[c * 4 + 3] = dd.w;
            es[c * 4 + 0] = ss.x; es[c * 4 + 1] = ss.y; es[c * 4 + 2] = ss.z; es[c * 4 + 3] = ss.w;
            ea[c * 4 + 0] = ww.x; ea[c * 4 + 1] = ww.y; ea[c * 4 + 2] = ww.z; ea[c * 4 + 3] = ww.w;
        }
        if (REMAP) {
#pragma unroll
            for (int j = 0; j < 16; ++j) { ed[j] = nid[ed[j]]; es[j] = nid[es[j]]; }
        }
        // pass 1: counts + weighted degree (from registers)
#pragma unroll
        for (int j = 0; j < 16; ++j) {
            bool valid = !REMAP || (ed[j] >= 0 && es[j] >= 0);
            if (valid) {
                int dl = ed[j] - nbase;
                atomicAdd(&cnt[dl], 1);
                atomicAdd(&wsum[dl], ea[j]);
            }
        }
        __syncthreads();
        int i = threadIdx.x;
        if (i < NPG) scn[i] = cnt[i];
        __syncthreads();
        for (int off = 1; off < NPG; off <<= 1) {
            int v = 0;
            if (i < NPG && i >= off) v = scn[i - off];
            __syncthreads();
            if (i < NPG) scn[i] += v;
            __syncthreads();
        }
        if (i < NPG) {
            int st = scn[i] - cnt[i];            // exclusive scan
            rowstart[nbase + i] = e0 + st;
            rowcnt[nbase + i]   = cnt[i];
            float di = rsqrtf(wsum[i] + 1.0f);
            dinv[nbase + i] = di;
            sdinv[i] = di;
            scn[i] = st;                          // running slot offset
        }
        __syncthreads();
        // pass 2: slot scatter with precomputed coef (from registers)
#pragma unroll
        for (int j = 0; j < 16; ++j) {
            bool valid = !REMAP || (ed[j] >= 0 && es[j] >= 0);
            if (valid) {
                int dl = ed[j] - nbase, sl = es[j] - nbase;
                float coef = sdinv[dl] * ea[j] * sdinv[sl];
                int slot = e0 + atomicAdd(&scn[dl], 1);
                pairs[slot] = make_int2(es[j], __float_as_int(coef));
            }
        }
    } else {
        // ---------------- GEMM: Y[nrows,64] = X @ W ----------------
        float (*sW)[68] = (float (*)[68])smem;                       // 17408 B
        int p = threadIdx.x >> 8;                                    // pipeline 0/1
        int t = threadIdx.x & 255;
        float (*sX)[68] = (float (*)[68])(smem + 17408 + p * 17408);
#pragma unroll
        for (int u = 0; u < 2; ++u) {            // stage W once (all 512 threads)
            int idx = threadIdx.x + u * 512;
            int r = idx >> 4, c4 = idx & 15;
            *(float4*)&sW[r][c4 * 4] = W4[idx];
        }
        int mb = blockIdx.x - BG;
        int ntiles = nrows >> 6;
        int rg = t >> 4, cg = t & 15;
        for (int tile = mb * 2 + p; tile < ntiles; tile += mmb * 2) {
            __syncthreads();                     // protect sX reuse; covers sW stage
            int row0 = tile << 6;
#pragma unroll
            for (int u = 0; u < 4; ++u) {        // stage 64 rows of X
                int idx = t + u * 256;
                int r = idx >> 4, c4 = idx & 15;
                *(float4*)&sX[r][c4 * 4] = X4[(size_t)(row0 + r) * 16 + c4];
            }
            __syncthreads();
            float4 acc0 = make_float4(0.f, 0.f, 0.f, 0.f);
            float4 acc1 = acc0, acc2 = acc0, acc3 = acc0;
#pragma unroll
            for (int k4 = 0; k4 < 16; ++k4) {
                float4 xv0 = *(const float4*)&sX[rg * 4 + 0][k4 * 4];
                float4 xv1 = *(const float4*)&sX[rg * 4 + 1][k4 * 4];
                float4 xv2 = *(const float4*)&sX[rg * 4 + 2][k4 * 4];
                float4 xv3 = *(const float4*)&sX[rg * 4 + 3][k4 * 4];
                float4 wv0 = *(const float4*)&sW[k4 * 4 + 0][cg * 4];
                float4 wv1 = *(const float4*)&sW[k4 * 4 + 1][cg * 4];
                float4 wv2 = *(const float4*)&sW[k4 * 4 + 2][cg * 4];
                float4 wv3 = *(const float4*)&sW[k4 * 4 + 3][cg * 4];
                acc0 = f4fma(xv0.x, wv0, acc0); acc0 = f4fma(xv0.y, wv1, acc0);
                acc0 = f4fma(xv0.z, wv2, acc0); acc0 = f4fma(xv0.w, wv3, acc0);
                acc1 = f4fma(xv1.x, wv0, acc1); acc1 = f4fma(xv1.y, wv1, acc1);
                acc1 = f4fma(xv1.z, wv2, acc1); acc1 = f4fma(xv1.w, wv3, acc1);
                acc2 = f4fma(xv2.x, wv0, acc2); acc2 = f4fma(xv2.y, wv1, acc2);
                acc2 = f4fma(xv2.z, wv2, acc2); acc2 = f4fma(xv2.w, wv3, acc2);
                acc3 = f4fma(xv3.x, wv0, acc3); acc3 = f4fma(xv3.y, wv1, acc3);
                acc3 = f4fma(xv3.z, wv2, acc3); acc3 = f4fma(xv3.w, wv3, acc3);
            }
            size_t ob = (size_t)(row0 + rg * 4) * 16 + cg;
            Y4[ob]      = acc0;
            Y4[ob + 16] = acc1;
            Y4[ob + 32] = acc2;
            Y4[ob + 48] = acc3;
        }
    }
}

// ---- gather conv: wave = 4 nodes x 16 lanes (float4 feats); fused self+bias,
// relu, and hp = relu(h) . Wp. XCD-swizzled so one graph stays on one XCD. ----
template <int NPG>
__global__ __launch_bounds__(256)
void gather_feat_kernel(const float4* __restrict__ hx4, const int2* __restrict__ pairs,
                        const int* __restrict__ rowstart, const int* __restrict__ rowcnt,
                        const float* __restrict__ dinv, const float4* __restrict__ b4,
                        const float4* __restrict__ wp4, float* __restrict__ hp,
                        float4* __restrict__ out4) {
    constexpr int BPG = NPG / 16;           // blocks per graph
    int i   = blockIdx.x;
    int xcd = i & 7;
    int k   = i >> 3;
    int g     = xcd * (BG / 8) + k / BPG;   // all BPG blocks of graph g on one XCD
    int chunk = k % BPG;
    int lane16 = threadIdx.x & 15;
    int sub    = (threadIdx.x >> 4) & 3;
    int wv     = threadIdx.x >> 6;
    int lanebase = (threadIdx.x & 63) & 48; // sub*16
    int node = g * NPG + chunk * 16 + wv * 4 + sub;

    float di = dinv[node];
    int st = rowstart[node], cn = rowcnt[node];
    float4 acc = hx4[(size_t)node * 16 + lane16];
    float dii = di * di;
    float4 bb = b4[lane16];
    acc.x = fmaf(acc.x, dii, bb.x);
    acc.y = fmaf(acc.y, dii, bb.y);
    acc.z = fmaf(acc.z, dii, bb.z);
    acc.w = fmaf(acc.w, dii, bb.w);

    for (int eb = 0; eb < cn; eb += 16) {
        int m = cn - eb; if (m > 16) m = 16;
        int2 pr = make_int2(0, 0);
        if (lane16 < m) pr = pairs[st + eb + lane16];
        int   s_cur = __shfl(pr.x, lanebase, 64);
        float c_cur = __int_as_float(__shfl(pr.y, lanebase, 64));
        float4 v_cur = hx4[(size_t)s_cur * 16 + lane16];
        for (int j = 0; j < m; ++j) {
            int s_n = s_cur; float c_n = 0.f; float4 v_n = v_cur;
            if (j + 1 < m) {
                s_n = __shfl(pr.x, lanebase + j + 1, 64);
                c_n = __int_as_float(__shfl(pr.y, lanebase + j + 1, 64));
                v_n = hx4[(size_t)s_n * 16 + lane16];     // prefetch next neighbor row
            }
            acc.x = fmaf(c_cur, v_cur.x, acc.x);
            acc.y = fmaf(c_cur, v_cur.y, acc.y);
            acc.z = fmaf(c_cur, v_cur.z, acc.z);
            acc.w = fmaf(c_cur, v_cur.w, acc.w);
            s_cur = s_n; c_cur = c_n; v_cur = v_n;
        }
    }
    acc.x = fmaxf(acc.x, 0.f); acc.y = fmaxf(acc.y, 0.f);
    acc.z = fmaxf(acc.z, 0.f); acc.w = fmaxf(acc.w, 0.f);
    out4[(size_t)node * 16 + lane16] = acc;
    // fused hp = h . Wp (group reduction over 16 lanes)
    float4 w4 = wp4[lane16];
    float t = acc.x * w4.x + acc.y * w4.y + acc.z * w4.z + acc.w * w4.w;
    t += __shfl_xor(t, 1, 64); t += __shfl_xor(t, 2, 64);
    t += __shfl_xor(t, 4, 64); t += __shfl_xor(t, 8, 64);
    if (lane16 == 0) hp[node] = t;
}

// ---- fused per-graph tail: score conv (hp staged in LDS) + exact top-k rank +
// gated gather + [gmp||gap] readout; FINAL also folds the (x1+x2)/2 combine. ----
// rank = #(s[j] > s[i]) + #(s[j]==s[i] && j<i)  (exact jax.lax.top_k order)
template <int NPG, int K, bool FINAL>
__global__ __launch_bounds__(512)
void score_pool_kernel(const float* __restrict__ hp, const int2* __restrict__ pairs,
                       const int* __restrict__ rowstart, const int* __restrict__ rowcnt,
                       const float* __restrict__ dinv, const float* __restrict__ bp,
                       const float4* __restrict__ h4, int* __restrict__ nid,
                       float4* __restrict__ xn4, float* __restrict__ xr,
                       const float* __restrict__ x1r, float* __restrict__ out) {
    __shared__ float  shp[NPG];
    __shared__ float  ssc[NPG];
    __shared__ int    lperm[K];
    __shared__ float  lgate[K];
    __shared__ float4 smx[32][16];
    __shared__ float4 ssm[32][16];
    int g = blockIdx.x, base = g * NPG;
    for (int i = threadIdx.x; i < NPG; i += 512) shp[i] = hp[base + i];
    __syncthreads();
    // score conv: edge sums read LDS hp
    for (int i = threadIdx.x; i < NPG; i += 512) {
        int st = rowstart[base + i], cn = rowcnt[base + i];
        float di = dinv[base + i];
        float acc = fmaf(shp[i], di * di, bp[0]);
        for (int j = 0; j < cn; ++j) {
            int2 pr = pairs[st + j];
            acc = fmaf(__int_as_float(pr.y), shp[pr.x - base], acc);
        }
        ssc[i] = acc;
    }
    __syncthreads();
    // exact top-k rank
    for (int i = threadIdx.x; i < NPG; i += 512) {
        float si = ssc[i];
        int rank = 0;
        for (int j = 0; j < NPG; ++j) {
            float sj = ssc[j];
            rank += (sj > si) || (sj == si && j < i);
        }
        if (rank < K) {
            nid[base + i] = g * K + rank;
            lperm[rank]   = i;
            lgate[rank]   = tanhf(si);
        } else {
            nid[base + i] = -1;
        }
    }
    __syncthreads();
    // gated gather + readout
    int q16 = threadIdx.x & 15;
    int jg  = threadIdx.x >> 4;              // 0..31
    float4 mx = make_float4(-3.402823466e38f, -3.402823466e38f, -3.402823466e38f, -3.402823466e38f);
    float4 sm = make_float4(0.f, 0.f, 0.f, 0.f);
    for (int j = jg; j < K; j += 32) {
        float gt = lgate[j];
        float4 v = h4[(size_t)(base + lperm[j]) * 16 + q16];
        v.x *= gt; v.y *= gt; v.z *= gt; v.w *= gt;
        xn4[((size_t)g * K + j) * 16 + q16] = v;
        mx.x = fmaxf(mx.x, v.x); mx.y = fmaxf(mx.y, v.y);
        mx.z = fmaxf(mx.z, v.z); mx.w = fmaxf(mx.w, v.w);
        sm.x += v.x; sm.y += v.y; sm.z += v.z; sm.w += v.w;
    }
    smx[jg][q16] = mx; ssm[jg][q16] = sm;
    __syncthreads();
    if (jg == 0) {
#pragma unroll
        for (int t = 1; t < 32; ++t) {
            float4 a = smx[t][q16], b = ssm[t][q16];
            mx.x = fmaxf(mx.x, a.x); mx.y = fmaxf(mx.y, a.y);
            mx.z = fmaxf(mx.z, a.z); mx.w = fmaxf(mx.w, a.w);
            sm.x += b.x; sm.y += b.y; sm.z += b.z; sm.w += b.w;
        }
        float invK = 1.f / K;
        int c = q16 * 4;
        float mr[4] = {mx.x, mx.y, mx.z, mx.w};
        float ar[4] = {sm.x * invK, sm.y * invK, sm.z * invK, sm.w * invK};
#pragma unroll
        for (int u = 0; u < 4; ++u) {
            if (FINAL) {
                out[g * 128 + c + u]      = 0.5f * (x1r[g * 128 + c + u]      + mr[u]);
                out[g * 128 + 64 + c + u] = 0.5f * (x1r[g * 128 + 64 + c + u] + ar[u]);
            } else {
                xr[g * 128 + c + u]      = mr[u];
                xr[g * 128 + 64 + c + u] = ar[u];
            }
        }
    }
}

extern "C" void kernel_launch(void* const* d_in, const int* in_sizes, int n_in,
                              void* d_out, int out_size, void* d_ws, size_t ws_size,
                              hipStream_t stream) {
    const float* x    = (const float*)d_in[0];
    const float* eatt = (const float*)d_in[1];
    const float* W1   = (const float*)d_in[2];
    const float* b1   = (const float*)d_in[3];
    const float* Wp1  = (const float*)d_in[4];
    const float* bp1  = (const float*)d_in[5];
    const float* W2   = (const float*)d_in[6];
    const float* b2   = (const float*)d_in[7];
    const float* Wp2  = (const float*)d_in[8];
    const float* bp2  = (const float*)d_in[9];
    const int*   esrc = (const int*)d_in[10];
    const int*   edst = (const int*)d_in[11];
    float* out = (float*)d_out;

    // workspace (~87 MB of floats); A/B regions reused across stages
    float* ws = (float*)d_ws;
    size_t o = 0;
    float* A    = ws + o; o += (size_t)N0 * 64;   // hx1 -> {xn1 | hx2} -> xn2
    float* Bb   = ws + o; o += (size_t)N0 * 64;   // h1 -> h2
    int2*  prs  = (int2*)(ws + o); o += (size_t)NE * 2;  // (src,coef) per CSR slot
    int*   rst  = (int*)(ws + o); o += N0;
    int*   rcn  = (int*)(ws + o); o += N0;
    float* dinv = ws + o; o += N0;
    float* hp   = ws + o; o += N0;
    int*   nid  = (int*)(ws + o); o += N0;        // nid1; reused as nid2
    float* x1r  = ws + o; o += BG * 128;

    float* hx1 = A;
    float* h1  = Bb;
    float* xn1 = A;                        // after hx1 dead
    float* hx2 = A + (size_t)N1_ * 64;
    float* h2  = Bb;                       // after h1 dead
    float* xn2 = A;                        // after xn1 dead

    // ---- stage 1 ----
    stage_head_kernel<NN, false><<<BG + 512, 512, 0, stream>>>(
        esrc, edst, eatt, nullptr, prs, rst, rcn, dinv,
        (const float4*)x, (const float4*)W1, (float4*)hx1, N0, 512);
    gather_feat_kernel<NN><<<BG * (NN / 16), 256, 0, stream>>>(
        (const float4*)hx1, prs, rst, rcn, dinv, (const float4*)b1, (const float4*)Wp1, hp, (float4*)h1);
    score_pool_kernel<NN, K1, false><<<BG, 512, 0, stream>>>(
        hp, prs, rst, rcn, dinv, bp1, (const float4*)h1, nid, (float4*)xn1, x1r, nullptr, nullptr);
    // ---- stage 2 ----
    stage_head_kernel<K1, true><<<BG + 256, 512, 0, stream>>>(
        esrc, edst, eatt, nid, prs, rst, rcn, dinv,
        (const float4*)xn1, (const float4*)W2, (float4*)hx2, N1_, 256);
    gather_feat_kernel<K1><<<BG * (K1 / 16), 256, 0, stream>>>(
        (const float4*)hx2, prs, rst, rcn, dinv, (const float4*)b2, (const float4*)Wp2, hp, (float4*)h2);
    score_pool_kernel<K1, K2, true><<<BG, 512, 0, stream>>>(
        hp, prs, rst, rcn, dinv, bp2, (const float4*)h2, nid, (float4*)xn2, nullptr, x1r, out);
}

// Round 7
// 257.366 us; speedup vs baseline: 4.6881x; 1.0290x over previous
//
#include <hip/hip_runtime.h>
#include <math.h>

#define BG   256                   // graphs
#define NN   512                   // nodes per graph
#define EPG  (NN * 16)             // 8192 edges per graph
#define NE   (BG * EPG)            // 2097152 edges
#define N0   (BG * NN)             // 131072
#define K1   256
#define N1_  (BG * K1)             // 65536
#define K2   128
#define N2_  (BG * K2)             // 32768

__device__ __forceinline__ float4 f4fma(float s, float4 a, float4 c) {
    c.x = fmaf(s, a.x, c.x); c.y = fmaf(s, a.y, c.y);
    c.z = fmaf(s, a.z, c.z); c.w = fmaf(s, a.w, c.w);
    return c;
}

// ---- fused stage head (512 threads/block):
// blocks [0,BG): CSR build for graph g — each thread caches its 16 edges in
// registers (ONE global read pass), LDS count/scan, slot-scatter of (src,coef)
// pairs INTO LDS (64 KB), then a fully-coalesced contiguous write-out (kills
// the 8B-scatter write amplification seen in r6: 126 MB WRITE -> ~16 MB).
// blocks [BG, BG+mmb): 64x64 GEMM Y = X @ W as two 256-thread tile pipelines.
template <int NPG, bool REMAP>
__global__ __launch_bounds__(512)
void stage_head_kernel(const int* __restrict__ esrc, const int* __restrict__ edst,
                       const float* __restrict__ eatt, const int* __restrict__ nid,
                       int2* __restrict__ pairs, int* __restrict__ rowstart,
                       int* __restrict__ rowcnt, float* __restrict__ dinv,
                       const float4* __restrict__ X4, const float4* __restrict__ W4,
                       float4* __restrict__ Y4, int nrows, int mmb) {
    __shared__ __align__(16) char smem[73728];   // max(csr 64K+8K, gemm 51K)
    if ((int)blockIdx.x < BG) {
        // ---------------- CSR build for graph g ----------------
        int2*  lpair = (int2*)smem;                      // [EPG] staging, 64 KB
        int*   cnt   = (int*)(smem + 65536);             // [NPG]
        float* wsum  = (float*)(smem + 65536) + NPG;     // [NPG]
        int*   scn   = (int*)(smem + 65536) + 2 * NPG;   // [NPG]
        float* sdinv = (float*)(smem + 65536) + 3 * NPG; // [NPG]
        __shared__ int stotal;
        int g = blockIdx.x;
        int e0 = g * EPG, nbase = g * NPG;
        for (int i = threadIdx.x; i < NPG; i += 512) { cnt[i] = 0; wsum[i] = 0.f; }
        __syncthreads();
        const int4*   edst4 = (const int4*)(edst + e0);
        const int4*   esrc4 = (const int4*)(esrc + e0);
        const float4* eatt4 = (const float4*)(eatt + e0);
        int ed[16]; int es[16]; float ea[16];
#pragma unroll
        for (int c = 0; c < 4; ++c) {            // single global read pass
            int ch = threadIdx.x + c * 512;
            int4   dd = edst4[ch];
            int4   ss = esrc4[ch];
            float4 ww = eatt4[ch];
            ed[c * 4 + 0] = dd.x; ed[c * 4 + 1] = dd.y; ed[c * 4 + 2] = dd.z; ed[c * 4 + 3] = dd.w;
            es[c * 4 + 0] = ss.x; es[c * 4 + 1] = ss.y; es[c * 4 + 2] = ss.z; es[c * 4 + 3] = ss.w;
            ea[c * 4 + 0] = ww.x; ea[c * 4 + 1] = ww.y; ea[c * 4 + 2] = ww.z; ea[c * 4 + 3] = ww.w;
        }
        if (REMAP) {
#pragma unroll
            for (int j = 0; j < 16; ++j) { ed[j] = nid[ed[j]]; es[j] = nid[es[j]]; }
        }
        // pass 1: counts + weighted degree (from registers)
#pragma unroll
        for (int j = 0; j < 16; ++j) {
            bool valid = !REMAP || (ed[j] >= 0 && es[j] >= 0);
            if (valid) {
                int dl = ed[j] - nbase;
                atomicAdd(&cnt[dl], 1);
                atomicAdd(&wsum[dl], ea[j]);
            }
        }
        __syncthreads();
        int i = threadIdx.x;
        if (i < NPG) scn[i] = cnt[i];
        __syncthreads();
        for (int off = 1; off < NPG; off <<= 1) {
            int v = 0;
            if (i < NPG && i >= off) v = scn[i - off];
            __syncthreads();
            if (i < NPG) scn[i] += v;
            __syncthreads();
        }
        if (i == NPG - 1) stotal = scn[i];       // total valid edges
        if (i < NPG) {
            int st = scn[i] - cnt[i];            // exclusive scan
            rowstart[nbase + i] = e0 + st;
            rowcnt[nbase + i]   = cnt[i];
            float di = rsqrtf(wsum[i] + 1.0f);
            dinv[nbase + i] = di;
            sdinv[i] = di;
            scn[i] = st;                          // running slot offset
        }
        __syncthreads();
        // pass 2: slot scatter into LDS staging (from registers)
#pragma unroll
        for (int j = 0; j < 16; ++j) {
            bool valid = !REMAP || (ed[j] >= 0 && es[j] >= 0);
            if (valid) {
                int dl = ed[j] - nbase, sl = es[j] - nbase;
                float coef = sdinv[dl] * ea[j] * sdinv[sl];
                int slot = atomicAdd(&scn[dl], 1);
                lpair[slot] = make_int2(es[j], __float_as_int(coef));
            }
        }
        __syncthreads();
        // pass 3: contiguous coalesced write-out of the valid prefix
        int total = stotal;
        for (int k = threadIdx.x; k < total; k += 512)
            pairs[e0 + k] = lpair[k];
    } else {
        // ---------------- GEMM: Y[nrows,64] = X @ W ----------------
        float (*sW)[68] = (float (*)[68])smem;                       // 17408 B
        int p = threadIdx.x >> 8;                                    // pipeline 0/1
        int t = threadIdx.x & 255;
        float (*sX)[68] = (float (*)[68])(smem + 17408 + p * 17408);
#pragma unroll
        for (int u = 0; u < 2; ++u) {            // stage W once (all 512 threads)
            int idx = threadIdx.x + u * 512;
            int r = idx >> 4, c4 = idx & 15;
            *(float4*)&sW[r][c4 * 4] = W4[idx];
        }
        int mb = blockIdx.x - BG;
        int ntiles = nrows >> 6;
        int rg = t >> 4, cg = t & 15;
        for (int tile = mb * 2 + p; tile < ntiles; tile += mmb * 2) {
            __syncthreads();                     // protect sX reuse; covers sW stage
            int row0 = tile << 6;
#pragma unroll
            for (int u = 0; u < 4; ++u) {        // stage 64 rows of X
                int idx = t + u * 256;
                int r = idx >> 4, c4 = idx & 15;
                *(float4*)&sX[r][c4 * 4] = X4[(size_t)(row0 + r) * 16 + c4];
            }
            __syncthreads();
            float4 acc0 = make_float4(0.f, 0.f, 0.f, 0.f);
            float4 acc1 = acc0, acc2 = acc0, acc3 = acc0;
#pragma unroll
            for (int k4 = 0; k4 < 16; ++k4) {
                float4 xv0 = *(const float4*)&sX[rg * 4 + 0][k4 * 4];
                float4 xv1 = *(const float4*)&sX[rg * 4 + 1][k4 * 4];
                float4 xv2 = *(const float4*)&sX[rg * 4 + 2][k4 * 4];
                float4 xv3 = *(const float4*)&sX[rg * 4 + 3][k4 * 4];
                float4 wv0 = *(const float4*)&sW[k4 * 4 + 0][cg * 4];
                float4 wv1 = *(const float4*)&sW[k4 * 4 + 1][cg * 4];
                float4 wv2 = *(const float4*)&sW[k4 * 4 + 2][cg * 4];
                float4 wv3 = *(const float4*)&sW[k4 * 4 + 3][cg * 4];
                acc0 = f4fma(xv0.x, wv0, acc0); acc0 = f4fma(xv0.y, wv1, acc0);
                acc0 = f4fma(xv0.z, wv2, acc0); acc0 = f4fma(xv0.w, wv3, acc0);
                acc1 = f4fma(xv1.x, wv0, acc1); acc1 = f4fma(xv1.y, wv1, acc1);
                acc1 = f4fma(xv1.z, wv2, acc1); acc1 = f4fma(xv1.w, wv3, acc1);
                acc2 = f4fma(xv2.x, wv0, acc2); acc2 = f4fma(xv2.y, wv1, acc2);
                acc2 = f4fma(xv2.z, wv2, acc2); acc2 = f4fma(xv2.w, wv3, acc2);
                acc3 = f4fma(xv3.x, wv0, acc3); acc3 = f4fma(xv3.y, wv1, acc3);
                acc3 = f4fma(xv3.z, wv2, acc3); acc3 = f4fma(xv3.w, wv3, acc3);
            }
            size_t ob = (size_t)(row0 + rg * 4) * 16 + cg;
            Y4[ob]      = acc0;
            Y4[ob + 16] = acc1;
            Y4[ob + 32] = acc2;
            Y4[ob + 48] = acc3;
        }
    }
}

// ---- gather conv: wave = 4 nodes x 16 lanes (float4 feats); fused self+bias,
// relu, and hp = relu(h) . Wp. XCD-swizzled so one graph stays on one XCD. ----
template <int NPG>
__global__ __launch_bounds__(256)
void gather_feat_kernel(const float4* __restrict__ hx4, const int2* __restrict__ pairs,
                        const int* __restrict__ rowstart, const int* __restrict__ rowcnt,
                        const float* __restrict__ dinv, const float4* __restrict__ b4,
                        const float4* __restrict__ wp4, float* __restrict__ hp,
                        float4* __restrict__ out4) {
    constexpr int BPG = NPG / 16;           // blocks per graph
    int i   = blockIdx.x;
    int xcd = i & 7;
    int k   = i >> 3;
    int g     = xcd * (BG / 8) + k / BPG;   // all BPG blocks of graph g on one XCD
    int chunk = k % BPG;
    int lane16 = threadIdx.x & 15;
    int sub    = (threadIdx.x >> 4) & 3;
    int wv     = threadIdx.x >> 6;
    int lanebase = (threadIdx.x & 63) & 48; // sub*16
    int node = g * NPG + chunk * 16 + wv * 4 + sub;

    float di = dinv[node];
    int st = rowstart[node], cn = rowcnt[node];
    float4 acc = hx4[(size_t)node * 16 + lane16];
    float dii = di * di;
    float4 bb = b4[lane16];
    acc.x = fmaf(acc.x, dii, bb.x);
    acc.y = fmaf(acc.y, dii, bb.y);
    acc.z = fmaf(acc.z, dii, bb.z);
    acc.w = fmaf(acc.w, dii, bb.w);

    for (int eb = 0; eb < cn; eb += 16) {
        int m = cn - eb; if (m > 16) m = 16;
        int2 pr = make_int2(0, 0);
        if (lane16 < m) pr = pairs[st + eb + lane16];
        int   s_cur = __shfl(pr.x, lanebase, 64);
        float c_cur = __int_as_float(__shfl(pr.y, lanebase, 64));
        float4 v_cur = hx4[(size_t)s_cur * 16 + lane16];
        for (int j = 0; j < m; ++j) {
            int s_n = s_cur; float c_n = 0.f; float4 v_n = v_cur;
            if (j + 1 < m) {
                s_n = __shfl(pr.x, lanebase + j + 1, 64);
                c_n = __int_as_float(__shfl(pr.y, lanebase + j + 1, 64));
                v_n = hx4[(size_t)s_n * 16 + lane16];     // prefetch next neighbor row
            }
            acc.x = fmaf(c_cur, v_cur.x, acc.x);
            acc.y = fmaf(c_cur, v_cur.y, acc.y);
            acc.z = fmaf(c_cur, v_cur.z, acc.z);
            acc.w = fmaf(c_cur, v_cur.w, acc.w);
            s_cur = s_n; c_cur = c_n; v_cur = v_n;
        }
    }
    acc.x = fmaxf(acc.x, 0.f); acc.y = fmaxf(acc.y, 0.f);
    acc.z = fmaxf(acc.z, 0.f); acc.w = fmaxf(acc.w, 0.f);
    out4[(size_t)node * 16 + lane16] = acc;
    // fused hp = h . Wp (group reduction over 16 lanes)
    float4 w4 = wp4[lane16];
    float t = acc.x * w4.x + acc.y * w4.y + acc.z * w4.z + acc.w * w4.w;
    t += __shfl_xor(t, 1, 64); t += __shfl_xor(t, 2, 64);
    t += __shfl_xor(t, 4, 64); t += __shfl_xor(t, 8, 64);
    if (lane16 == 0) hp[node] = t;
}

// ---- fused per-graph tail: score conv (hp staged in LDS) + exact top-k rank +
// gated gather + [gmp||gap] readout; FINAL also folds the (x1+x2)/2 combine. ----
// rank = #(s[j] > s[i]) + #(s[j]==s[i] && j<i)  (exact jax.lax.top_k order)
template <int NPG, int K, bool FINAL>
__global__ __launch_bounds__(512)
void score_pool_kernel(const float* __restrict__ hp, const int2* __restrict__ pairs,
                       const int* __restrict__ rowstart, const int* __restrict__ rowcnt,
                       const float* __restrict__ dinv, const float* __restrict__ bp,
                       const float4* __restrict__ h4, int* __restrict__ nid,
                       float4* __restrict__ xn4, float* __restrict__ xr,
                       const float* __restrict__ x1r, float* __restrict__ out) {
    __shared__ float  shp[NPG];
    __shared__ float  ssc[NPG];
    __shared__ int    lperm[K];
    __shared__ float  lgate[K];
    __shared__ float4 smx[32][16];
    __shared__ float4 ssm[32][16];
    int g = blockIdx.x, base = g * NPG;
    for (int i = threadIdx.x; i < NPG; i += 512) shp[i] = hp[base + i];
    __syncthreads();
    // score conv: edge sums read LDS hp
    for (int i = threadIdx.x; i < NPG; i += 512) {
        int st = rowstart[base + i], cn = rowcnt[base + i];
        float di = dinv[base + i];
        float acc = fmaf(shp[i], di * di, bp[0]);
        for (int j = 0; j < cn; ++j) {
            int2 pr = pairs[st + j];
            acc = fmaf(__int_as_float(pr.y), shp[pr.x - base], acc);
        }
        ssc[i] = acc;
    }
    __syncthreads();
    // exact top-k rank
    for (int i = threadIdx.x; i < NPG; i += 512) {
        float si = ssc[i];
        int rank = 0;
        for (int j = 0; j < NPG; ++j) {
            float sj = ssc[j];
            rank += (sj > si) || (sj == si && j < i);
        }
        if (rank < K) {
            nid[base + i] = g * K + rank;
            lperm[rank]   = i;
            lgate[rank]   = tanhf(si);
        } else {
            nid[base + i] = -1;
        }
    }
    __syncthreads();
    // gated gather + readout
    int q16 = threadIdx.x & 15;
    int jg  = threadIdx.x >> 4;              // 0..31
    float4 mx = make_float4(-3.402823466e38f, -3.402823466e38f, -3.402823466e38f, -3.402823466e38f);
    float4 sm = make_float4(0.f, 0.f, 0.f, 0.f);
    for (int j = jg; j < K; j += 32) {
        float gt = lgate[j];
        float4 v = h4[(size_t)(base + lperm[j]) * 16 + q16];
        v.x *= gt; v.y *= gt; v.z *= gt; v.w *= gt;
        xn4[((size_t)g * K + j) * 16 + q16] = v;
        mx.x = fmaxf(mx.x, v.x); mx.y = fmaxf(mx.y, v.y);
        mx.z = fmaxf(mx.z, v.z); mx.w = fmaxf(mx.w, v.w);
        sm.x += v.x; sm.y += v.y; sm.z += v.z; sm.w += v.w;
    }
    smx[jg][q16] = mx; ssm[jg][q16] = sm;
    __syncthreads();
    if (jg == 0) {
#pragma unroll
        for (int t = 1; t < 32; ++t) {
            float4 a = smx[t][q16], b = ssm[t][q16];
            mx.x = fmaxf(mx.x, a.x); mx.y = fmaxf(mx.y, a.y);
            mx.z = fmaxf(mx.z, a.z); mx.w = fmaxf(mx.w, a.w);
            sm.x += b.x; sm.y += b.y; sm.z += b.z; sm.w += b.w;
        }
        float invK = 1.f / K;
        int c = q16 * 4;
        float mr[4] = {mx.x, mx.y, mx.z, mx.w};
        float ar[4] = {sm.x * invK, sm.y * invK, sm.z * invK, sm.w * invK};
#pragma unroll
        for (int u = 0; u < 4; ++u) {
            if (FINAL) {
                out[g * 128 + c + u]      = 0.5f * (x1r[g * 128 + c + u]      + mr[u]);
                out[g * 128 + 64 + c + u] = 0.5f * (x1r[g * 128 + 64 + c + u] + ar[u]);
            } else {
                xr[g * 128 + c + u]      = mr[u];
                xr[g * 128 + 64 + c + u] = ar[u];
            }
        }
    }
}

extern "C" void kernel_launch(void* const* d_in, const int* in_sizes, int n_in,
                              void* d_out, int out_size, void* d_ws, size_t ws_size,
                              hipStream_t stream) {
    const float* x    = (const float*)d_in[0];
    const float* eatt = (const float*)d_in[1];
    const float* W1   = (const float*)d_in[2];
    const float* b1   = (const float*)d_in[3];
    const float* Wp1  = (const float*)d_in[4];
    const float* bp1  = (const float*)d_in[5];
    const float* W2   = (const float*)d_in[6];
    const float* b2   = (const float*)d_in[7];
    const float* Wp2  = (const float*)d_in[8];
    const float* bp2  = (const float*)d_in[9];
    const int*   esrc = (const int*)d_in[10];
    const int*   edst = (const int*)d_in[11];
    float* out = (float*)d_out;

    // workspace (~87 MB of floats); A/B regions reused across stages
    float* ws = (float*)d_ws;
    size_t o = 0;
    float* A    = ws + o; o += (size_t)N0 * 64;   // hx1 -> {xn1 | hx2} -> xn2
    float* Bb   = ws + o; o += (size_t)N0 * 64;   // h1 -> h2
    int2*  prs  = (int2*)(ws + o); o += (size_t)NE * 2;  // (src,coef) per CSR slot
    int*   rst  = (int*)(ws + o); o += N0;
    int*   rcn  = (int*)(ws + o); o += N0;
    float* dinv = ws + o; o += N0;
    float* hp   = ws + o; o += N0;
    int*   nid  = (int*)(ws + o); o += N0;        // nid1; reused as nid2
    float* x1r  = ws + o; o += BG * 128;

    float* hx1 = A;
    float* h1  = Bb;
    float* xn1 = A;                        // after hx1 dead
    float* hx2 = A + (size_t)N1_ * 64;
    float* h2  = Bb;                       // after h1 dead
    float* xn2 = A;                        // after xn1 dead

    // ---- stage 1 ----
    stage_head_kernel<NN, false><<<BG + 512, 512, 0, stream>>>(
        esrc, edst, eatt, nullptr, prs, rst, rcn, dinv,
        (const float4*)x, (const float4*)W1, (float4*)hx1, N0, 512);
    gather_feat_kernel<NN><<<BG * (NN / 16), 256, 0, stream>>>(
        (const float4*)hx1, prs, rst, rcn, dinv, (const float4*)b1, (const float4*)Wp1, hp, (float4*)h1);
    score_pool_kernel<NN, K1, false><<<BG, 512, 0, stream>>>(
        hp, prs, rst, rcn, dinv, bp1, (const float4*)h1, nid, (float4*)xn1, x1r, nullptr, nullptr);
    // ---- stage 2 ----
    stage_head_kernel<K1, true><<<BG + 256, 512, 0, stream>>>(
        esrc, edst, eatt, nid, prs, rst, rcn, dinv,
        (const float4*)xn1, (const float4*)W2, (float4*)hx2, N1_, 256);
    gather_feat_kernel<K1><<<BG * (K1 / 16), 256, 0, stream>>>(
        (const float4*)hx2, prs, rst, rcn, dinv, (const float4*)b2, (const float4*)Wp2, hp, (float4*)h2);
    score_pool_kernel<K1, K2, true><<<BG, 512, 0, stream>>>(
        hp, prs, rst, rcn, dinv, bp2, (const float4*)h2, nid, (float4*)xn2, nullptr, x1r, out);
}

// Round 8
// 250.225 us; speedup vs baseline: 4.8218x; 1.0285x over previous
//
#include <hip/hip_runtime.h>
#include <math.h>

#define BG   256                   // graphs
#define NN   512                   // nodes per graph
#define EPG  (NN * 16)             // 8192 edges per graph
#define NE   (BG * EPG)            // 2097152 edges
#define N0   (BG * NN)             // 131072
#define K1   256
#define N1_  (BG * K1)             // 65536
#define K2   128
#define N2_  (BG * K2)             // 32768

__device__ __forceinline__ float4 f4fma(float s, float4 a, float4 c) {
    c.x = fmaf(s, a.x, c.x); c.y = fmaf(s, a.y, c.y);
    c.z = fmaf(s, a.z, c.z); c.w = fmaf(s, a.w, c.w);
    return c;
}

// ---- fused stage head (512 threads/block):
// blocks [0,BG): CSR build for graph g — edges register-cached (one global
// read pass), LDS count + wave-shuffle scan (2 barriers, not 18), slot
// assignment via one atomic pass, then scatter/flush through a 32 KB LDS
// staging buffer in two 4096-slot ranges (coalesced pair write-out).
// blocks [BG, BG+mmb): 64x64 GEMM Y = X @ W, two 256-thread tile pipelines.
// Static LDS = 52 KB -> 3 blocks/CU for both branches.
template <int NPG, bool REMAP>
__global__ __launch_bounds__(512)
void stage_head_kernel(const int* __restrict__ esrc, const int* __restrict__ edst,
                       const float* __restrict__ eatt, const int* __restrict__ nid,
                       int2* __restrict__ pairs, int* __restrict__ rowstart,
                       int* __restrict__ rowcnt, float* __restrict__ dinv,
                       const float4* __restrict__ X4, const float4* __restrict__ W4,
                       float4* __restrict__ Y4, int nrows, int mmb) {
    __shared__ __align__(16) char smem[52224];   // max(csr 41K, gemm 51K)
    if ((int)blockIdx.x < BG) {
        // ---------------- CSR build for graph g ----------------
        int2*  lpair = (int2*)smem;                      // [4096] staging, 32 KB
        int*   cnt   = (int*)(smem + 32768);             // [NPG]
        float* wsum  = (float*)(smem + 32768) + NPG;     // [NPG]
        int*   scn   = (int*)(smem + 32768) + 2 * NPG;   // [NPG]
        float* sdinv = (float*)(smem + 32768) + 3 * NPG; // [NPG]
        int*   wtot  = (int*)(smem + 32768) + 4 * NPG;   // [8]
        int g = blockIdx.x;
        int e0 = g * EPG, nbase = g * NPG;
        for (int ii = threadIdx.x; ii < NPG; ii += 512) { cnt[ii] = 0; wsum[ii] = 0.f; }
        __syncthreads();
        const int4*   edst4 = (const int4*)(edst + e0);
        const int4*   esrc4 = (const int4*)(esrc + e0);
        const float4* eatt4 = (const float4*)(eatt + e0);
        int ed[16]; int es[16]; float ea[16];
#pragma unroll
        for (int c = 0; c < 4; ++c) {            // single global read pass
            int ch = threadIdx.x + c * 512;
            int4   dd = edst4[ch];
            int4   ss = esrc4[ch];
            float4 ww = eatt4[ch];
            ed[c * 4 + 0] = dd.x; ed[c * 4 + 1] = dd.y; ed[c * 4 + 2] = dd.z; ed[c * 4 + 3] = dd.w;
            es[c * 4 + 0] = ss.x; es[c * 4 + 1] = ss.y; es[c * 4 + 2] = ss.z; es[c * 4 + 3] = ss.w;
            ea[c * 4 + 0] = ww.x; ea[c * 4 + 1] = ww.y; ea[c * 4 + 2] = ww.z; ea[c * 4 + 3] = ww.w;
        }
        if (REMAP) {
#pragma unroll
            for (int j = 0; j < 16; ++j) { ed[j] = nid[ed[j]]; es[j] = nid[es[j]]; }
        }
        // pass 1: counts + weighted degree (from registers)
#pragma unroll
        for (int j = 0; j < 16; ++j) {
            bool valid = !REMAP || (ed[j] >= 0 && es[j] >= 0);
            if (valid) {
                int dl = ed[j] - nbase;
                atomicAdd(&cnt[dl], 1);
                atomicAdd(&wsum[dl], ea[j]);
            }
        }
        __syncthreads();
        // wave-shuffle scan of cnt[0..NPG)
        int i = threadIdx.x;
        int lane = i & 63, wvid = i >> 6;
        int xval = (i < NPG) ? cnt[i] : 0;
        int xs = xval;
#pragma unroll
        for (int off = 1; off < 64; off <<= 1) {
            int v = __shfl_up(xs, off, 64);
            if (lane >= off) xs += v;
        }
        if (lane == 63) wtot[wvid] = xs;
        __syncthreads();
        int woff = 0, total = 0;
#pragma unroll
        for (int t = 0; t < 8; ++t) {
            int wt = wtot[t];
            if (t < wvid) woff += wt;
            total += wt;
        }
        xs += woff;                              // inclusive scan
        if (i < NPG) {
            int st = xs - xval;                  // exclusive
            rowstart[nbase + i] = e0 + st;
            rowcnt[nbase + i]   = xval;
            float di = rsqrtf(wsum[i] + 1.0f);
            dinv[nbase + i] = di;
            sdinv[i] = di;
            scn[i] = st;                          // running slot offset
        }
        __syncthreads();
        // slot assignment + coef (one atomic pass, results in registers)
        int slots[16]; float cf[16];
#pragma unroll
        for (int j = 0; j < 16; ++j) {
            bool valid = !REMAP || (ed[j] >= 0 && es[j] >= 0);
            slots[j] = -1;
            if (valid) {
                int dl = ed[j] - nbase, sl = es[j] - nbase;
                cf[j] = sdinv[dl] * ea[j] * sdinv[sl];
                slots[j] = atomicAdd(&scn[dl], 1);
            }
        }
        // range 0: slots [0,4096)
#pragma unroll
        for (int j = 0; j < 16; ++j)
            if (slots[j] >= 0 && slots[j] < 4096)
                lpair[slots[j]] = make_int2(es[j], __float_as_int(cf[j]));
        __syncthreads();
        int n0 = total < 4096 ? total : 4096;
        for (int k = threadIdx.x; k < n0; k += 512) pairs[e0 + k] = lpair[k];
        __syncthreads();
        // range 1: slots [4096,8192)
        if (total > 4096) {
#pragma unroll
            for (int j = 0; j < 16; ++j)
                if (slots[j] >= 4096)
                    lpair[slots[j] - 4096] = make_int2(es[j], __float_as_int(cf[j]));
            __syncthreads();
            int n1 = total - 4096;
            for (int k = threadIdx.x; k < n1; k += 512) pairs[e0 + 4096 + k] = lpair[k];
        }
    } else {
        // ---------------- GEMM: Y[nrows,64] = X @ W ----------------
        float (*sW)[68] = (float (*)[68])smem;                       // 17408 B
        int p = threadIdx.x >> 8;                                    // pipeline 0/1
        int t = threadIdx.x & 255;
        float (*sX)[68] = (float (*)[68])(smem + 17408 + p * 17408);
#pragma unroll
        for (int u = 0; u < 2; ++u) {            // stage W once (all 512 threads)
            int idx = threadIdx.x + u * 512;
            int r = idx >> 4, c4 = idx & 15;
            *(float4*)&sW[r][c4 * 4] = W4[idx];
        }
        int mb = blockIdx.x - BG;
        int ntiles = nrows >> 6;
        int rg = t >> 4, cg = t & 15;
        for (int tile = mb * 2 + p; tile < ntiles; tile += mmb * 2) {
            __syncthreads();                     // protect sX reuse; covers sW stage
            int row0 = tile << 6;
#pragma unroll
            for (int u = 0; u < 4; ++u) {        // stage 64 rows of X
                int idx = t + u * 256;
                int r = idx >> 4, c4 = idx & 15;
                *(float4*)&sX[r][c4 * 4] = X4[(size_t)(row0 + r) * 16 + c4];
            }
            __syncthreads();
            float4 acc0 = make_float4(0.f, 0.f, 0.f, 0.f);
            float4 acc1 = acc0, acc2 = acc0, acc3 = acc0;
#pragma unroll
            for (int k4 = 0; k4 < 16; ++k4) {
                float4 xv0 = *(const float4*)&sX[rg * 4 + 0][k4 * 4];
                float4 xv1 = *(const float4*)&sX[rg * 4 + 1][k4 * 4];
                float4 xv2 = *(const float4*)&sX[rg * 4 + 2][k4 * 4];
                float4 xv3 = *(const float4*)&sX[rg * 4 + 3][k4 * 4];
                float4 wv0 = *(const float4*)&sW[k4 * 4 + 0][cg * 4];
                float4 wv1 = *(const float4*)&sW[k4 * 4 + 1][cg * 4];
                float4 wv2 = *(const float4*)&sW[k4 * 4 + 2][cg * 4];
                float4 wv3 = *(const float4*)&sW[k4 * 4 + 3][cg * 4];
                acc0 = f4fma(xv0.x, wv0, acc0); acc0 = f4fma(xv0.y, wv1, acc0);
                acc0 = f4fma(xv0.z, wv2, acc0); acc0 = f4fma(xv0.w, wv3, acc0);
                acc1 = f4fma(xv1.x, wv0, acc1); acc1 = f4fma(xv1.y, wv1, acc1);
                acc1 = f4fma(xv1.z, wv2, acc1); acc1 = f4fma(xv1.w, wv3, acc1);
                acc2 = f4fma(xv2.x, wv0, acc2); acc2 = f4fma(xv2.y, wv1, acc2);
                acc2 = f4fma(xv2.z, wv2, acc2); acc2 = f4fma(xv2.w, wv3, acc2);
                acc3 = f4fma(xv3.x, wv0, acc3); acc3 = f4fma(xv3.y, wv1, acc3);
                acc3 = f4fma(xv3.z, wv2, acc3); acc3 = f4fma(xv3.w, wv3, acc3);
            }
            size_t ob = (size_t)(row0 + rg * 4) * 16 + cg;
            Y4[ob]      = acc0;
            Y4[ob + 16] = acc1;
            Y4[ob + 32] = acc2;
            Y4[ob + 48] = acc3;
        }
    }
}

// ---- gather conv: wave = 4 nodes x 16 lanes (float4 feats); 4-deep
// software-pipelined neighbor loads; fused self+bias, relu, hp = relu(h).Wp.
// XCD-swizzled so one graph stays on one XCD. ----
template <int NPG>
__global__ __launch_bounds__(256)
void gather_feat_kernel(const float4* __restrict__ hx4, const int2* __restrict__ pairs,
                        const int* __restrict__ rowstart, const int* __restrict__ rowcnt,
                        const float* __restrict__ dinv, const float4* __restrict__ b4,
                        const float4* __restrict__ wp4, float* __restrict__ hp,
                        float4* __restrict__ out4) {
    constexpr int BPG = NPG / 16;           // blocks per graph
    int i   = blockIdx.x;
    int xcd = i & 7;
    int k   = i >> 3;
    int g     = xcd * (BG / 8) + k / BPG;   // all BPG blocks of graph g on one XCD
    int chunk = k % BPG;
    int lane16 = threadIdx.x & 15;
    int sub    = (threadIdx.x >> 4) & 3;
    int wv     = threadIdx.x >> 6;
    int lanebase = (threadIdx.x & 63) & 48; // sub*16
    int node = g * NPG + chunk * 16 + wv * 4 + sub;

    float di = dinv[node];
    int st = rowstart[node], cn = rowcnt[node];
    float4 acc = hx4[(size_t)node * 16 + lane16];
    float dii = di * di;
    float4 bb = b4[lane16];
    acc.x = fmaf(acc.x, dii, bb.x);
    acc.y = fmaf(acc.y, dii, bb.y);
    acc.z = fmaf(acc.z, dii, bb.z);
    acc.w = fmaf(acc.w, dii, bb.w);

    for (int eb = 0; eb < cn; eb += 16) {
        int m = cn - eb; if (m > 16) m = 16;
        int2 pr = make_int2(0, 0);
        if (lane16 < m) pr = pairs[st + eb + lane16];
        float4 vbuf[4];
#pragma unroll
        for (int j0 = 0; j0 < 4; ++j0) {         // prime 4 loads
            if (j0 < m) {
                int s = __shfl(pr.x, lanebase + j0, 64);
                vbuf[j0] = hx4[(size_t)s * 16 + lane16];
            }
        }
        for (int jb = 0; jb < m; jb += 4) {
#pragma unroll
            for (int u = 0; u < 4; ++u) {
                int j = jb + u;
                if (j < m) {
                    float c = __int_as_float(__shfl(pr.y, lanebase + j, 64));
                    float4 v = vbuf[u];
                    int jn = j + 4;
                    if (jn < m) {
                        int s = __shfl(pr.x, lanebase + jn, 64);
                        vbuf[u] = hx4[(size_t)s * 16 + lane16];   // refill slot
                    }
                    acc = f4fma(c, v, acc);
                }
            }
        }
    }
    acc.x = fmaxf(acc.x, 0.f); acc.y = fmaxf(acc.y, 0.f);
    acc.z = fmaxf(acc.z, 0.f); acc.w = fmaxf(acc.w, 0.f);
    out4[(size_t)node * 16 + lane16] = acc;
    // fused hp = h . Wp (group reduction over 16 lanes)
    float4 w4 = wp4[lane16];
    float t = acc.x * w4.x + acc.y * w4.y + acc.z * w4.z + acc.w * w4.w;
    t += __shfl_xor(t, 1, 64); t += __shfl_xor(t, 2, 64);
    t += __shfl_xor(t, 4, 64); t += __shfl_xor(t, 8, 64);
    if (lane16 == 0) hp[node] = t;
}

// ---- fused per-graph tail: score conv (hp staged in LDS) + exact top-k rank +
// gated gather + [gmp||gap] readout; FINAL also folds the (x1+x2)/2 combine. ----
// rank = #(s[j] > s[i]) + #(s[j]==s[i] && j<i)  (exact jax.lax.top_k order)
template <int NPG, int K, bool FINAL>
__global__ __launch_bounds__(512)
void score_pool_kernel(const float* __restrict__ hp, const int2* __restrict__ pairs,
                       const int* __restrict__ rowstart, const int* __restrict__ rowcnt,
                       const float* __restrict__ dinv, const float* __restrict__ bp,
                       const float4* __restrict__ h4, int* __restrict__ nid,
                       float4* __restrict__ xn4, float* __restrict__ xr,
                       const float* __restrict__ x1r, float* __restrict__ out) {
    __shared__ float  shp[NPG];
    __shared__ float  ssc[NPG];
    __shared__ int    lperm[K];
    __shared__ float  lgate[K];
    __shared__ float4 smx[32][16];
    __shared__ float4 ssm[32][16];
    int g = blockIdx.x, base = g * NPG;
    for (int i = threadIdx.x; i < NPG; i += 512) shp[i] = hp[base + i];
    __syncthreads();
    // score conv: edge sums read LDS hp
    for (int i = threadIdx.x; i < NPG; i += 512) {
        int st = rowstart[base + i], cn = rowcnt[base + i];
        float di = dinv[base + i];
        float acc = fmaf(shp[i], di * di, bp[0]);
        for (int j = 0; j < cn; ++j) {
            int2 pr = pairs[st + j];
            acc = fmaf(__int_as_float(pr.y), shp[pr.x - base], acc);
        }
        ssc[i] = acc;
    }
    __syncthreads();
    // exact top-k rank
    for (int i = threadIdx.x; i < NPG; i += 512) {
        float si = ssc[i];
        int rank = 0;
        for (int j = 0; j < NPG; ++j) {
            float sj = ssc[j];
            rank += (sj > si) || (sj == si && j < i);
        }
        if (rank < K) {
            nid[base + i] = g * K + rank;
            lperm[rank]   = i;
            lgate[rank]   = tanhf(si);
        } else {
            nid[base + i] = -1;
        }
    }
    __syncthreads();
    // gated gather + readout
    int q16 = threadIdx.x & 15;
    int jg  = threadIdx.x >> 4;              // 0..31
    float4 mx = make_float4(-3.402823466e38f, -3.402823466e38f, -3.402823466e38f, -3.402823466e38f);
    float4 sm = make_float4(0.f, 0.f, 0.f, 0.f);
    for (int j = jg; j < K; j += 32) {
        float gt = lgate[j];
        float4 v = h4[(size_t)(base + lperm[j]) * 16 + q16];
        v.x *= gt; v.y *= gt; v.z *= gt; v.w *= gt;
        xn4[((size_t)g * K + j) * 16 + q16] = v;
        mx.x = fmaxf(mx.x, v.x); mx.y = fmaxf(mx.y, v.y);
        mx.z = fmaxf(mx.z, v.z); mx.w = fmaxf(mx.w, v.w);
        sm.x += v.x; sm.y += v.y; sm.z += v.z; sm.w += v.w;
    }
    smx[jg][q16] = mx; ssm[jg][q16] = sm;
    __syncthreads();
    if (jg == 0) {
#pragma unroll
        for (int t = 1; t < 32; ++t) {
            float4 a = smx[t][q16], b = ssm[t][q16];
            mx.x = fmaxf(mx.x, a.x); mx.y = fmaxf(mx.y, a.y);
            mx.z = fmaxf(mx.z, a.z); mx.w = fmaxf(mx.w, a.w);
            sm.x += b.x; sm.y += b.y; sm.z += b.z; sm.w += b.w;
        }
        float invK = 1.f / K;
        int c = q16 * 4;
        float mr[4] = {mx.x, mx.y, mx.z, mx.w};
        float ar[4] = {sm.x * invK, sm.y * invK, sm.z * invK, sm.w * invK};
#pragma unroll
        for (int u = 0; u < 4; ++u) {
            if (FINAL) {
                out[g * 128 + c + u]      = 0.5f * (x1r[g * 128 + c + u]      + mr[u]);
                out[g * 128 + 64 + c + u] = 0.5f * (x1r[g * 128 + 64 + c + u] + ar[u]);
            } else {
                xr[g * 128 + c + u]      = mr[u];
                xr[g * 128 + 64 + c + u] = ar[u];
            }
        }
    }
}

extern "C" void kernel_launch(void* const* d_in, const int* in_sizes, int n_in,
                              void* d_out, int out_size, void* d_ws, size_t ws_size,
                              hipStream_t stream) {
    const float* x    = (const float*)d_in[0];
    const float* eatt = (const float*)d_in[1];
    const float* W1   = (const float*)d_in[2];
    const float* b1   = (const float*)d_in[3];
    const float* Wp1  = (const float*)d_in[4];
    const float* bp1  = (const float*)d_in[5];
    const float* W2   = (const float*)d_in[6];
    const float* b2   = (const float*)d_in[7];
    const float* Wp2  = (const float*)d_in[8];
    const float* bp2  = (const float*)d_in[9];
    const int*   esrc = (const int*)d_in[10];
    const int*   edst = (const int*)d_in[11];
    float* out = (float*)d_out;

    // workspace (~87 MB of floats); A/B regions reused across stages
    float* ws = (float*)d_ws;
    size_t o = 0;
    float* A    = ws + o; o += (size_t)N0 * 64;   // hx1 -> {xn1 | hx2} -> xn2
    float* Bb   = ws + o; o += (size_t)N0 * 64;   // h1 -> h2
    int2*  prs  = (int2*)(ws + o); o += (size_t)NE * 2;  // (src,coef) per CSR slot
    int*   rst  = (int*)(ws + o); o += N0;
    int*   rcn  = (int*)(ws + o); o += N0;
    float* dinv = ws + o; o += N0;
    float* hp   = ws + o; o += N0;
    int*   nid  = (int*)(ws + o); o += N0;        // nid1; reused as nid2
    float* x1r  = ws + o; o += BG * 128;

    float* hx1 = A;
    float* h1  = Bb;
    float* xn1 = A;                        // after hx1 dead
    float* hx2 = A + (size_t)N1_ * 64;
    float* h2  = Bb;                       // after h1 dead
    float* xn2 = A;                        // after xn1 dead

    // ---- stage 1 ----
    stage_head_kernel<NN, false><<<BG + 512, 512, 0, stream>>>(
        esrc, edst, eatt, nullptr, prs, rst, rcn, dinv,
        (const float4*)x, (const float4*)W1, (float4*)hx1, N0, 512);
    gather_feat_kernel<NN><<<BG * (NN / 16), 256, 0, stream>>>(
        (const float4*)hx1, prs, rst, rcn, dinv, (const float4*)b1, (const float4*)Wp1, hp, (float4*)h1);
    score_pool_kernel<NN, K1, false><<<BG, 512, 0, stream>>>(
        hp, prs, rst, rcn, dinv, bp1, (const float4*)h1, nid, (float4*)xn1, x1r, nullptr, nullptr);
    // ---- stage 2 ----
    stage_head_kernel<K1, true><<<BG + 256, 512, 0, stream>>>(
        esrc, edst, eatt, nid, prs, rst, rcn, dinv,
        (const float4*)xn1, (const float4*)W2, (float4*)hx2, N1_, 256);
    gather_feat_kernel<K1><<<BG * (K1 / 16), 256, 0, stream>>>(
        (const float4*)hx2, prs, rst, rcn, dinv, (const float4*)b2, (const float4*)Wp2, hp, (float4*)h2);
    score_pool_kernel<K1, K2, true><<<BG, 512, 0, stream>>>(
        hp, prs, rst, rcn, dinv, bp2, (const float4*)h2, nid, (float4*)xn2, nullptr, x1r, out);
}

// Round 9
// 247.185 us; speedup vs baseline: 4.8811x; 1.0123x over previous
//
#include <hip/hip_runtime.h>
#include <math.h>

#define BG   256                   // graphs
#define NN   512                   // nodes per graph
#define EPG  (NN * 16)             // 8192 edges per graph
#define NE   (BG * EPG)            // 2097152 edges
#define N0   (BG * NN)             // 131072
#define K1   256
#define N1_  (BG * K1)             // 65536
#define K2   128
#define N2_  (BG * K2)             // 32768

__device__ __forceinline__ float4 f4fma(float s, float4 a, float4 c) {
    c.x = fmaf(s, a.x, c.x); c.y = fmaf(s, a.y, c.y);
    c.z = fmaf(s, a.z, c.z); c.w = fmaf(s, a.w, c.w);
    return c;
}

// ---- fused stage head (512 threads/block): unchanged from r8 ----
// blocks [0,BG): CSR build; blocks [BG,BG+mmb): 64x64 GEMM Y = X @ W.
template <int NPG, bool REMAP>
__global__ __launch_bounds__(512)
void stage_head_kernel(const int* __restrict__ esrc, const int* __restrict__ edst,
                       const float* __restrict__ eatt, const int* __restrict__ nid,
                       int2* __restrict__ pairs, int* __restrict__ rowstart,
                       int* __restrict__ rowcnt, float* __restrict__ dinv,
                       const float4* __restrict__ X4, const float4* __restrict__ W4,
                       float4* __restrict__ Y4, int nrows, int mmb) {
    __shared__ __align__(16) char smem[52224];   // max(csr 41K, gemm 51K)
    if ((int)blockIdx.x < BG) {
        int2*  lpair = (int2*)smem;                      // [4096] staging, 32 KB
        int*   cnt   = (int*)(smem + 32768);             // [NPG]
        float* wsum  = (float*)(smem + 32768) + NPG;     // [NPG]
        int*   scn   = (int*)(smem + 32768) + 2 * NPG;   // [NPG]
        float* sdinv = (float*)(smem + 32768) + 3 * NPG; // [NPG]
        int*   wtot  = (int*)(smem + 32768) + 4 * NPG;   // [8]
        int g = blockIdx.x;
        int e0 = g * EPG, nbase = g * NPG;
        for (int ii = threadIdx.x; ii < NPG; ii += 512) { cnt[ii] = 0; wsum[ii] = 0.f; }
        __syncthreads();
        const int4*   edst4 = (const int4*)(edst + e0);
        const int4*   esrc4 = (const int4*)(esrc + e0);
        const float4* eatt4 = (const float4*)(eatt + e0);
        int ed[16]; int es[16]; float ea[16];
#pragma unroll
        for (int c = 0; c < 4; ++c) {            // single global read pass
            int ch = threadIdx.x + c * 512;
            int4   dd = edst4[ch];
            int4   ss = esrc4[ch];
            float4 ww = eatt4[ch];
            ed[c * 4 + 0] = dd.x; ed[c * 4 + 1] = dd.y; ed[c * 4 + 2] = dd.z; ed[c * 4 + 3] = dd.w;
            es[c * 4 + 0] = ss.x; es[c * 4 + 1] = ss.y; es[c * 4 + 2] = ss.z; es[c * 4 + 3] = ss.w;
            ea[c * 4 + 0] = ww.x; ea[c * 4 + 1] = ww.y; ea[c * 4 + 2] = ww.z; ea[c * 4 + 3] = ww.w;
        }
        if (REMAP) {
#pragma unroll
            for (int j = 0; j < 16; ++j) { ed[j] = nid[ed[j]]; es[j] = nid[es[j]]; }
        }
#pragma unroll
        for (int j = 0; j < 16; ++j) {
            bool valid = !REMAP || (ed[j] >= 0 && es[j] >= 0);
            if (valid) {
                int dl = ed[j] - nbase;
                atomicAdd(&cnt[dl], 1);
                atomicAdd(&wsum[dl], ea[j]);
            }
        }
        __syncthreads();
        // wave-shuffle scan of cnt[0..NPG)
        int i = threadIdx.x;
        int lane = i & 63, wvid = i >> 6;
        int xval = (i < NPG) ? cnt[i] : 0;
        int xs = xval;
#pragma unroll
        for (int off = 1; off < 64; off <<= 1) {
            int v = __shfl_up(xs, off, 64);
            if (lane >= off) xs += v;
        }
        if (lane == 63) wtot[wvid] = xs;
        __syncthreads();
        int woff = 0, total = 0;
#pragma unroll
        for (int t = 0; t < 8; ++t) {
            int wt = wtot[t];
            if (t < wvid) woff += wt;
            total += wt;
        }
        xs += woff;                              // inclusive scan
        if (i < NPG) {
            int st = xs - xval;                  // exclusive
            rowstart[nbase + i] = e0 + st;
            rowcnt[nbase + i]   = xval;
            float di = rsqrtf(wsum[i] + 1.0f);
            dinv[nbase + i] = di;
            sdinv[i] = di;
            scn[i] = st;                          // running slot offset
        }
        __syncthreads();
        int slots[16]; float cf[16];
#pragma unroll
        for (int j = 0; j < 16; ++j) {
            bool valid = !REMAP || (ed[j] >= 0 && es[j] >= 0);
            slots[j] = -1;
            if (valid) {
                int dl = ed[j] - nbase, sl = es[j] - nbase;
                cf[j] = sdinv[dl] * ea[j] * sdinv[sl];
                slots[j] = atomicAdd(&scn[dl], 1);
            }
        }
#pragma unroll
        for (int j = 0; j < 16; ++j)
            if (slots[j] >= 0 && slots[j] < 4096)
                lpair[slots[j]] = make_int2(es[j], __float_as_int(cf[j]));
        __syncthreads();
        int n0 = total < 4096 ? total : 4096;
        for (int k = threadIdx.x; k < n0; k += 512) pairs[e0 + k] = lpair[k];
        __syncthreads();
        if (total > 4096) {
#pragma unroll
            for (int j = 0; j < 16; ++j)
                if (slots[j] >= 4096)
                    lpair[slots[j] - 4096] = make_int2(es[j], __float_as_int(cf[j]));
            __syncthreads();
            int n1 = total - 4096;
            for (int k = threadIdx.x; k < n1; k += 512) pairs[e0 + 4096 + k] = lpair[k];
        }
    } else {
        // ---------------- GEMM: Y[nrows,64] = X @ W ----------------
        float (*sW)[68] = (float (*)[68])smem;                       // 17408 B
        int p = threadIdx.x >> 8;                                    // pipeline 0/1
        int t = threadIdx.x & 255;
        float (*sX)[68] = (float (*)[68])(smem + 17408 + p * 17408);
#pragma unroll
        for (int u = 0; u < 2; ++u) {            // stage W once (all 512 threads)
            int idx = threadIdx.x + u * 512;
            int r = idx >> 4, c4 = idx & 15;
            *(float4*)&sW[r][c4 * 4] = W4[idx];
        }
        int mb = blockIdx.x - BG;
        int ntiles = nrows >> 6;
        int rg = t >> 4, cg = t & 15;
        for (int tile = mb * 2 + p; tile < ntiles; tile += mmb * 2) {
            __syncthreads();                     // protect sX reuse; covers sW stage
            int row0 = tile << 6;
#pragma unroll
            for (int u = 0; u < 4; ++u) {        // stage 64 rows of X
                int idx = t + u * 256;
                int r = idx >> 4, c4 = idx & 15;
                *(float4*)&sX[r][c4 * 4] = X4[(size_t)(row0 + r) * 16 + c4];
            }
            __syncthreads();
            float4 acc0 = make_float4(0.f, 0.f, 0.f, 0.f);
            float4 acc1 = acc0, acc2 = acc0, acc3 = acc0;
#pragma unroll
            for (int k4 = 0; k4 < 16; ++k4) {
                float4 xv0 = *(const float4*)&sX[rg * 4 + 0][k4 * 4];
                float4 xv1 = *(const float4*)&sX[rg * 4 + 1][k4 * 4];
                float4 xv2 = *(const float4*)&sX[rg * 4 + 2][k4 * 4];
                float4 xv3 = *(const float4*)&sX[rg * 4 + 3][k4 * 4];
                float4 wv0 = *(const float4*)&sW[k4 * 4 + 0][cg * 4];
                float4 wv1 = *(const float4*)&sW[k4 * 4 + 1][cg * 4];
                float4 wv2 = *(const float4*)&sW[k4 * 4 + 2][cg * 4];
                float4 wv3 = *(const float4*)&sW[k4 * 4 + 3][cg * 4];
                acc0 = f4fma(xv0.x, wv0, acc0); acc0 = f4fma(xv0.y, wv1, acc0);
                acc0 = f4fma(xv0.z, wv2, acc0); acc0 = f4fma(xv0.w, wv3, acc0);
                acc1 = f4fma(xv1.x, wv0, acc1); acc1 = f4fma(xv1.y, wv1, acc1);
                acc1 = f4fma(xv1.z, wv2, acc1); acc1 = f4fma(xv1.w, wv3, acc1);
                acc2 = f4fma(xv2.x, wv0, acc2); acc2 = f4fma(xv2.y, wv1, acc2);
                acc2 = f4fma(xv2.z, wv2, acc2); acc2 = f4fma(xv2.w, wv3, acc2);
                acc3 = f4fma(xv3.x, wv0, acc3); acc3 = f4fma(xv3.y, wv1, acc3);
                acc3 = f4fma(xv3.z, wv2, acc3); acc3 = f4fma(xv3.w, wv3, acc3);
            }
            size_t ob = (size_t)(row0 + rg * 4) * 16 + cg;
            Y4[ob]      = acc0;
            Y4[ob + 16] = acc1;
            Y4[ob + 32] = acc2;
            Y4[ob + 48] = acc3;
        }
    }
}

// ---- per-graph megafused tail: block = graph, 512 threads.
// Phase 1: stage hx (NPG x 64 f32, stride 68) into LDS.
// Phase 2: conv -> h kept in REGISTERS (acc[PASSES] float4/thread); neighbor
//          rows via ds_read_b128; (src,coef) via group-uniform 8B global load
//          (no shfl); fused self+bias+relu and hp = h . Wp.
// Phase 3 (hx dead, LDS reused): score conv from LDS hp, exact top-k rank,
//          nid write, gated xn write (selected rows only), [gmp||gap] readout;
//          FINAL folds the (x1+x2)/2 combine. ----
template <int NPG, int K, bool FINAL>
__global__ __launch_bounds__(512)
void tail_kernel(const float4* __restrict__ hx4, const int2* __restrict__ pairs,
                 const int* __restrict__ rowstart, const int* __restrict__ rowcnt,
                 const float* __restrict__ dinv, const float4* __restrict__ b4,
                 const float4* __restrict__ wp4, const float* __restrict__ bp,
                 int* __restrict__ nid, float4* __restrict__ xn4,
                 float* __restrict__ xr, const float* __restrict__ x1r,
                 float* __restrict__ out) {
    constexpr int PASSES = NPG / 32;         // 8 waves x 4 nodes per pass
    __shared__ __align__(16) char smem[NPG * 68 * 4];
    float* shx = (float*)smem;               // [NPG][68] (conv phase)
    float* shp = (float*)smem;               // overlay (post-conv): [NPG]
    float* ssc = (float*)smem + NPG;         // [NPG]
    int*   rnk = (int*)smem + 2 * NPG;       // [NPG]
    float4* smx = (float4*)(smem + 3 * NPG * 4);        // [32][16]
    float4* ssm = smx + 32 * 16;                        // [32][16]

    int g = blockIdx.x, nbase = g * NPG;
    int t = threadIdx.x;
    int lane16 = t & 15, sub = (t >> 4) & 3, wv = t >> 6;
    // phase 1: stage hx
    for (int i = t; i < NPG * 16; i += 512) {
        int r = i >> 4, c4 = i & 15;
        *(float4*)&shx[r * 68 + c4 * 4] = hx4[(size_t)nbase * 16 + i];
    }
    __syncthreads();
    // phase 2: conv (h in registers) + hp
    float4 acc[PASSES];
    float  hpreg[PASSES];
    float4 bb = b4[lane16];
    float4 w4 = wp4[lane16];
#pragma unroll
    for (int p = 0; p < PASSES; ++p) {
        int nl = p * 32 + wv * 4 + sub;
        int node = nbase + nl;
        float di = dinv[node];
        int st = rowstart[node], cn = rowcnt[node];
        float dii = di * di;
        float4 a = *(const float4*)&shx[nl * 68 + lane16 * 4];
        a.x = fmaf(a.x, dii, bb.x);
        a.y = fmaf(a.y, dii, bb.y);
        a.z = fmaf(a.z, dii, bb.z);
        a.w = fmaf(a.w, dii, bb.w);
        for (int j = 0; j < cn; ++j) {
            int2 pr = pairs[st + j];          // group-uniform 8B load
            const float4 v = *(const float4*)&shx[(pr.x - nbase) * 68 + lane16 * 4];
            a = f4fma(__int_as_float(pr.y), v, a);
        }
        a.x = fmaxf(a.x, 0.f); a.y = fmaxf(a.y, 0.f);
        a.z = fmaxf(a.z, 0.f); a.w = fmaxf(a.w, 0.f);
        acc[p] = a;
        float tt = a.x * w4.x + a.y * w4.y + a.z * w4.z + a.w * w4.w;
        tt += __shfl_xor(tt, 1, 64); tt += __shfl_xor(tt, 2, 64);
        tt += __shfl_xor(tt, 4, 64); tt += __shfl_xor(tt, 8, 64);
        hpreg[p] = tt;
    }
    __syncthreads();                         // conv done, shx dead
#pragma unroll
    for (int p = 0; p < PASSES; ++p) {
        int nl = p * 32 + wv * 4 + sub;
        if (lane16 == 0) shp[nl] = hpreg[p];
    }
    __syncthreads();
    // score conv (reads LDS hp; same serial order as r8's score_pool)
    for (int i = t; i < NPG; i += 512) {
        int st = rowstart[nbase + i], cn = rowcnt[nbase + i];
        float di = dinv[nbase + i];
        float a = fmaf(shp[i], di * di, bp[0]);
        for (int j = 0; j < cn; ++j) {
            int2 pr = pairs[st + j];
            a = fmaf(__int_as_float(pr.y), shp[pr.x - nbase], a);
        }
        ssc[i] = a;
    }
    __syncthreads();
    // exact top-k rank: rank = #(s[j] > s[i]) + #(s[j]==s[i] && j<i)
    for (int i = t; i < NPG; i += 512) {
        float si = ssc[i];
        int rank = 0;
        for (int j = 0; j < NPG; ++j) {
            float sj = ssc[j];
            rank += (sj > si) || (sj == si && j < i);
        }
        rnk[i] = rank;
        if (!FINAL) nid[nbase + i] = (rank < K) ? (g * K + rank) : -1;
    }
    __syncthreads();
    // gated xn write (selected only) + readout partials
    float4 mx = make_float4(-3.402823466e38f, -3.402823466e38f, -3.402823466e38f, -3.402823466e38f);
    float4 sm = make_float4(0.f, 0.f, 0.f, 0.f);
#pragma unroll
    for (int p = 0; p < PASSES; ++p) {
        int nl = p * 32 + wv * 4 + sub;
        int r = rnk[nl];
        if (r < K) {
            float gt = tanhf(ssc[nl]);
            float4 v = acc[p];
            v.x *= gt; v.y *= gt; v.z *= gt; v.w *= gt;
            if (!FINAL) xn4[((size_t)g * K + r) * 16 + lane16] = v;
            mx.x = fmaxf(mx.x, v.x); mx.y = fmaxf(mx.y, v.y);
            mx.z = fmaxf(mx.z, v.z); mx.w = fmaxf(mx.w, v.w);
            sm.x += v.x; sm.y += v.y; sm.z += v.z; sm.w += v.w;
        }
    }
    int grp = t >> 4;                        // 0..31
    smx[grp * 16 + lane16] = mx;
    ssm[grp * 16 + lane16] = sm;
    __syncthreads();
    if (grp == 0) {
#pragma unroll
        for (int u = 1; u < 32; ++u) {
            float4 a = smx[u * 16 + lane16], b = ssm[u * 16 + lane16];
            mx.x = fmaxf(mx.x, a.x); mx.y = fmaxf(mx.y, a.y);
            mx.z = fmaxf(mx.z, a.z); mx.w = fmaxf(mx.w, a.w);
            sm.x += b.x; sm.y += b.y; sm.z += b.z; sm.w += b.w;
        }
        float invK = 1.f / K;
        int c = lane16 * 4;
        float mr[4] = {mx.x, mx.y, mx.z, mx.w};
        float ar[4] = {sm.x * invK, sm.y * invK, sm.z * invK, sm.w * invK};
#pragma unroll
        for (int u = 0; u < 4; ++u) {
            if (FINAL) {
                out[g * 128 + c + u]      = 0.5f * (x1r[g * 128 + c + u]      + mr[u]);
                out[g * 128 + 64 + c + u] = 0.5f * (x1r[g * 128 + 64 + c + u] + ar[u]);
            } else {
                xr[g * 128 + c + u]      = mr[u];
                xr[g * 128 + 64 + c + u] = ar[u];
            }
        }
    }
}

extern "C" void kernel_launch(void* const* d_in, const int* in_sizes, int n_in,
                              void* d_out, int out_size, void* d_ws, size_t ws_size,
                              hipStream_t stream) {
    const float* x    = (const float*)d_in[0];
    const float* eatt = (const float*)d_in[1];
    const float* W1   = (const float*)d_in[2];
    const float* b1   = (const float*)d_in[3];
    const float* Wp1  = (const float*)d_in[4];
    const float* bp1  = (const float*)d_in[5];
    const float* W2   = (const float*)d_in[6];
    const float* b2   = (const float*)d_in[7];
    const float* Wp2  = (const float*)d_in[8];
    const float* bp2  = (const float*)d_in[9];
    const int*   esrc = (const int*)d_in[10];
    const int*   edst = (const int*)d_in[11];
    float* out = (float*)d_out;

    float* ws = (float*)d_ws;
    size_t o = 0;
    float* A    = ws + o; o += (size_t)N0 * 64;   // hx1 -> hx2
    float* xn1  = ws + o; o += (size_t)N1_ * 64;
    int2*  prs  = (int2*)(ws + o); o += (size_t)NE * 2;  // (src,coef) per CSR slot
    int*   rst  = (int*)(ws + o); o += N0;
    int*   rcn  = (int*)(ws + o); o += N0;
    float* dinv = ws + o; o += N0;
    int*   nid  = (int*)(ws + o); o += N0;
    float* x1r  = ws + o; o += BG * 128;

    float* hx1 = A;
    float* hx2 = A;                        // hx1 dead after tail1

    // ---- stage 1 ----
    stage_head_kernel<NN, false><<<BG + 512, 512, 0, stream>>>(
        esrc, edst, eatt, nullptr, prs, rst, rcn, dinv,
        (const float4*)x, (const float4*)W1, (float4*)hx1, N0, 512);
    tail_kernel<NN, K1, false><<<BG, 512, 0, stream>>>(
        (const float4*)hx1, prs, rst, rcn, dinv, (const float4*)b1,
        (const float4*)Wp1, bp1, nid, (float4*)xn1, x1r, nullptr, nullptr);
    // ---- stage 2 ----
    stage_head_kernel<K1, true><<<BG + 256, 512, 0, stream>>>(
        esrc, edst, eatt, nid, prs, rst, rcn, dinv,
        (const float4*)xn1, (const float4*)W2, (float4*)hx2, N1_, 256);
    tail_kernel<K1, K2, true><<<BG, 512, 0, stream>>>(
        (const float4*)hx2, prs, rst, rcn, dinv, (const float4*)b2,
        (const float4*)Wp2, bp2, nullptr, nullptr, nullptr, x1r, out);
}

// Round 10
// 235.415 us; speedup vs baseline: 5.1252x; 1.0500x over previous
//
#include <hip/hip_runtime.h>
#include <math.h>

#define BG   256                   // graphs
#define NN   512                   // nodes per graph
#define EPG  (NN * 16)             // 8192 edges per graph
#define NE   (BG * EPG)            // 2097152 edges
#define N0   (BG * NN)             // 131072
#define K1   256
#define N1_  (BG * K1)             // 65536
#define K2   128
#define N2_  (BG * K2)             // 32768

__device__ __forceinline__ float4 f4fma(float s, float4 a, float4 c) {
    c.x = fmaf(s, a.x, c.x); c.y = fmaf(s, a.y, c.y);
    c.z = fmaf(s, a.z, c.z); c.w = fmaf(s, a.w, c.w);
    return c;
}

// ---- fused stage head (512 threads/block):
// blocks [0,BG): CSR build; blocks [BG,BG+mmb): 64x64 GEMM Y = X @ W.
// pairs.x now stores the LOCAL src index (0..NPG).
template <int NPG, bool REMAP>
__global__ __launch_bounds__(512)
void stage_head_kernel(const int* __restrict__ esrc, const int* __restrict__ edst,
                       const float* __restrict__ eatt, const int* __restrict__ nid,
                       int2* __restrict__ pairs, int* __restrict__ rowstart,
                       int* __restrict__ rowcnt, float* __restrict__ dinv,
                       const float4* __restrict__ X4, const float4* __restrict__ W4,
                       float4* __restrict__ Y4, int nrows, int mmb) {
    __shared__ __align__(16) char smem[52224];   // max(csr 41K, gemm 51K)
    if ((int)blockIdx.x < BG) {
        int2*  lpair = (int2*)smem;                      // [4096] staging, 32 KB
        int*   cnt   = (int*)(smem + 32768);             // [NPG]
        float* wsum  = (float*)(smem + 32768) + NPG;     // [NPG]
        int*   scn   = (int*)(smem + 32768) + 2 * NPG;   // [NPG]
        float* sdinv = (float*)(smem + 32768) + 3 * NPG; // [NPG]
        int*   wtot  = (int*)(smem + 32768) + 4 * NPG;   // [8]
        int g = blockIdx.x;
        int e0 = g * EPG, nbase = g * NPG;
        for (int ii = threadIdx.x; ii < NPG; ii += 512) { cnt[ii] = 0; wsum[ii] = 0.f; }
        __syncthreads();
        const int4*   edst4 = (const int4*)(edst + e0);
        const int4*   esrc4 = (const int4*)(esrc + e0);
        const float4* eatt4 = (const float4*)(eatt + e0);
        int ed[16]; int es[16]; float ea[16];
#pragma unroll
        for (int c = 0; c < 4; ++c) {            // single global read pass
            int ch = threadIdx.x + c * 512;
            int4   dd = edst4[ch];
            int4   ss = esrc4[ch];
            float4 ww = eatt4[ch];
            ed[c * 4 + 0] = dd.x; ed[c * 4 + 1] = dd.y; ed[c * 4 + 2] = dd.z; ed[c * 4 + 3] = dd.w;
            es[c * 4 + 0] = ss.x; es[c * 4 + 1] = ss.y; es[c * 4 + 2] = ss.z; es[c * 4 + 3] = ss.w;
            ea[c * 4 + 0] = ww.x; ea[c * 4 + 1] = ww.y; ea[c * 4 + 2] = ww.z; ea[c * 4 + 3] = ww.w;
        }
        if (REMAP) {
#pragma unroll
            for (int j = 0; j < 16; ++j) { ed[j] = nid[ed[j]]; es[j] = nid[es[j]]; }
        }
#pragma unroll
        for (int j = 0; j < 16; ++j) {
            bool valid = !REMAP || (ed[j] >= 0 && es[j] >= 0);
            if (valid) {
                int dl = ed[j] - nbase;
                atomicAdd(&cnt[dl], 1);
                atomicAdd(&wsum[dl], ea[j]);
            }
        }
        __syncthreads();
        // wave-shuffle scan of cnt[0..NPG)
        int i = threadIdx.x;
        int lane = i & 63, wvid = i >> 6;
        int xval = (i < NPG) ? cnt[i] : 0;
        int xs = xval;
#pragma unroll
        for (int off = 1; off < 64; off <<= 1) {
            int v = __shfl_up(xs, off, 64);
            if (lane >= off) xs += v;
        }
        if (lane == 63) wtot[wvid] = xs;
        __syncthreads();
        int woff = 0, total = 0;
#pragma unroll
        for (int t = 0; t < 8; ++t) {
            int wt = wtot[t];
            if (t < wvid) woff += wt;
            total += wt;
        }
        xs += woff;                              // inclusive scan
        if (i < NPG) {
            int st = xs - xval;                  // exclusive
            rowstart[nbase + i] = e0 + st;
            rowcnt[nbase + i]   = xval;
            float di = rsqrtf(wsum[i] + 1.0f);
            dinv[nbase + i] = di;
            sdinv[i] = di;
            scn[i] = st;                          // running slot offset
        }
        __syncthreads();
        int slots[16]; float cf[16];
#pragma unroll
        for (int j = 0; j < 16; ++j) {
            bool valid = !REMAP || (ed[j] >= 0 && es[j] >= 0);
            slots[j] = -1;
            if (valid) {
                int dl = ed[j] - nbase, sl = es[j] - nbase;
                cf[j] = sdinv[dl] * ea[j] * sdinv[sl];
                slots[j] = atomicAdd(&scn[dl], 1);
            }
        }
#pragma unroll
        for (int j = 0; j < 16; ++j)
            if (slots[j] >= 0 && slots[j] < 4096)
                lpair[slots[j]] = make_int2(es[j] - nbase, __float_as_int(cf[j]));
        __syncthreads();
        int n0 = total < 4096 ? total : 4096;
        for (int k = threadIdx.x; k < n0; k += 512) pairs[e0 + k] = lpair[k];
        __syncthreads();
        if (total > 4096) {
#pragma unroll
            for (int j = 0; j < 16; ++j)
                if (slots[j] >= 4096)
                    lpair[slots[j] - 4096] = make_int2(es[j] - nbase, __float_as_int(cf[j]));
            __syncthreads();
            int n1 = total - 4096;
            for (int k = threadIdx.x; k < n1; k += 512) pairs[e0 + 4096 + k] = lpair[k];
        }
    } else {
        // ---------------- GEMM: Y[nrows,64] = X @ W ----------------
        float (*sW)[68] = (float (*)[68])smem;                       // 17408 B
        int p = threadIdx.x >> 8;                                    // pipeline 0/1
        int t = threadIdx.x & 255;
        float (*sX)[68] = (float (*)[68])(smem + 17408 + p * 17408);
#pragma unroll
        for (int u = 0; u < 2; ++u) {            // stage W once (all 512 threads)
            int idx = threadIdx.x + u * 512;
            int r = idx >> 4, c4 = idx & 15;
            *(float4*)&sW[r][c4 * 4] = W4[idx];
        }
        int mb = blockIdx.x - BG;
        int ntiles = nrows >> 6;
        int rg = t >> 4, cg = t & 15;
        for (int tile = mb * 2 + p; tile < ntiles; tile += mmb * 2) {
            __syncthreads();                     // protect sX reuse; covers sW stage
            int row0 = tile << 6;
#pragma unroll
            for (int u = 0; u < 4; ++u) {        // stage 64 rows of X
                int idx = t + u * 256;
                int r = idx >> 4, c4 = idx & 15;
                *(float4*)&sX[r][c4 * 4] = X4[(size_t)(row0 + r) * 16 + c4];
            }
            __syncthreads();
            float4 acc0 = make_float4(0.f, 0.f, 0.f, 0.f);
            float4 acc1 = acc0, acc2 = acc0, acc3 = acc0;
#pragma unroll
            for (int k4 = 0; k4 < 16; ++k4) {
                float4 xv0 = *(const float4*)&sX[rg * 4 + 0][k4 * 4];
                float4 xv1 = *(const float4*)&sX[rg * 4 + 1][k4 * 4];
                float4 xv2 = *(const float4*)&sX[rg * 4 + 2][k4 * 4];
                float4 xv3 = *(const float4*)&sX[rg * 4 + 3][k4 * 4];
                float4 wv0 = *(const float4*)&sW[k4 * 4 + 0][cg * 4];
                float4 wv1 = *(const float4*)&sW[k4 * 4 + 1][cg * 4];
                float4 wv2 = *(const float4*)&sW[k4 * 4 + 2][cg * 4];
                float4 wv3 = *(const float4*)&sW[k4 * 4 + 3][cg * 4];
                acc0 = f4fma(xv0.x, wv0, acc0); acc0 = f4fma(xv0.y, wv1, acc0);
                acc0 = f4fma(xv0.z, wv2, acc0); acc0 = f4fma(xv0.w, wv3, acc0);
                acc1 = f4fma(xv1.x, wv0, acc1); acc1 = f4fma(xv1.y, wv1, acc1);
                acc1 = f4fma(xv1.z, wv2, acc1); acc1 = f4fma(xv1.w, wv3, acc1);
                acc2 = f4fma(xv2.x, wv0, acc2); acc2 = f4fma(xv2.y, wv1, acc2);
                acc2 = f4fma(xv2.z, wv2, acc2); acc2 = f4fma(xv2.w, wv3, acc2);
                acc3 = f4fma(xv3.x, wv0, acc3); acc3 = f4fma(xv3.y, wv1, acc3);
                acc3 = f4fma(xv3.z, wv2, acc3); acc3 = f4fma(xv3.w, wv3, acc3);
            }
            size_t ob = (size_t)(row0 + rg * 4) * 16 + cg;
            Y4[ob]      = acc0;
            Y4[ob + 16] = acc1;
            Y4[ob + 32] = acc2;
            Y4[ob + 48] = acc3;
        }
    }
}

// ---- per-graph megafused tail (r9 structure + r10 conv fix):
// conv phase now batch-loads 16 pairs per node with ONE coalesced 16-lane load
// (+ rolling cross-pass prefetch) and broadcasts via shfl — removes the serial
// per-edge dependent 8B load chain that made r9's tail 70 us. ----
template <int NPG, int K, bool FINAL>
__global__ __launch_bounds__(512)
void tail_kernel(const float4* __restrict__ hx4, const int2* __restrict__ pairs,
                 const int* __restrict__ rowstart, const int* __restrict__ rowcnt,
                 const float* __restrict__ dinv, const float4* __restrict__ b4,
                 const float4* __restrict__ wp4, const float* __restrict__ bp,
                 int* __restrict__ nid, float4* __restrict__ xn4,
                 float* __restrict__ xr, const float* __restrict__ x1r,
                 float* __restrict__ out) {
    constexpr int PASSES = NPG / 32;         // 8 waves x 4 nodes per pass
    __shared__ __align__(16) char smem[NPG * 68 * 4];
    float* shx = (float*)smem;               // [NPG][68] (conv phase)
    float* shp = (float*)smem;               // overlay (post-conv): [NPG]
    float* ssc = (float*)smem + NPG;         // [NPG]
    int*   rnk = (int*)smem + 2 * NPG;       // [NPG]
    float4* smx = (float4*)(smem + 3 * NPG * 4);        // [32][16]
    float4* ssm = smx + 32 * 16;                        // [32][16]

    int g = blockIdx.x, nbase = g * NPG;
    int t = threadIdx.x;
    int lane16 = t & 15, sub = (t >> 4) & 3, wv = t >> 6;
    int lanebase = (t & 63) & 48;            // sub*16
    // phase 1: stage hx
    for (int i = t; i < NPG * 16; i += 512) {
        int r = i >> 4, c4 = i & 15;
        *(float4*)&shx[r * 68 + c4 * 4] = hx4[(size_t)nbase * 16 + i];
    }
    // per-pass row metadata (independent loads, issued together)
    int stA[PASSES], cnA[PASSES]; float diA[PASSES];
#pragma unroll
    for (int p = 0; p < PASSES; ++p) {
        int node = nbase + p * 32 + wv * 4 + sub;
        stA[p] = rowstart[node];
        cnA[p] = rowcnt[node];
        diA[p] = dinv[node];
    }
    __syncthreads();
    // phase 2: conv (h in registers) + hp; batched pairs + rolling prefetch
    float4 acc[PASSES];
    float  hpreg[PASSES];
    float4 bb = b4[lane16];
    float4 w4 = wp4[lane16];
    int2 cur = pairs[stA[0] + lane16];       // pass-0 batch-0 prefetch
#pragma unroll
    for (int p = 0; p < PASSES; ++p) {
        int2 nxt = make_int2(0, 0);
        if (p + 1 < PASSES) nxt = pairs[stA[p + 1] + lane16];   // next pass prefetch
        int st = stA[p], cn = cnA[p];
        float di = diA[p], dii = di * di;
        int nl = p * 32 + wv * 4 + sub;
        float4 a = *(const float4*)&shx[nl * 68 + lane16 * 4];
        a.x = fmaf(a.x, dii, bb.x);
        a.y = fmaf(a.y, dii, bb.y);
        a.z = fmaf(a.z, dii, bb.z);
        a.w = fmaf(a.w, dii, bb.w);
        int2 bpr = cur;
        for (int eb = 0; eb < cn; eb += 16) {
            int m = cn - eb; if (m > 16) m = 16;
            int2 bnext = make_int2(0, 0);
            if (eb + 16 < cn) bnext = pairs[st + eb + 16 + lane16];  // rare 2nd batch
            for (int j = 0; j < m; ++j) {
                int   s = __shfl(bpr.x, lanebase + j, 64);
                float c = __int_as_float(__shfl(bpr.y, lanebase + j, 64));
                const float4 v = *(const float4*)&shx[s * 68 + lane16 * 4];
                a = f4fma(c, v, a);
            }
            bpr = bnext;
        }
        a.x = fmaxf(a.x, 0.f); a.y = fmaxf(a.y, 0.f);
        a.z = fmaxf(a.z, 0.f); a.w = fmaxf(a.w, 0.f);
        acc[p] = a;
        float tt = a.x * w4.x + a.y * w4.y + a.z * w4.z + a.w * w4.w;
        tt += __shfl_xor(tt, 1, 64); tt += __shfl_xor(tt, 2, 64);
        tt += __shfl_xor(tt, 4, 64); tt += __shfl_xor(tt, 8, 64);
        hpreg[p] = tt;
        cur = nxt;
    }
    __syncthreads();                         // conv done, shx dead
#pragma unroll
    for (int p = 0; p < PASSES; ++p) {
        int nl = p * 32 + wv * 4 + sub;
        if (lane16 == 0) shp[nl] = hpreg[p];
    }
    __syncthreads();
    // score conv (reads LDS hp; per-lane independent chains)
    for (int i = t; i < NPG; i += 512) {
        int st = rowstart[nbase + i], cn = rowcnt[nbase + i];
        float di = dinv[nbase + i];
        float a = fmaf(shp[i], di * di, bp[0]);
        for (int j = 0; j < cn; ++j) {
            int2 pr = pairs[st + j];
            a = fmaf(__int_as_float(pr.y), shp[pr.x], a);
        }
        ssc[i] = a;
    }
    __syncthreads();
    // exact top-k rank: rank = #(s[j] > s[i]) + #(s[j]==s[i] && j<i)
    for (int i = t; i < NPG; i += 512) {
        float si = ssc[i];
        int rank = 0;
        for (int j = 0; j < NPG; ++j) {
            float sj = ssc[j];
            rank += (sj > si) || (sj == si && j < i);
        }
        rnk[i] = rank;
        if (!FINAL) nid[nbase + i] = (rank < K) ? (g * K + rank) : -1;
    }
    __syncthreads();
    // gated xn write (selected only) + readout partials
    float4 mx = make_float4(-3.402823466e38f, -3.402823466e38f, -3.402823466e38f, -3.402823466e38f);
    float4 sm = make_float4(0.f, 0.f, 0.f, 0.f);
#pragma unroll
    for (int p = 0; p < PASSES; ++p) {
        int nl = p * 32 + wv * 4 + sub;
        int r = rnk[nl];
        if (r < K) {
            float gt = tanhf(ssc[nl]);
            float4 v = acc[p];
            v.x *= gt; v.y *= gt; v.z *= gt; v.w *= gt;
            if (!FINAL) xn4[((size_t)g * K + r) * 16 + lane16] = v;
            mx.x = fmaxf(mx.x, v.x); mx.y = fmaxf(mx.y, v.y);
            mx.z = fmaxf(mx.z, v.z); mx.w = fmaxf(mx.w, v.w);
            sm.x += v.x; sm.y += v.y; sm.z += v.z; sm.w += v.w;
        }
    }
    int grp = t >> 4;                        // 0..31
    smx[grp * 16 + lane16] = mx;
    ssm[grp * 16 + lane16] = sm;
    __syncthreads();
    if (grp == 0) {
#pragma unroll
        for (int u = 1; u < 32; ++u) {
            float4 a = smx[u * 16 + lane16], b = ssm[u * 16 + lane16];
            mx.x = fmaxf(mx.x, a.x); mx.y = fmaxf(mx.y, a.y);
            mx.z = fmaxf(mx.z, a.z); mx.w = fmaxf(mx.w, a.w);
            sm.x += b.x; sm.y += b.y; sm.z += b.z; sm.w += b.w;
        }
        float invK = 1.f / K;
        int c = lane16 * 4;
        float mr[4] = {mx.x, mx.y, mx.z, mx.w};
        float ar[4] = {sm.x * invK, sm.y * invK, sm.z * invK, sm.w * invK};
#pragma unroll
        for (int u = 0; u < 4; ++u) {
            if (FINAL) {
                out[g * 128 + c + u]      = 0.5f * (x1r[g * 128 + c + u]      + mr[u]);
                out[g * 128 + 64 + c + u] = 0.5f * (x1r[g * 128 + 64 + c + u] + ar[u]);
            } else {
                xr[g * 128 + c + u]      = mr[u];
                xr[g * 128 + 64 + c + u] = ar[u];
            }
        }
    }
}

extern "C" void kernel_launch(void* const* d_in, const int* in_sizes, int n_in,
                              void* d_out, int out_size, void* d_ws, size_t ws_size,
                              hipStream_t stream) {
    const float* x    = (const float*)d_in[0];
    const float* eatt = (const float*)d_in[1];
    const float* W1   = (const float*)d_in[2];
    const float* b1   = (const float*)d_in[3];
    const float* Wp1  = (const float*)d_in[4];
    const float* bp1  = (const float*)d_in[5];
    const float* W2   = (const float*)d_in[6];
    const float* b2   = (const float*)d_in[7];
    const float* Wp2  = (const float*)d_in[8];
    const float* bp2  = (const float*)d_in[9];
    const int*   esrc = (const int*)d_in[10];
    const int*   edst = (const int*)d_in[11];
    float* out = (float*)d_out;

    float* ws = (float*)d_ws;
    size_t o = 0;
    float* A    = ws + o; o += (size_t)N0 * 64;   // hx1 -> hx2
    float* xn1  = ws + o; o += (size_t)N1_ * 64;
    int2*  prs  = (int2*)(ws + o); o += (size_t)NE * 2;  // (local src,coef) per slot
    int*   rst  = (int*)(ws + o); o += N0;
    int*   rcn  = (int*)(ws + o); o += N0;
    float* dinv = ws + o; o += N0;
    int*   nid  = (int*)(ws + o); o += N0;
    float* x1r  = ws + o; o += BG * 128;

    float* hx1 = A;
    float* hx2 = A;                        // hx1 dead after tail1

    // ---- stage 1 ----
    stage_head_kernel<NN, false><<<BG + 512, 512, 0, stream>>>(
        esrc, edst, eatt, nullptr, prs, rst, rcn, dinv,
        (const float4*)x, (const float4*)W1, (float4*)hx1, N0, 512);
    tail_kernel<NN, K1, false><<<BG, 512, 0, stream>>>(
        (const float4*)hx1, prs, rst, rcn, dinv, (const float4*)b1,
        (const float4*)Wp1, bp1, nid, (float4*)xn1, x1r, nullptr, nullptr);
    // ---- stage 2 ----
    stage_head_kernel<K1, true><<<BG + 256, 512, 0, stream>>>(
        esrc, edst, eatt, nid, prs, rst, rcn, dinv,
        (const float4*)xn1, (const float4*)W2, (float4*)hx2, N1_, 256);
    tail_kernel<K1, K2, true><<<BG, 512, 0, stream>>>(
        (const float4*)hx2, prs, rst, rcn, dinv, (const float4*)b2,
        (const float4*)Wp2, bp2, nullptr, nullptr, nullptr, x1r, out);
}

// Round 11
// 226.196 us; speedup vs baseline: 5.3341x; 1.0408x over previous
//
#include <hip/hip_runtime.h>
#include <math.h>

#define BG   256                   // graphs
#define NN   512                   // nodes per graph
#define EPG  (NN * 16)             // 8192 edges per graph
#define NE   (BG * EPG)            // 2097152 edges
#define N0   (BG * NN)             // 131072
#define K1   256
#define N1_  (BG * K1)             // 65536
#define K2   128
#define N2_  (BG * K2)             // 32768

__device__ __forceinline__ float4 f4fma(float s, float4 a, float4 c) {
    c.x = fmaf(s, a.x, c.x); c.y = fmaf(s, a.y, c.y);
    c.z = fmaf(s, a.z, c.z); c.w = fmaf(s, a.w, c.w);
    return c;
}

// ---- fused stage head (512 threads/block): unchanged from r10 ----
// blocks [0,BG): CSR build (pairs.x = LOCAL src); blocks [BG,..): 64x64 GEMM.
template <int NPG, bool REMAP>
__global__ __launch_bounds__(512)
void stage_head_kernel(const int* __restrict__ esrc, const int* __restrict__ edst,
                       const float* __restrict__ eatt, const int* __restrict__ nid,
                       int2* __restrict__ pairs, int* __restrict__ rowstart,
                       int* __restrict__ rowcnt, float* __restrict__ dinv,
                       const float4* __restrict__ X4, const float4* __restrict__ W4,
                       float4* __restrict__ Y4, int nrows, int mmb) {
    __shared__ __align__(16) char smem[52224];   // max(csr 41K, gemm 51K)
    if ((int)blockIdx.x < BG) {
        int2*  lpair = (int2*)smem;                      // [4096] staging, 32 KB
        int*   cnt   = (int*)(smem + 32768);             // [NPG]
        float* wsum  = (float*)(smem + 32768) + NPG;     // [NPG]
        int*   scn   = (int*)(smem + 32768) + 2 * NPG;   // [NPG]
        float* sdinv = (float*)(smem + 32768) + 3 * NPG; // [NPG]
        int*   wtot  = (int*)(smem + 32768) + 4 * NPG;   // [8]
        int g = blockIdx.x;
        int e0 = g * EPG, nbase = g * NPG;
        for (int ii = threadIdx.x; ii < NPG; ii += 512) { cnt[ii] = 0; wsum[ii] = 0.f; }
        __syncthreads();
        const int4*   edst4 = (const int4*)(edst + e0);
        const int4*   esrc4 = (const int4*)(esrc + e0);
        const float4* eatt4 = (const float4*)(eatt + e0);
        int ed[16]; int es[16]; float ea[16];
#pragma unroll
        for (int c = 0; c < 4; ++c) {            // single global read pass
            int ch = threadIdx.x + c * 512;
            int4   dd = edst4[ch];
            int4   ss = esrc4[ch];
            float4 ww = eatt4[ch];
            ed[c * 4 + 0] = dd.x; ed[c * 4 + 1] = dd.y; ed[c * 4 + 2] = dd.z; ed[c * 4 + 3] = dd.w;
            es[c * 4 + 0] = ss.x; es[c * 4 + 1] = ss.y; es[c * 4 + 2] = ss.z; es[c * 4 + 3] = ss.w;
            ea[c * 4 + 0] = ww.x; ea[c * 4 + 1] = ww.y; ea[c * 4 + 2] = ww.z; ea[c * 4 + 3] = ww.w;
        }
        if (REMAP) {
#pragma unroll
            for (int j = 0; j < 16; ++j) { ed[j] = nid[ed[j]]; es[j] = nid[es[j]]; }
        }
#pragma unroll
        for (int j = 0; j < 16; ++j) {
            bool valid = !REMAP || (ed[j] >= 0 && es[j] >= 0);
            if (valid) {
                int dl = ed[j] - nbase;
                atomicAdd(&cnt[dl], 1);
                atomicAdd(&wsum[dl], ea[j]);
            }
        }
        __syncthreads();
        int i = threadIdx.x;
        int lane = i & 63, wvid = i >> 6;
        int xval = (i < NPG) ? cnt[i] : 0;
        int xs = xval;
#pragma unroll
        for (int off = 1; off < 64; off <<= 1) {
            int v = __shfl_up(xs, off, 64);
            if (lane >= off) xs += v;
        }
        if (lane == 63) wtot[wvid] = xs;
        __syncthreads();
        int woff = 0, total = 0;
#pragma unroll
        for (int t = 0; t < 8; ++t) {
            int wt = wtot[t];
            if (t < wvid) woff += wt;
            total += wt;
        }
        xs += woff;                              // inclusive scan
        if (i < NPG) {
            int st = xs - xval;                  // exclusive
            rowstart[nbase + i] = e0 + st;
            rowcnt[nbase + i]   = xval;
            float di = rsqrtf(wsum[i] + 1.0f);
            dinv[nbase + i] = di;
            sdinv[i] = di;
            scn[i] = st;                          // running slot offset
        }
        __syncthreads();
        int slots[16]; float cf[16];
#pragma unroll
        for (int j = 0; j < 16; ++j) {
            bool valid = !REMAP || (ed[j] >= 0 && es[j] >= 0);
            slots[j] = -1;
            if (valid) {
                int dl = ed[j] - nbase, sl = es[j] - nbase;
                cf[j] = sdinv[dl] * ea[j] * sdinv[sl];
                slots[j] = atomicAdd(&scn[dl], 1);
            }
        }
#pragma unroll
        for (int j = 0; j < 16; ++j)
            if (slots[j] >= 0 && slots[j] < 4096)
                lpair[slots[j]] = make_int2(es[j] - nbase, __float_as_int(cf[j]));
        __syncthreads();
        int n0 = total < 4096 ? total : 4096;
        for (int k = threadIdx.x; k < n0; k += 512) pairs[e0 + k] = lpair[k];
        __syncthreads();
        if (total > 4096) {
#pragma unroll
            for (int j = 0; j < 16; ++j)
                if (slots[j] >= 4096)
                    lpair[slots[j] - 4096] = make_int2(es[j] - nbase, __float_as_int(cf[j]));
            __syncthreads();
            int n1 = total - 4096;
            for (int k = threadIdx.x; k < n1; k += 512) pairs[e0 + 4096 + k] = lpair[k];
        }
    } else {
        // ---------------- GEMM: Y[nrows,64] = X @ W ----------------
        float (*sW)[68] = (float (*)[68])smem;                       // 17408 B
        int p = threadIdx.x >> 8;                                    // pipeline 0/1
        int t = threadIdx.x & 255;
        float (*sX)[68] = (float (*)[68])(smem + 17408 + p * 17408);
#pragma unroll
        for (int u = 0; u < 2; ++u) {            // stage W once (all 512 threads)
            int idx = threadIdx.x + u * 512;
            int r = idx >> 4, c4 = idx & 15;
            *(float4*)&sW[r][c4 * 4] = W4[idx];
        }
        int mb = blockIdx.x - BG;
        int ntiles = nrows >> 6;
        int rg = t >> 4, cg = t & 15;
        for (int tile = mb * 2 + p; tile < ntiles; tile += mmb * 2) {
            __syncthreads();                     // protect sX reuse; covers sW stage
            int row0 = tile << 6;
#pragma unroll
            for (int u = 0; u < 4; ++u) {        // stage 64 rows of X
                int idx = t + u * 256;
                int r = idx >> 4, c4 = idx & 15;
                *(float4*)&sX[r][c4 * 4] = X4[(size_t)(row0 + r) * 16 + c4];
            }
            __syncthreads();
            float4 acc0 = make_float4(0.f, 0.f, 0.f, 0.f);
            float4 acc1 = acc0, acc2 = acc0, acc3 = acc0;
#pragma unroll
            for (int k4 = 0; k4 < 16; ++k4) {
                float4 xv0 = *(const float4*)&sX[rg * 4 + 0][k4 * 4];
                float4 xv1 = *(const float4*)&sX[rg * 4 + 1][k4 * 4];
                float4 xv2 = *(const float4*)&sX[rg * 4 + 2][k4 * 4];
                float4 xv3 = *(const float4*)&sX[rg * 4 + 3][k4 * 4];
                float4 wv0 = *(const float4*)&sW[k4 * 4 + 0][cg * 4];
                float4 wv1 = *(const float4*)&sW[k4 * 4 + 1][cg * 4];
                float4 wv2 = *(const float4*)&sW[k4 * 4 + 2][cg * 4];
                float4 wv3 = *(const float4*)&sW[k4 * 4 + 3][cg * 4];
                acc0 = f4fma(xv0.x, wv0, acc0); acc0 = f4fma(xv0.y, wv1, acc0);
                acc0 = f4fma(xv0.z, wv2, acc0); acc0 = f4fma(xv0.w, wv3, acc0);
                acc1 = f4fma(xv1.x, wv0, acc1); acc1 = f4fma(xv1.y, wv1, acc1);
                acc1 = f4fma(xv1.z, wv2, acc1); acc1 = f4fma(xv1.w, wv3, acc1);
                acc2 = f4fma(xv2.x, wv0, acc2); acc2 = f4fma(xv2.y, wv1, acc2);
                acc2 = f4fma(xv2.z, wv2, acc2); acc2 = f4fma(xv2.w, wv3, acc2);
                acc3 = f4fma(xv3.x, wv0, acc3); acc3 = f4fma(xv3.y, wv1, acc3);
                acc3 = f4fma(xv3.z, wv2, acc3); acc3 = f4fma(xv3.w, wv3, acc3);
            }
            size_t ob = (size_t)(row0 + rg * 4) * 16 + cg;
            Y4[ob]      = acc0;
            Y4[ob + 16] = acc1;
            Y4[ob + 32] = acc2;
            Y4[ob + 48] = acc3;
        }
    }
}

// ---- per-graph megafused tail, r11: node-per-LANE conv.
// Conv: lane owns a whole node row; (src,coef) is a per-lane register (no
// shfl broadcasts); neighbor row = 16 ds_read_b128, each carrying 1 KB/wave.
// Counting-sort node->lane assignment by degree kills j-loop divergence
// (pure permutation — per-node fp order unchanged). After conv, h overwrites
// shx in LDS; hp/score/rank/readout phases are r10-verbatim (bitwise equal).
template <int NPG, int K, bool FINAL>
__global__ __launch_bounds__(512)
void tail_kernel(const float4* __restrict__ hx4, const int2* __restrict__ pairs,
                 const int* __restrict__ rowstart, const int* __restrict__ rowcnt,
                 const float* __restrict__ dinv, const float4* __restrict__ b4,
                 const float4* __restrict__ wp4, const float* __restrict__ bp,
                 int* __restrict__ nid, float4* __restrict__ xn4,
                 float* __restrict__ xr, const float* __restrict__ x1r,
                 float* __restrict__ out) {
    constexpr int PASSES = NPG / 32;
    constexpr int SH_A  = NPG * 68;          // shx: hx -> h
    constexpr int SH_UN = 4096;              // union: {perm,shp} then {smx,ssm}
    __shared__ __align__(16) float smem[SH_A + SH_UN + 2 * NPG + 64 + 64];
    float*  shx  = smem;
    int*    perm = (int*)(smem + SH_A);                  // [NPG]   (conv/score)
    float*  shp  = smem + SH_A + NPG;                    // [NPG]   (score)
    float4* smx  = (float4*)(smem + SH_A);               // [32*16] (final, overlays)
    float4* ssm  = (float4*)(smem + SH_A + 2048);        // [32*16]
    float*  ssc  = smem + SH_A + SH_UN;                  // [NPG]
    int*    rnk  = (int*)(smem + SH_A + SH_UN + NPG);    // [NPG]
    float*  sbw  = smem + SH_A + SH_UN + 2 * NPG;        // [64] bias
    int*    hist = (int*)(smem + SH_A + SH_UN + 2 * NPG + 64); // [64]

    int g = blockIdx.x, nbase = g * NPG;
    int t = threadIdx.x;
    int lane16 = t & 15, sub = (t >> 4) & 3, wv = t >> 6, lane = t & 63;

    // phase 1: stage hx; bias; degree histogram
    for (int i = t; i < NPG * 16; i += 512) {
        int r = i >> 4, c4 = i & 15;
        *(float4*)&shx[r * 68 + c4 * 4] = hx4[(size_t)nbase * 16 + i];
    }
    if (t < 64) { sbw[t] = ((const float*)b4)[t]; hist[t] = 0; }
    __syncthreads();
    for (int i = t; i < NPG; i += 512) {
        int c = min(rowcnt[nbase + i], 63);
        atomicAdd(&hist[c], 1);
    }
    __syncthreads();
    if (t < 64) {                             // exclusive scan of 64 bins (1 wave)
        int v = hist[t], s = v;
#pragma unroll
        for (int off = 1; off < 64; off <<= 1) {
            int u = __shfl_up(s, off, 64);
            if (lane >= off) s += u;
        }
        hist[t] = s - v;
    }
    __syncthreads();
    for (int i = t; i < NPG; i += 512) {
        int c = min(rowcnt[nbase + i], 63);
        int pos = atomicAdd(&hist[c], 1);
        perm[pos] = i;                        // sorted by degree -> lanes
    }
    __syncthreads();
    // phase 2: conv, one node per lane
    int idx = wv * 64 + lane;
    float4 acc[16];
    int nl = 0;
    if (idx < NPG) {
        nl = perm[idx];
        int st = rowstart[nbase + nl], cn = rowcnt[nbase + nl];
        float di = dinv[nbase + nl], dii = di * di;
#pragma unroll
        for (int c = 0; c < 16; ++c) {
            float4 xv = *(const float4*)&shx[nl * 68 + c * 4];
            acc[c].x = fmaf(xv.x, dii, sbw[c * 4 + 0]);
            acc[c].y = fmaf(xv.y, dii, sbw[c * 4 + 1]);
            acc[c].z = fmaf(xv.z, dii, sbw[c * 4 + 2]);
            acc[c].w = fmaf(xv.w, dii, sbw[c * 4 + 3]);
        }
        int2 pc = (cn > 0) ? pairs[st] : make_int2(0, 0);
        for (int j = 0; j < cn; ++j) {
            int2 pn = (j + 1 < cn) ? pairs[st + j + 1] : make_int2(0, 0);
            float cf = __int_as_float(pc.y);
            int   s  = pc.x;
#pragma unroll
            for (int c = 0; c < 16; ++c)
                acc[c] = f4fma(cf, *(const float4*)&shx[s * 68 + c * 4], acc[c]);
            pc = pn;
        }
#pragma unroll
        for (int c = 0; c < 16; ++c) {
            acc[c].x = fmaxf(acc[c].x, 0.f); acc[c].y = fmaxf(acc[c].y, 0.f);
            acc[c].z = fmaxf(acc[c].z, 0.f); acc[c].w = fmaxf(acc[c].w, 0.f);
        }
    }
    __syncthreads();                          // all conv reads of hx complete
    if (idx < NPG) {
#pragma unroll
        for (int c = 0; c < 16; ++c)
            *(float4*)&shx[nl * 68 + c * 4] = acc[c];   // h overwrites hx
    }
    __syncthreads();
    // hp = h . Wp  (r10-verbatim group layout -> bitwise identical)
    float4 w4 = wp4[lane16];
#pragma unroll
    for (int p = 0; p < PASSES; ++p) {
        int n2 = p * 32 + wv * 4 + sub;
        float4 a = *(const float4*)&shx[n2 * 68 + lane16 * 4];
        float tt = a.x * w4.x + a.y * w4.y + a.z * w4.z + a.w * w4.w;
        tt += __shfl_xor(tt, 1, 64); tt += __shfl_xor(tt, 2, 64);
        tt += __shfl_xor(tt, 4, 64); tt += __shfl_xor(tt, 8, 64);
        if (lane16 == 0) shp[n2] = tt;
    }
    __syncthreads();
    // score conv (r10-verbatim body; thread->node via perm for low divergence)
    if (t < NPG) {
        int i = perm[t];
        int st = rowstart[nbase + i], cn = rowcnt[nbase + i];
        float di = dinv[nbase + i];
        float a = fmaf(shp[i], di * di, bp[0]);
        for (int j = 0; j < cn; ++j) {
            int2 pr = pairs[st + j];
            a = fmaf(__int_as_float(pr.y), shp[pr.x], a);
        }
        ssc[i] = a;
    }
    __syncthreads();
    // exact top-k rank: rank = #(s[j] > s[i]) + #(s[j]==s[i] && j<i)
    for (int i = t; i < NPG; i += 512) {
        float si = ssc[i];
        int rank = 0;
        for (int j = 0; j < NPG; ++j) {
            float sj = ssc[j];
            rank += (sj > si) || (sj == si && j < i);
        }
        rnk[i] = rank;
        if (!FINAL) nid[nbase + i] = (rank < K) ? (g * K + rank) : -1;
    }
    __syncthreads();
    // gated xn write + readout partials (r10-verbatim; v from LDS h)
    float4 mx = make_float4(-3.402823466e38f, -3.402823466e38f, -3.402823466e38f, -3.402823466e38f);
    float4 sm = make_float4(0.f, 0.f, 0.f, 0.f);
#pragma unroll
    for (int p = 0; p < PASSES; ++p) {
        int n2 = p * 32 + wv * 4 + sub;
        int r = rnk[n2];
        if (r < K) {
            float gt = tanhf(ssc[n2]);
            float4 v = *(const float4*)&shx[n2 * 68 + lane16 * 4];
            v.x *= gt; v.y *= gt; v.z *= gt; v.w *= gt;
            if (!FINAL) xn4[((size_t)g * K + r) * 16 + lane16] = v;
            mx.x = fmaxf(mx.x, v.x); mx.y = fmaxf(mx.y, v.y);
            mx.z = fmaxf(mx.z, v.z); mx.w = fmaxf(mx.w, v.w);
            sm.x += v.x; sm.y += v.y; sm.z += v.z; sm.w += v.w;
        }
    }
    int grp = t >> 4;                        // 0..31
    __syncthreads();                         // perm/shp dead; smx/ssm overlay safe
    smx[grp * 16 + lane16] = mx;
    ssm[grp * 16 + lane16] = sm;
    __syncthreads();
    if (grp == 0) {
#pragma unroll
        for (int u = 1; u < 32; ++u) {
            float4 a = smx[u * 16 + lane16], b = ssm[u * 16 + lane16];
            mx.x = fmaxf(mx.x, a.x); mx.y = fmaxf(mx.y, a.y);
            mx.z = fmaxf(mx.z, a.z); mx.w = fmaxf(mx.w, a.w);
            sm.x += b.x; sm.y += b.y; sm.z += b.z; sm.w += b.w;
        }
        float invK = 1.f / K;
        int c = lane16 * 4;
        float mr[4] = {mx.x, mx.y, mx.z, mx.w};
        float ar[4] = {sm.x * invK, sm.y * invK, sm.z * invK, sm.w * invK};
#pragma unroll
        for (int u = 0; u < 4; ++u) {
            if (FINAL) {
                out[g * 128 + c + u]      = 0.5f * (x1r[g * 128 + c + u]      + mr[u]);
                out[g * 128 + 64 + c + u] = 0.5f * (x1r[g * 128 + 64 + c + u] + ar[u]);
            } else {
                xr[g * 128 + c + u]      = mr[u];
                xr[g * 128 + 64 + c + u] = ar[u];
            }
        }
    }
}

extern "C" void kernel_launch(void* const* d_in, const int* in_sizes, int n_in,
                              void* d_out, int out_size, void* d_ws, size_t ws_size,
                              hipStream_t stream) {
    const float* x    = (const float*)d_in[0];
    const float* eatt = (const float*)d_in[1];
    const float* W1   = (const float*)d_in[2];
    const float* b1   = (const float*)d_in[3];
    const float* Wp1  = (const float*)d_in[4];
    const float* bp1  = (const float*)d_in[5];
    const float* W2   = (const float*)d_in[6];
    const float* b2   = (const float*)d_in[7];
    const float* Wp2  = (const float*)d_in[8];
    const float* bp2  = (const float*)d_in[9];
    const int*   esrc = (const int*)d_in[10];
    const int*   edst = (const int*)d_in[11];
    float* out = (float*)d_out;

    float* ws = (float*)d_ws;
    size_t o = 0;
    float* A    = ws + o; o += (size_t)N0 * 64;   // hx1 -> hx2
    float* xn1  = ws + o; o += (size_t)N1_ * 64;
    int2*  prs  = (int2*)(ws + o); o += (size_t)NE * 2;  // (local src,coef) per slot
    int*   rst  = (int*)(ws + o); o += N0;
    int*   rcn  = (int*)(ws + o); o += N0;
    float* dinv = ws + o; o += N0;
    int*   nid  = (int*)(ws + o); o += N0;
    float* x1r  = ws + o; o += BG * 128;

    float* hx1 = A;
    float* hx2 = A;                        // hx1 dead after tail1

    // ---- stage 1 ----
    stage_head_kernel<NN, false><<<BG + 512, 512, 0, stream>>>(
        esrc, edst, eatt, nullptr, prs, rst, rcn, dinv,
        (const float4*)x, (const float4*)W1, (float4*)hx1, N0, 512);
    tail_kernel<NN, K1, false><<<BG, 512, 0, stream>>>(
        (const float4*)hx1, prs, rst, rcn, dinv, (const float4*)b1,
        (const float4*)Wp1, bp1, nid, (float4*)xn1, x1r, nullptr, nullptr);
    // ---- stage 2 ----
    stage_head_kernel<K1, true><<<BG + 256, 512, 0, stream>>>(
        esrc, edst, eatt, nid, prs, rst, rcn, dinv,
        (const float4*)xn1, (const float4*)W2, (float4*)hx2, N1_, 256);
    tail_kernel<K1, K2, true><<<BG, 512, 0, stream>>>(
        (const float4*)hx2, prs, rst, rcn, dinv, (const float4*)b2,
        (const float4*)Wp2, bp2, nullptr, nullptr, nullptr, x1r, out);
}